// Round 7
// baseline (16631.825 us; speedup 1.0000x reference)
//
#include <hip/hip_runtime.h>
#include <stdint.h>
#include <math.h>

typedef unsigned int u32;
typedef unsigned long long u64;
typedef _Float16 f16;
typedef _Float16 h4 __attribute__((ext_vector_type(4)));
typedef _Float16 h2 __attribute__((ext_vector_type(2)));
typedef _Float16 h8 __attribute__((ext_vector_type(8)));
typedef float f4 __attribute__((ext_vector_type(4)));

// Problem constants
#define Vn     50000
#define DEMBn  200
#define Hn     150
#define NCn    119
#define NAn    103
#define NTn    11
#define Bn     32
#define Tn     512
#define LCn    50
#define LVn    50
#define ECn    600
#define EAn    500

#define IDIV 1073741824 // identity arow mapping

__device__ __forceinline__ float sigm(float x){ return 1.0f / (1.0f + expf(-x)); }

#if __has_builtin(__builtin_amdgcn_fdot2)
__device__ __forceinline__ float FDOT2(h2 a, h2 b, float c){
  return __builtin_amdgcn_fdot2(a, b, c, false);
}
#else
__device__ __forceinline__ float FDOT2(h2 a, h2 b, float c){
  return c + (float)a.x*(float)b.x + (float)a.y*(float)b.y;
}
#endif

// LLC-coherent agent-scope 64-bit ops (bypass non-coherent L1/L2).
__device__ __forceinline__ u64 llc_load64(const u64* p){
  return __hip_atomic_load(p, __ATOMIC_RELAXED, __HIP_MEMORY_SCOPE_AGENT);
}
__device__ __forceinline__ void llc_store64(u64* p, u64 v){
  __hip_atomic_store(p, v, __ATOMIC_RELAXED, __HIP_MEMORY_SCOPE_AGENT);
}

// 8-way compile-time select tree (no runtime array indexing -> stays in VGPRs)
__device__ __forceinline__ float sel8(const float* a, int l){
  float t0 = (l & 1) ? a[1] : a[0];
  float t1 = (l & 1) ? a[3] : a[2];
  float t2 = (l & 1) ? a[5] : a[4];
  float t3 = (l & 1) ? a[7] : a[6];
  float u0 = (l & 2) ? t1 : t0;
  float u1 = (l & 2) ? t3 : t2;
  return (l & 4) ? u1 : u0;
}

// ---------------------------------------------------------------------------
// Tiled fp32 GEMM (small/gather cases): C[M][N] = A[arow(m)][K] @ B[N][K]^T
// ---------------------------------------------------------------------------
template<int AMODE>
__global__ __launch_bounds__(256)
void gemm_k(const float* A0, const float* A1, const float* A2,
            const float* Etab, const int* tok,
            const float* Bm, int ldb, int bc0, int bc1, int bc2,
            const float* bias, const float* rowbias, int rb_div, int rb_stride,
            int arow_div, int arow_stride, int arow_off,
            float* C, int M, int N, int K)
{
  __shared__ float As[8][132];
  __shared__ float Bs[8][132];
  __shared__ int tokS[128];
  int tid = threadIdx.x;
  int m0 = blockIdx.y * 128, n0 = blockIdx.x * 128;
  if (AMODE == 1){
    for (int i = tid; i < 128; i += 256){
      int m = m0 + i;
      tokS[i] = (m < M) ? tok[m] : 0;
    }
  }
  __syncthreads();
  float acc[8][8];
  #pragma unroll
  for (int i=0;i<8;i++)
    #pragma unroll
    for (int j=0;j<8;j++) acc[i][j] = 0.f;

  int tx = tid & 15, ty = tid >> 4;

  for (int k0 = 0; k0 < K; k0 += 8){
    #pragma unroll
    for (int r = 0; r < 4; r++){
      int i = tid + 256*r;          // [0,1024)
      int ml = i >> 3, kl = i & 7;
      int k = k0 + kl;
      {
        int m = m0 + ml;
        float v = 0.f;
        if (m < M && k < K){
          if (AMODE == 0){
            int s = k / 300; int kk = k - s*300;
            const float* Ap = (s==0) ? A0 : ((s==1) ? A1 : A2);
            int ar = (m / arow_div)*arow_stride + (m % arow_div) + arow_off;
            v = Ap[(size_t)ar*300 + kk];
          } else {
            v = Etab[(size_t)tokS[ml]*DEMBn + k];
          }
        }
        As[kl][ml] = v;
      }
      {
        int n = n0 + ml;
        float v = 0.f;
        if (n < N && k < K){
          int col;
          if (AMODE == 0){ int s = k / 300; int kk = k - s*300; col = ((s==0)?bc0:((s==1)?bc1:bc2)) + kk; }
          else col = k;
          v = Bm[(size_t)n*ldb + col];
        }
        Bs[kl][ml] = v;
      }
    }
    __syncthreads();
    #pragma unroll
    for (int kk = 0; kk < 8; kk++){
      float a[8], b[8];
      #pragma unroll
      for (int i=0;i<8;i++) a[i] = As[kk][ty*8+i];
      #pragma unroll
      for (int i=0;i<8;i++) b[i] = Bs[kk][tx*8+i];
      #pragma unroll
      for (int i=0;i<8;i++)
        #pragma unroll
        for (int j=0;j<8;j++) acc[i][j] += a[i]*b[j];
    }
    __syncthreads();
  }
  #pragma unroll
  for (int i=0;i<8;i++){
    int m = m0 + ty*8 + i; if (m >= M) continue;
    #pragma unroll
    for (int j=0;j<8;j++){
      int n = n0 + tx*8 + j; if (n >= N) continue;
      float v = acc[i][j];
      if (bias)    v += bias[n];
      if (rowbias) v += rowbias[(size_t)(m / rb_div)*rb_stride + n];
      C[(size_t)m*N + n] = v;
    }
  }
}

// ---------------------------------------------------------------------------
// MFMA split-f16 staging GEMM for the big xs gemms (art/term).
// Precision: A=Ahi+Alo, B=Bhi+Blo (f16 split); acc += AhBh + AhBl + AlBh in
// f32 MFMA -> ~2^-22 relative error (f32-grade), at MFMA rates.
// ---------------------------------------------------------------------------
__global__ __launch_bounds__(256)
void stage_mfma_k(const float* A0, const float* A1, const float* A2,
                  const float* Bm, int ldb, int bc0, int bc1, int bc2,
                  const float* bias, const float* rowbias, int rb_stride,
                  int arow_off,
                  float* C, int N, int K)
{
  constexpr int KP = 40;                    // f16 row stride (80B: 16B-aligned rows)
  __shared__ __align__(16) f16 Ah[128*KP];
  __shared__ __align__(16) f16 Al[128*KP];
  __shared__ __align__(16) f16 Bh[128*KP];
  __shared__ __align__(16) f16 Bl[128*KP];

  int tid = threadIdx.x;
  int n0 = blockIdx.x * 128, m0 = blockIdx.y * 128;
  int lane = tid & 63, w = tid >> 6;
  int wr = (w >> 1) * 64, wc = (w & 1) * 64;   // wave tile origin in block tile
  int li = lane & 15, lk = (lane >> 4) * 8;

  f4 acc[4][4];
  #pragma unroll
  for (int i=0;i<4;i++)
    #pragma unroll
    for (int j=0;j<4;j++) acc[i][j] = (f4){0.f,0.f,0.f,0.f};

  int srow = tid >> 1, scb = (tid & 1) << 4;   // staging: row, col-base (16 k each)
  int sm = m0 + srow;
  size_t abase = (size_t)(((sm >> 8) * 512) + (sm & 255) + arow_off) * 300;
  int sn = n0 + srow;

  for (int k0 = 0; k0 < K; k0 += 32){
    // ---- stage A,B k-tile as hi/lo f16 ----
    #pragma unroll
    for (int q = 0; q < 16; q += 2){
      float va0=0.f, va1=0.f, vb0=0.f, vb1=0.f;
      int k = k0 + scb + q;
      if (k < K){
        int s = (k >= 600) ? 2 : ((k >= 300) ? 1 : 0);
        int kk = k - s*300;
        const float* Ap = (s==0) ? A0 : ((s==1) ? A1 : A2);
        va0 = Ap[abase + kk];
        if (sn < N) vb0 = Bm[(size_t)sn*ldb + ((s==0)?bc0:((s==1)?bc1:bc2)) + kk];
      }
      int k1 = k + 1;
      if (k1 < K){
        int s = (k1 >= 600) ? 2 : ((k1 >= 300) ? 1 : 0);
        int kk = k1 - s*300;
        const float* Ap = (s==0) ? A0 : ((s==1) ? A1 : A2);
        va1 = Ap[abase + kk];
        if (sn < N) vb1 = Bm[(size_t)sn*ldb + ((s==0)?bc0:((s==1)?bc1:bc2)) + kk];
      }
      f16 a0h=(f16)va0, a1h=(f16)va1, b0h=(f16)vb0, b1h=(f16)vb1;
      f16 a0l=(f16)(va0-(float)a0h), a1l=(f16)(va1-(float)a1h);
      f16 b0l=(f16)(vb0-(float)b0h), b1l=(f16)(vb1-(float)b1h);
      int off = srow*KP + scb + q;
      *(h2*)&Ah[off] = (h2){a0h, a1h};
      *(h2*)&Al[off] = (h2){a0l, a1l};
      *(h2*)&Bh[off] = (h2){b0h, b1h};
      *(h2*)&Bl[off] = (h2){b0l, b1l};
    }
    __syncthreads();

    // ---- fragments + 3-pass MFMA ----
    h8 fah[4], fal[4], fbh[4], fbl[4];
    #pragma unroll
    for (int f = 0; f < 4; f++){
      fah[f] = *(const h8*)&Ah[(wr + f*16 + li)*KP + lk];
      fal[f] = *(const h8*)&Al[(wr + f*16 + li)*KP + lk];
      fbh[f] = *(const h8*)&Bh[(wc + f*16 + li)*KP + lk];
      fbl[f] = *(const h8*)&Bl[(wc + f*16 + li)*KP + lk];
    }
    #pragma unroll
    for (int i = 0; i < 4; i++)
      #pragma unroll
      for (int j = 0; j < 4; j++){
        acc[i][j] = __builtin_amdgcn_mfma_f32_16x16x32_f16(fah[i], fbh[j], acc[i][j], 0,0,0);
        acc[i][j] = __builtin_amdgcn_mfma_f32_16x16x32_f16(fah[i], fbl[j], acc[i][j], 0,0,0);
        acc[i][j] = __builtin_amdgcn_mfma_f32_16x16x32_f16(fal[i], fbh[j], acc[i][j], 0,0,0);
      }
    __syncthreads();
  }

  // ---- epilogue ----
  #pragma unroll
  for (int i = 0; i < 4; i++){
    int r0 = m0 + wr + i*16 + (lane >> 4)*4;
    #pragma unroll
    for (int j = 0; j < 4; j++){
      int c = n0 + wc + j*16 + li;
      if (c < N){
        float badd = bias ? bias[c] : 0.f;
        #pragma unroll
        for (int r = 0; r < 4; r++){
          int row = r0 + r;
          float v = acc[i][j][r] + badd;
          if (rowbias) v += rowbias[(size_t)(row >> 8)*rb_stride + c];
          C[(size_t)row*N + c] = v;
        }
      }
    }
  }
}

// ---------------------------------------------------------------------------
// Small-GRU recurrence (H=150): one block per (seq, dir). 4 lanes/row,
// exact f32 weights in VGPRs, parity double-buffered h, 1 barrier/step.
// ---------------------------------------------------------------------------
__global__ __launch_bounds__(640)
void gru_small_k(const float* xs, int ncols,
                 const float* Whh, const float* bhh,
                 float* ys, float* meanOut, int T)
{
  constexpr int KSTEP = 38;                 // ceil(150/4)
  __shared__ __align__(16) float hl[2][152];
  int tid = threadIdx.x;
  int seq = blockIdx.x, dir = blockIdx.y;
  int row = tid >> 2, l = tid & 3;
  bool comp = (row < 150);
  int k0 = l * KSTEP;

  float w0[KSTEP], w1[KSTEP], w2[KSTEP];
  if (comp){
    const float* base = Whh + (size_t)dir*67500;
    const float* p0 = base + (size_t)(0*150 + row)*150;
    const float* p1 = base + (size_t)(1*150 + row)*150;
    const float* p2 = base + (size_t)(2*150 + row)*150;
    #pragma unroll
    for (int i=0;i<KSTEP;i++){
      int k = k0 + i;
      int kc = (k < 150) ? k : 0;
      float m = (k < 150) ? 1.f : 0.f;
      w0[i] = p0[kc]*m; w1[i] = p1[kc]*m; w2[i] = p2[kc]*m;
    }
  }
  float bR=0.f, bZ=0.f, bN=0.f;
  if (comp && l==0){
    bR = bhh[dir*450 + row];
    bZ = bhh[dir*450 + 150 + row];
    bN = bhh[dir*450 + 300 + row];
  }
  for (int i = tid; i < 2*152; i += 640) (&hl[0][0])[i] = 0.f;
  __syncthreads();

  float msum = 0.f;
  size_t rowbase = (size_t)seq * T;
  for (int tt = 0; tt < T; tt++){
    int t = dir ? (T-1-tt) : tt;
    int par = tt & 1;
    const float* hr = hl[par];
    float* hw = hl[1-par];

    float xr=0.f, xz=0.f, xn=0.f, hprev=0.f;
    if (comp && l==0){
      const float* xp = xs + (rowbase + t)*(size_t)ncols + dir*450;
      xr = xp[row]; xz = xp[150+row]; xn = xp[300+row];
      hprev = hr[row];
    }

    float a0=0.f, a1=0.f, a2=0.f;
    if (comp){
      #pragma unroll
      for (int i=0;i<KSTEP;i++){
        float hv = hr[k0 + i];
        a0 += w0[i]*hv; a1 += w1[i]*hv; a2 += w2[i]*hv;
      }
    }
    a0 += __shfl_xor(a0,1); a0 += __shfl_xor(a0,2);
    a1 += __shfl_xor(a1,1); a1 += __shfl_xor(a1,2);
    a2 += __shfl_xor(a2,1); a2 += __shfl_xor(a2,2);

    if (comp && l==0){
      float rr = sigm(xr + a0 + bR);
      float zz = sigm(xz + a1 + bZ);
      float nn = tanhf(xn + rr*(a2 + bN));
      float hn = (1.f - zz)*nn + zz*hprev;
      hw[row] = hn;
      msum += hn;
      if (ys) ys[(rowbase + t)*(size_t)300 + dir*150 + row] = hn;
    }
    __syncthreads();
  }
  if (meanOut && comp && l==0)
    meanOut[(size_t)seq*300 + dir*150 + row] = msum / (float)T;
}

// ---------------------------------------------------------------------------
// Big-GRU recurrence, BOTH dirs per launch, time-sliced. Weights in VGPRs,
// tagged-pair LLC h exchange, exact f32 hold + HSEED chunk reseed.
// R7: SB=8 batches per block (bg grid halved) — 8 independent chains' tag
// loads share one LLC round-trip window; doubled gemv fills the wait.
// ---------------------------------------------------------------------------
template<int BLK, int JB, int KC, int Hh, int SB>
__global__ __launch_bounds__(BLK)
void gru_big_k(const float* xs0, const float* xs1,
               const float* Whh,         // [2][3*Hh][Hh] f32
               const float* bhh,         // [2][3*Hh]
               u64* hbuf,                // [2 parity][2 dir][B][Hh/2] tagged pairs
               float* hseed,             // [2 dir][B][Hh] exact f32 chunk seed
               float* meanOut, int mean_stride,
               u32 tagbase,
               int TT, int TC, int t0)
{
  constexpr int LPR   = 8;
  constexpr int KSTEP = 2*KC;
  constexpr int HS    = LPR*KSTEP;
  constexpr int HP    = Hh/2;
  constexpr int NPAIR = SB*HP;
  constexpr int RMAX  = (NPAIR + BLK - 1)/BLK;
  constexpr int H3    = 3*Hh;

  __shared__ __align__(16) f16 hstage[2][SB*HS];

  int tid = threadIdx.x;
  int jc = blockIdx.x, bg = blockIdx.y, dir = blockIdx.z;
  int j0 = jc * JB;
  int row = tid >> 3, l = tid & 7;
  bool comp = (row < JB);
  int jg = j0 + row;
  int k0 = l * KSTEP;

  const float* Wd = Whh + (size_t)dir*H3*Hh;
  const float* xs = dir ? xs1 : xs0;
  int xoff = dir ? (TT - TC - t0) : t0;

  h2 w0[KC], w1[KC], w2[KC];
  if (comp){
    const float* p0 = Wd + ((size_t)0*Hh + jg)*(size_t)Hh;
    const float* p1 = Wd + ((size_t)1*Hh + jg)*(size_t)Hh;
    const float* p2 = Wd + ((size_t)2*Hh + jg)*(size_t)Hh;
    #pragma unroll
    for (int i=0;i<KC;i++){
      int k = k0 + 2*i;
      h2 a; a.x=(f16)0.f; a.y=(f16)0.f;
      h2 b = a, c = a;
      if (k < Hh){   a.x=(f16)p0[k];   b.x=(f16)p1[k];   c.x=(f16)p2[k]; }
      if (k+1 < Hh){ a.y=(f16)p0[k+1]; b.y=(f16)p1[k+1]; c.y=(f16)p2[k+1]; }
      w0[i]=a; w1[i]=b; w2[i]=c;
    }
  } else {
    #pragma unroll
    for (int i=0;i<KC;i++){
      h2 z; z.x=(f16)0.f; z.y=(f16)0.f;
      w0[i]=z; w1[i]=z; w2[i]=z;
    }
  }
  float br=0.f, bz=0.f, bn_=0.f;
  if (comp && l < SB){
    br = bhh[(size_t)dir*H3 + jg];
    bz = bhh[(size_t)dir*H3 + Hh + jg];
    bn_= bhh[(size_t)dir*H3 + 2*Hh + jg];
  }

  {
    f16* hz = &hstage[0][0];
    for (int i = tid; i < 2*SB*HS; i += BLK) hz[i] = (f16)0.f;
  }

  float msum_own = 0.f;
  float hold_own = 0.f;                  // batch s = l ownership (l < SB)
  if (t0 > 0 && comp && l < SB){
    const float* hs = hseed + (size_t)dir*Bn*Hh;
    hold_own = hs[(size_t)(bg*SB+l)*Hh + jg];
  }
  __syncthreads();

  for (int tt = 0; tt < TC; tt++){
    int g = t0 + tt;
    int t = dir ? (TT-1-g) : g;
    int par = g & 1;
    const u64* hrd = hbuf + (size_t)(par*2 + dir)*Bn*HP;
    u64*       hwr = hbuf + (size_t)((1-par)*2 + dir)*Bn*HP;
    f16* hsb = hstage[par];

    u64 tmp[RMAX];
    const u64* hb = hrd + (size_t)(bg*SB)*HP;
    if (g != 0){
      #pragma unroll
      for (int r=0;r<RMAX;r++){
        int idx = tid + r*BLK;
        if (idx < NPAIR) tmp[r] = llc_load64(&hb[idx]);
      }
    }

    // xs prefetch: lane l<SB loads batch l only (3 loads, overlaps tag check)
    float xr=0.f, xz=0.f, xn=0.f;
    if (comp && l < SB){
      const float* xp = xs + ((size_t)(bg*SB+l)*TC + (t - xoff))*(size_t)H3;
      xr = xp[jg]; xz = xp[Hh+jg]; xn = xp[2*Hh+jg];
    }

    if (g != 0){
      u32 want = tagbase + (u32)g;
      u32 pend = 0;
      #pragma unroll
      for (int r=0;r<RMAX;r++){
        int idx = tid + r*BLK;
        if (idx < NPAIR && (u32)(tmp[r] >> 32) != want) pend |= (1u << r);
      }
      int guard = 0;
      while (pend){
        __builtin_amdgcn_s_sleep(1);
        #pragma unroll
        for (int r=0;r<RMAX;r++)
          if (pend & (1u << r)) tmp[r] = llc_load64(&hb[tid + r*BLK]);
        #pragma unroll
        for (int r=0;r<RMAX;r++)
          if ((pend & (1u << r)) && (u32)(tmp[r] >> 32) == want) pend &= ~(1u << r);
        if (++guard > 200000) break;   // failsafe: wrong result > GPU hang
      }
      #pragma unroll
      for (int r=0;r<RMAX;r++){
        int idx = tid + r*BLK;
        if (idx < NPAIR){
          int s = idx / HP, jp = idx - s*HP;
          union { u32 i; h2 h; } u; u.i = (u32)tmp[r];
          *(h2*)(hsb + s*HS + 2*jp) = u.h;
        }
      }
    }
    __syncthreads();

    float a0[SB], a1[SB], a2[SB];
    #pragma unroll
    for (int s=0;s<SB;s++){ a0[s]=0.f; a1[s]=0.f; a2[s]=0.f; }
    if (comp){
      const f16* hp = hsb + k0;
      #pragma unroll
      for (int i=0;i<KC;i++){
        const int kk = 2*i;
        #pragma unroll
        for (int s=0;s<SB;s++){
          h2 hv = *(const h2*)(hp + s*HS + kk);
          a0[s]=FDOT2(w0[i],hv,a0[s]);
          a1[s]=FDOT2(w1[i],hv,a1[s]);
          a2[s]=FDOT2(w2[i],hv,a2[s]);
        }
      }
    }
    #pragma unroll
    for (int s=0;s<SB;s++){
      a0[s] += __shfl_xor(a0[s],1); a0[s] += __shfl_xor(a0[s],2); a0[s] += __shfl_xor(a0[s],4);
      a1[s] += __shfl_xor(a1[s],1); a1[s] += __shfl_xor(a1[s],2); a1[s] += __shfl_xor(a1[s],4);
      a2[s] += __shfl_xor(a2[s],1); a2[s] += __shfl_xor(a2[s],2); a2[s] += __shfl_xor(a2[s],4);
    }
    // lane l selects batch l's sums (compile-time cndmask tree)
    float A0 = sel8(a0, l), A1 = sel8(a1, l), A2 = sel8(a2, l);

    float hn_own = 0.f;
    if (comp && l < SB){
      float rr = sigm(xr + A0 + br);
      float zz = sigm(xz + A1 + bz);
      float nn = tanhf(xn + rr*(A2 + bn_));
      hn_own = (1.f - zz)*nn + zz*hold_own;
      hold_own = hn_own;
      msum_own += hn_own;
    }
    // pair adjacent rows: even row's lane l grabs odd row's hn (lane+8)
    u32 wtag = tagbase + (u32)g + 1u;
    float hp2 = __shfl_down(hn_own, 8);
    if (comp && l < SB && !(row & 1)){
      h2 pk; pk.x = (f16)hn_own; pk.y = (f16)hp2;
      union { h2 h; u32 i; } u; u.h = pk;
      llc_store64(&hwr[(size_t)(bg*SB+l)*HP + ((unsigned)(j0+row) >> 1)],
                  ((u64)wtag << 32) | (u64)u.i);
    }
    if (tt == TC-1 && comp && l < SB){
      float* hs = hseed + (size_t)dir*Bn*Hh;
      hs[(size_t)(bg*SB+l)*Hh + jg] = hold_own;
    }
  }
  if (comp && l < SB){
    float* mp = meanOut + (size_t)(bg*SB+l)*mean_stride + dir*Hh + jg;
    *mp += msum_own / (float)TT;
  }
}

// ---------------------------------------------------------------------------
// mask_att + fact_sep fused: per (b, 8-t chunk).
// ---------------------------------------------------------------------------
__global__ __launch_bounds__(256)
void mask_att_k(const float* ctx, const float* vh, float* simOut, float* diffOut)
{
  __shared__ float vhl[50*300];
  __shared__ float ctxl[8*300];
  __shared__ float attl[8*52];
  __shared__ float scenl[8*300];
  __shared__ float ratio[8];
  int tid = threadIdx.x;
  int b = blockIdx.y, tc = blockIdx.x;
  size_t cbase = ((size_t)b*Tn + tc*8) * 300;
  for (int i = tid; i < 15000; i += 256) vhl[i] = vh[(size_t)b*15000 + i];
  for (int i = tid; i < 2400; i += 256)  ctxl[i] = ctx[cbase + i];
  __syncthreads();
  for (int p = tid; p < 400; p += 256){
    int ttl = p / 50, v = p % 50;
    const float* cp = ctxl + ttl*300;
    const float* vp = vhl + v*300;
    float acc = 0.f;
    for (int d = 0; d < 300; d++) acc += cp[d]*vp[d];
    attl[ttl*52 + v] = acc;
  }
  __syncthreads();
  if (tid < 8){
    float mx = -INFINITY;
    for (int v=0; v<50; v++){
      float a = attl[tid*52+v];
      float msk = (a == 0.f) ? -INFINITY : a;
      attl[tid*52+v] = msk;
      mx = fmaxf(mx, msk);
    }
    if (mx == -INFINITY){
      for (int v=0; v<50; v++) attl[tid*52+v] = 0.f;
    } else {
      float sum = 0.f;
      for (int v=0; v<50; v++){ float e = expf(attl[tid*52+v] - mx); attl[tid*52+v] = e; sum += e; }
      float inv = 1.f/sum;
      for (int v=0; v<50; v++) attl[tid*52+v] *= inv;
    }
  }
  __syncthreads();
  for (int p = tid; p < 2400; p += 256){
    int ttl = p / 300, d = p % 300;
    float acc = 0.f;
    for (int v=0; v<50; v++) acc += attl[ttl*52+v] * vhl[v*300+d];
    scenl[p] = acc;
  }
  __syncthreads();
  if (tid < 8){
    float x3=0.f, x4=0.f;
    for (int d=0; d<300; d++){ float s = scenl[tid*300+d]; x3 += ctxl[tid*300+d]*s; x4 += s*s; }
    ratio[tid] = x3 / (x4 + 1e-10f);
  }
  __syncthreads();
  for (int p = tid; p < 2400; p += 256){
    float sim = ratio[p/300] * scenl[p];
    simOut[cbase + p]  = sim;
    diffOut[cbase + p] = ctxl[p] - sim;
  }
}

// ---------------------------------------------------------------------------
// code_wise helpers
// ---------------------------------------------------------------------------
__global__ void rowmax_k(const float* S, float* out, int M, int N){
  int row = blockIdx.x*4 + (threadIdx.x >> 6);
  int lane = threadIdx.x & 63;
  if (row >= M) return;
  float mx = -INFINITY;
  for (int n = lane; n < N; n += 64) mx = fmaxf(mx, S[(size_t)row*N + n]);
  for (int off = 32; off; off >>= 1) mx = fmaxf(mx, __shfl_xor(mx, off, 64));
  if (lane == 0) out[row] = mx;
}

__global__ __launch_bounds__(256)
void softmaxT_k(const float* m, float* att){
  __shared__ float red[256];
  int b = blockIdx.x, tid = threadIdx.x;
  float v1 = m[b*512 + tid], v2 = m[b*512 + 256 + tid];
  red[tid] = fmaxf(v1, v2); __syncthreads();
  for (int s=128; s; s>>=1){ if (tid<s) red[tid] = fmaxf(red[tid], red[tid+s]); __syncthreads(); }
  float M = red[0]; __syncthreads();
  float e1 = expf(v1-M), e2 = expf(v2-M);
  red[tid] = e1+e2; __syncthreads();
  for (int s=128; s; s>>=1){ if (tid<s) red[tid] += red[tid+s]; __syncthreads(); }
  float inv = 1.f / red[0];
  att[b*512+tid] = e1*inv; att[b*512+256+tid] = e2*inv;
}

__global__ __launch_bounds__(256)
void wsum_k(const float* att, const float* dh, float* out){
  int b = blockIdx.x, tid = threadIdx.x;
  for (int d = tid; d < 300; d += 256){
    float acc = 0.f;
    #pragma unroll 8
    for (int t = 0; t < 512; t++)
      acc += att[b*512+t] * dh[((size_t)b*512 + t)*300 + d];
    out[b*300+d] = acc;
  }
}

// ---------------------------------------------------------------------------
// graph_decomp helpers
// ---------------------------------------------------------------------------
__global__ void count_k(const int* src, int E, float* counts){
  int e = blockIdx.x*256 + threadIdx.x;
  if (e < E) atomicAdd(&counts[src[e]], 1.f);
}
__global__ void coef_k(const float* L, const int* src, const int* dst, int E, float* coef){
  int e = blockIdx.x*4 + (threadIdx.x >> 6);
  int lane = threadIdx.x & 63;
  if (e >= E) return;
  const float* Li = L + (size_t)src[e]*300;
  const float* Lj = L + (size_t)dst[e]*300;
  float num = 0.f, den = 0.f;
  for (int d = lane; d < 300; d += 64){ float lj = Lj[d]; num += Li[d]*lj; den += lj*lj; }
  for (int off = 32; off; off >>= 1){ num += __shfl_xor(num, off, 64); den += __shfl_xor(den, off, 64); }
  if (lane == 0) coef[e] = num / (den + 1e-10f);
}
__global__ void agg_k(const float* L, const int* src, const int* dst, const float* coef, int E, float* agg){
  int e = blockIdx.x;
  float c = coef[e];
  const float* Lj = L + (size_t)dst[e]*300;
  float* ag = agg + (size_t)src[e]*300;
  for (int d = threadIdx.x; d < 300; d += 256) atomicAdd(&ag[d], c*Lj[d]);
}
__global__ void upd_k(const float* L, const float* agg, const float* counts, float* out, int n){
  int i = blockIdx.x;
  float c = counts[i];
  for (int d = threadIdx.x; d < 300; d += 256){
    float v = L[(size_t)i*300+d];
    out[(size_t)i*300+d] = (c > 0.f) ? v - agg[(size_t)i*300+d]/fmaxf(c, 1.f) : v;
  }
}

// ---------------------------------------------------------------------------
// classifier heads, argmax, gather
// ---------------------------------------------------------------------------
__global__ __launch_bounds__(128)
void logits_k(const float* A0, const float* A1, const float* A2, int srcw,
              const float* W, const float* bias, int C, int K,
              float* outF){
  int b = blockIdx.x, tid = threadIdx.x;
  for (int c = tid; c < C; c += 128){
    float acc = bias[c];
    const float* wp = W + (size_t)c*K;
    for (int k = 0; k < K; k++){
      int s = k / srcw; int kk = k - s*srcw;
      const float* Ap = (s==0) ? A0 : ((s==1) ? A1 : A2);
      acc += Ap[(size_t)b*srcw + kk] * wp[k];
    }
    outF[b*C + c] = acc;
  }
}
__global__ void argmax_k(const float* lf, int C, int* pred){
  int b = threadIdx.x;
  if (b < 32){
    const float* p = lf + (size_t)b*C;
    int best = 0; float bv = p[0];
    for (int c = 1; c < C; c++){ float v = p[c]; if (v > bv){ bv = v; best = c; } }
    pred[b] = best;
  }
}
__global__ void vtok_k(const int* table, const int* pred, int* vt, int L){
  int i = blockIdx.x*256 + threadIdx.x;
  if (i < 32*L) vt[i] = table[pred[i/L]*L + i%L];
}

// ---------------------------------------------------------------------------
extern "C" void kernel_launch(void* const* d_in, const int* in_sizes, int n_in,
                              void* d_out, int out_size, void* d_ws, size_t ws_size,
                              hipStream_t stream)
{
  (void)in_sizes; (void)n_in; (void)out_size;
  const float* E        = (const float*)d_in[0];
  const int* chTok    = (const int*)d_in[1];
  const int* arTok    = (const int*)d_in[2];
  const int* docs     = (const int*)d_in[3];
  const int* chVerd   = (const int*)d_in[4];
  const int* arVerd   = (const int*)d_in[5];
  const int* c_src    = (const int*)d_in[6];
  const int* c_dst    = (const int*)d_in[7];
  const int* a_src    = (const int*)d_in[8];
  const int* a_dst    = (const int*)d_in[9];
  const float* enc_Wih  = (const float*)d_in[10];
  const float* enc_Whh  = (const float*)d_in[11];
  const float* enc_bih  = (const float*)d_in[12];
  const float* enc_bhh  = (const float*)d_in[13];
  const float* ech_Wih  = (const float*)d_in[14];
  const float* ech_Whh  = (const float*)d_in[15];
  const float* ech_bih  = (const float*)d_in[16];
  const float* ech_bhh  = (const float*)d_in[17];
  const float* term_Wih = (const float*)d_in[18];
  const float* term_Whh = (const float*)d_in[19];
  const float* term_bih = (const float*)d_in[20];
  const float* term_bhh = (const float*)d_in[21];
  const float* art_Wih  = (const float*)d_in[22];
  const float* art_Whh  = (const float*)d_in[23];
  const float* art_bih  = (const float*)d_in[24];
  const float* art_bhh  = (const float*)d_in[25];
  const float* W_charge = (const float*)d_in[26];
  const float* b_charge = (const float*)d_in[27];
  const float* W_article= (const float*)d_in[28];
  const float* b_article= (const float*)d_in[29];
  const float* W_time   = (const float*)d_in[30];
  const float* b_time   = (const float*)d_in[31];
  float* out = (float*)d_out;
  float* OUTC = out;            // [32][119]
  float* OUTA = out + 3808;     // [32][103]
  float* OUTT = out + 7104;     // [32][11]

  char* wsb = (char*)d_ws;
  size_t off = 0;
  auto alloc = [&](size_t nf)->float* {
    float* p = (float*)(wsb + off);
    off += ((nf*4 + 255) & ~(size_t)255);
    return p;
  };
  float* XS0   = alloc(14745600ULL);        // 59.0 MB
  float* XS1   = alloc(14745600ULL);        // 59.0 MB
  float* SBUF  = XS0;                       // alias: disjoint lifetime
  float* DH    = alloc(4915200);            // d_hidden [32][512][300]
  float* ADC   = alloc(4915200);            // adc, later dsc
  float* SEC   = alloc(4915200);
  float* SSC   = alloc(4915200);
  float* VHYS  = alloc(480000);             // [32][50][300]
  float* MECH  = alloc(66600);              // encch means [222][300]
  float* LC1   = alloc(35700);
  float* LC0   = alloc(35700);
  float* LA1   = alloc(30900);
  float* LA0   = alloc(30900);
  float* AGG   = alloc(35700);
  float* CNTS  = alloc(256);                // counts_c @0, counts_a @128
  float* COEF  = alloc(640);
  float* DHC   = alloc(9600);
  float* DA    = alloc(9600);
  float* DHNA  = alloc(9600);
  float* DB    = alloc(9600);
  float* MDH   = alloc(9600);               // mean_t d_hidden [32][300]
  float* MFA   = alloc(38400);              // fa mean [32][1200] (accumulated)
  float* MTH   = alloc(28800);              // th mean [32][900] (accumulated)
  float* RB    = alloc(115200);             // art rowbias [32][3600]
  float* RMX   = alloc(16384);
  float* ATTB  = alloc(16384);
  u64*   HBUF  = (u64*)alloc(76800);        // [2][2][32][300] u64 tagged pairs
  float* HSEED = alloc(38400);              // [2][32][600] exact f32 seeds
  int*   PREDC = (int*)alloc(64);
  int*   PREDA = (int*)alloc(64);
  int*   VTOK  = (int*)alloc(1600);
  int*   TCC   = (int*)alloc(11104);

  if (off > ws_size) return;   // diagnostic: leaves out==0 -> absmax==max|ref|

  hipMemsetAsync(HBUF, 0, 2*2*Bn*300*sizeof(u64), stream);  // tags = 0
  hipMemsetAsync(CNTS, 0, 256*4, stream);

  // --- encch on charge+article token sequences (222 seqs, L=50) ---
  hipMemcpyAsync(TCC, chTok, NCn*LCn*4, hipMemcpyDeviceToDevice, stream);
  hipMemcpyAsync(TCC + NCn*LCn, arTok, NAn*LCn*4, hipMemcpyDeviceToDevice, stream);
  {
    dim3 g((900+127)/128, (11100+127)/128);
    gemm_k<1><<<g,256,0,stream>>>(nullptr,nullptr,nullptr, E, TCC,
        ech_Wih, 200, 0,0,0, ech_bih, nullptr, 1, 1, IDIV,0,0,
        XS0, 11100, 900, 200);
  }
  gru_small_k<<<dim3(222,2),640,0,stream>>>(XS0, 900, ech_Whh, ech_bhh, nullptr, MECH, 50);

  // --- enc on documents ---
  {
    dim3 g((900+127)/128, (16384+127)/128);
    gemm_k<1><<<g,256,0,stream>>>(nullptr,nullptr,nullptr, E, docs,
        enc_Wih, 200, 0,0,0, enc_bih, nullptr, 1, 1, IDIV,0,0,
        XS0, 16384, 900, 200);
  }
  gru_small_k<<<dim3(32,2),640,0,stream>>>(XS0, 900, enc_Whh, enc_bhh, DH, MDH, 512);

  // --- graph_decomp (charge, article), 2 layers each ---
  count_k<<<3,256,0,stream>>>(c_src, ECn, CNTS);
  count_k<<<2,256,0,stream>>>(a_src, EAn, CNTS+128);
  coef_k<<<150,256,0,stream>>>(MECH, c_src, c_dst, ECn, COEF);
  hipMemsetAsync(AGG, 0, 35700*4, stream);
  agg_k<<<ECn,256,0,stream>>>(MECH, c_src, c_dst, COEF, ECn, AGG);
  upd_k<<<NCn,256,0,stream>>>(MECH, AGG, CNTS, LC1, NCn);
  coef_k<<<150,256,0,stream>>>(LC1, c_src, c_dst, ECn, COEF);
  hipMemsetAsync(AGG, 0, 35700*4, stream);
  agg_k<<<ECn,256,0,stream>>>(LC1, c_src, c_dst, COEF, ECn, AGG);
  upd_k<<<NCn,256,0,stream>>>(LC1, AGG, CNTS, LC0, NCn);

  const float* MEAR = MECH + (size_t)NCn*300;
  coef_k<<<125,256,0,stream>>>(MEAR, a_src, a_dst, EAn, COEF);
  hipMemsetAsync(AGG, 0, 30900*4, stream);
  agg_k<<<EAn,256,0,stream>>>(MEAR, a_src, a_dst, COEF, EAn, AGG);
  upd_k<<<NAn,256,0,stream>>>(MEAR, AGG, CNTS+128, LA1, NAn);
  coef_k<<<125,256,0,stream>>>(LA1, a_src, a_dst, EAn, COEF);
  hipMemsetAsync(AGG, 0, 30900*4, stream);
  agg_k<<<EAn,256,0,stream>>>(LA1, a_src, a_dst, COEF, EAn, AGG);
  upd_k<<<NAn,256,0,stream>>>(LA1, AGG, CNTS+128, LA0, NAn);

  // --- code_wise x4 (S-buffer aliased into XS0) ---
  auto codewise = [&](const float* q, int Nq, float* outv){
    dim3 g((Nq+127)/128, 128);
    gemm_k<0><<<g,256,0,stream>>>(DH, nullptr, nullptr, nullptr, nullptr,
        q, 300, 0,0,0, nullptr, nullptr, 1, 1, IDIV,0,0,
        SBUF, 16384, Nq, 300);
    rowmax_k<<<4096,256,0,stream>>>(SBUF, RMX, 16384, Nq);
    softmaxT_k<<<32,256,0,stream>>>(RMX, ATTB);
    wsum_k<<<32,256,0,stream>>>(ATTB, DH, outv);
  };
  codewise(LC0,  NCn, DHC);    // new_charge
  codewise(MECH, NCn, DA);     // ori charge
  codewise(LA0,  NAn, DHNA);   // new_article
  codewise(MEAR, NAn, DB);     // ori article

  // --- charge head ---
  logits_k<<<32,128,0,stream>>>(MDH, DHC, DA, 300, W_charge, b_charge, NCn, 900, OUTC);
  argmax_k<<<1,64,0,stream>>>(OUTC, NCn, PREDC);

  // --- fact_sep #1 ---
  vtok_k<<<7,256,0,stream>>>(chVerd, PREDC, VTOK, LVn);
  {
    dim3 g((900+127)/128, (1600+127)/128);
    gemm_k<1><<<g,256,0,stream>>>(nullptr,nullptr,nullptr, E, VTOK,
        enc_Wih, 200, 0,0,0, enc_bih, nullptr, 1, 1, IDIV,0,0,
        XS0, 1600, 900, 200);
  }
  gru_small_k<<<dim3(32,2),640,0,stream>>>(XS0, 900, enc_Whh, enc_bhh, VHYS, nullptr, 50);
  mask_att_k<<<dim3(64,32),256,0,stream>>>(DH, VHYS, ADC, SEC);

  // --- article bigru: rowbias, then time-sliced dual-dir chunks ---
  {
    dim3 g((3600+127)/128, 1);
    gemm_k<0><<<g,256,0,stream>>>(DHNA, DB, nullptr, nullptr, nullptr,
        art_Wih, 1200, 300, 900, 0, art_bih, nullptr, 1, 1, IDIV,0,0,
        RB, 32, 3600, 600);
  }
  hipMemsetAsync(MFA, 0, 38400*4, stream);
  for (int L = 0; L < 2; L++){
    stage_mfma_k<<<dim3(15,64),256,0,stream>>>(DH, ADC, nullptr,
        art_Wih, 1200, 0, 600, 0,
        nullptr, RB, 3600, 256*L,
        XS0, 1800, 600);
    stage_mfma_k<<<dim3(15,64),256,0,stream>>>(DH, ADC, nullptr,
        art_Wih + (size_t)1800*1200, 1200, 0, 600, 0,
        nullptr, RB + 1800, 3600, 256*(1-L),
        XS1, 1800, 600);
    gru_big_k<384,40,38,600,8><<<dim3(15,4,2),384,0,stream>>>(XS0, XS1,
        art_Whh, art_bhh, HBUF, HSEED, MFA, 1200, 0u,
        512, 256, 256*L);
  }
  logits_k<<<32,128,0,stream>>>(MFA, nullptr, nullptr, 1200, W_article, b_article, NAn, 1200, OUTA);
  argmax_k<<<1,64,0,stream>>>(OUTA, NAn, PREDA);

  // --- fact_sep #2 (context = sec_vector) ---
  vtok_k<<<7,256,0,stream>>>(arVerd, PREDA, VTOK, LVn);
  {
    dim3 g((900+127)/128, (1600+127)/128);
    gemm_k<1><<<g,256,0,stream>>>(nullptr,nullptr,nullptr, E, VTOK,
        enc_Wih, 200, 0,0,0, enc_bih, nullptr, 1, 1, IDIV,0,0,
        XS0, 1600, 900, 200);
  }
  gru_small_k<<<dim3(32,2),640,0,stream>>>(XS0, 900, enc_Whh, enc_bhh, VHYS, nullptr, 50);
  mask_att_k<<<dim3(64,32),256,0,stream>>>(SEC, VHYS, SSC, ADC);   // ssc, dsc(=ADC)

  // --- term bigru, time-sliced dual-dir chunks ---
  hipMemsetAsync(MTH, 0, 28800*4, stream);
  for (int L = 0; L < 2; L++){
    stage_mfma_k<<<dim3(11,64),256,0,stream>>>(DH, SSC, ADC,
        term_Wih, 900, 0, 300, 600,
        term_bih, nullptr, 0, 256*L,
        XS0, 1350, 900);
    stage_mfma_k<<<dim3(11,64),256,0,stream>>>(DH, SSC, ADC,
        term_Wih + (size_t)1350*900, 900, 0, 300, 600,
        term_bih + 1350, nullptr, 0, 256*(1-L),
        XS1, 1350, 900);
    gru_big_k<448,50,29,450,8><<<dim3(9,4,2),448,0,stream>>>(XS0, XS1,
        term_Whh, term_bhh, HBUF, HSEED, MTH, 900, 512u,
        512, 256, 256*L);
  }
  logits_k<<<32,128,0,stream>>>(MTH, nullptr, nullptr, 900, W_time, b_time, NTn, 900, OUTT);
}

// Round 8
// 12241.261 us; speedup vs baseline: 1.3587x; 1.3587x over previous
//
#include <hip/hip_runtime.h>
#include <stdint.h>
#include <math.h>

typedef unsigned int u32;
typedef unsigned long long u64;
typedef _Float16 f16;
typedef _Float16 h4 __attribute__((ext_vector_type(4)));
typedef _Float16 h2 __attribute__((ext_vector_type(2)));
typedef _Float16 h8 __attribute__((ext_vector_type(8)));
typedef float f4 __attribute__((ext_vector_type(4)));

// Problem constants
#define Vn     50000
#define DEMBn  200
#define Hn     150
#define NCn    119
#define NAn    103
#define NTn    11
#define Bn     32
#define Tn     512
#define LCn    50
#define LVn    50
#define ECn    600
#define EAn    500

#define IDIV 1073741824 // identity arow mapping

__device__ __forceinline__ float sigm(float x){ return 1.0f / (1.0f + expf(-x)); }

#if __has_builtin(__builtin_amdgcn_fdot2)
__device__ __forceinline__ float FDOT2(h2 a, h2 b, float c){
  return __builtin_amdgcn_fdot2(a, b, c, false);
}
#else
__device__ __forceinline__ float FDOT2(h2 a, h2 b, float c){
  return c + (float)a.x*(float)b.x + (float)a.y*(float)b.y;
}
#endif

// LLC-coherent agent-scope 64-bit ops (bypass non-coherent L1/L2).
__device__ __forceinline__ u64 llc_load64(const u64* p){
  return __hip_atomic_load(p, __ATOMIC_RELAXED, __HIP_MEMORY_SCOPE_AGENT);
}
__device__ __forceinline__ void llc_store64(u64* p, u64 v){
  __hip_atomic_store(p, v, __ATOMIC_RELAXED, __HIP_MEMORY_SCOPE_AGENT);
}

// ---------------------------------------------------------------------------
// Tiled fp32 GEMM (small/gather cases): C[M][N] = A[arow(m)][K] @ B[N][K]^T
// ---------------------------------------------------------------------------
template<int AMODE>
__global__ __launch_bounds__(256)
void gemm_k(const float* A0, const float* A1, const float* A2,
            const float* Etab, const int* tok,
            const float* Bm, int ldb, int bc0, int bc1, int bc2,
            const float* bias, const float* rowbias, int rb_div, int rb_stride,
            int arow_div, int arow_stride, int arow_off,
            float* C, int M, int N, int K)
{
  __shared__ float As[8][132];
  __shared__ float Bs[8][132];
  __shared__ int tokS[128];
  int tid = threadIdx.x;
  int m0 = blockIdx.y * 128, n0 = blockIdx.x * 128;
  if (AMODE == 1){
    for (int i = tid; i < 128; i += 256){
      int m = m0 + i;
      tokS[i] = (m < M) ? tok[m] : 0;
    }
  }
  __syncthreads();
  float acc[8][8];
  #pragma unroll
  for (int i=0;i<8;i++)
    #pragma unroll
    for (int j=0;j<8;j++) acc[i][j] = 0.f;

  int tx = tid & 15, ty = tid >> 4;

  for (int k0 = 0; k0 < K; k0 += 8){
    #pragma unroll
    for (int r = 0; r < 4; r++){
      int i = tid + 256*r;          // [0,1024)
      int ml = i >> 3, kl = i & 7;
      int k = k0 + kl;
      {
        int m = m0 + ml;
        float v = 0.f;
        if (m < M && k < K){
          if (AMODE == 0){
            int s = k / 300; int kk = k - s*300;
            const float* Ap = (s==0) ? A0 : ((s==1) ? A1 : A2);
            int ar = (m / arow_div)*arow_stride + (m % arow_div) + arow_off;
            v = Ap[(size_t)ar*300 + kk];
          } else {
            v = Etab[(size_t)tokS[ml]*DEMBn + k];
          }
        }
        As[kl][ml] = v;
      }
      {
        int n = n0 + ml;
        float v = 0.f;
        if (n < N && k < K){
          int col;
          if (AMODE == 0){ int s = k / 300; int kk = k - s*300; col = ((s==0)?bc0:((s==1)?bc1:bc2)) + kk; }
          else col = k;
          v = Bm[(size_t)n*ldb + col];
        }
        Bs[kl][ml] = v;
      }
    }
    __syncthreads();
    #pragma unroll
    for (int kk = 0; kk < 8; kk++){
      float a[8], b[8];
      #pragma unroll
      for (int i=0;i<8;i++) a[i] = As[kk][ty*8+i];
      #pragma unroll
      for (int i=0;i<8;i++) b[i] = Bs[kk][tx*8+i];
      #pragma unroll
      for (int i=0;i<8;i++)
        #pragma unroll
        for (int j=0;j<8;j++) acc[i][j] += a[i]*b[j];
    }
    __syncthreads();
  }
  #pragma unroll
  for (int i=0;i<8;i++){
    int m = m0 + ty*8 + i; if (m >= M) continue;
    #pragma unroll
    for (int j=0;j<8;j++){
      int n = n0 + tx*8 + j; if (n >= N) continue;
      float v = acc[i][j];
      if (bias)    v += bias[n];
      if (rowbias) v += rowbias[(size_t)(m / rb_div)*rb_stride + n];
      C[(size_t)m*N + n] = v;
    }
  }
}

// ---------------------------------------------------------------------------
// MFMA split-f16 staging GEMM for the big xs gemms (art/term).
// Precision: A=Ahi+Alo, B=Bhi+Blo (f16 split); acc += AhBh + AhBl + AlBh in
// f32 MFMA -> ~2^-22 relative error (f32-grade), at MFMA rates.
// ---------------------------------------------------------------------------
__global__ __launch_bounds__(256)
void stage_mfma_k(const float* A0, const float* A1, const float* A2,
                  const float* Bm, int ldb, int bc0, int bc1, int bc2,
                  const float* bias, const float* rowbias, int rb_stride,
                  int arow_off,
                  float* C, int N, int K)
{
  constexpr int KP = 40;                    // f16 row stride (80B: 16B-aligned rows)
  __shared__ __align__(16) f16 Ah[128*KP];
  __shared__ __align__(16) f16 Al[128*KP];
  __shared__ __align__(16) f16 Bh[128*KP];
  __shared__ __align__(16) f16 Bl[128*KP];

  int tid = threadIdx.x;
  int n0 = blockIdx.x * 128, m0 = blockIdx.y * 128;
  int lane = tid & 63, w = tid >> 6;
  int wr = (w >> 1) * 64, wc = (w & 1) * 64;   // wave tile origin in block tile
  int li = lane & 15, lk = (lane >> 4) * 8;

  f4 acc[4][4];
  #pragma unroll
  for (int i=0;i<4;i++)
    #pragma unroll
    for (int j=0;j<4;j++) acc[i][j] = (f4){0.f,0.f,0.f,0.f};

  int srow = tid >> 1, scb = (tid & 1) << 4;   // staging: row, col-base (16 k each)
  int sm = m0 + srow;
  size_t abase = (size_t)(((sm >> 8) * 512) + (sm & 255) + arow_off) * 300;
  int sn = n0 + srow;

  for (int k0 = 0; k0 < K; k0 += 32){
    // ---- stage A,B k-tile as hi/lo f16 ----
    #pragma unroll
    for (int q = 0; q < 16; q += 2){
      float va0=0.f, va1=0.f, vb0=0.f, vb1=0.f;
      int k = k0 + scb + q;
      if (k < K){
        int s = (k >= 600) ? 2 : ((k >= 300) ? 1 : 0);
        int kk = k - s*300;
        const float* Ap = (s==0) ? A0 : ((s==1) ? A1 : A2);
        va0 = Ap[abase + kk];
        if (sn < N) vb0 = Bm[(size_t)sn*ldb + ((s==0)?bc0:((s==1)?bc1:bc2)) + kk];
      }
      int k1 = k + 1;
      if (k1 < K){
        int s = (k1 >= 600) ? 2 : ((k1 >= 300) ? 1 : 0);
        int kk = k1 - s*300;
        const float* Ap = (s==0) ? A0 : ((s==1) ? A1 : A2);
        va1 = Ap[abase + kk];
        if (sn < N) vb1 = Bm[(size_t)sn*ldb + ((s==0)?bc0:((s==1)?bc1:bc2)) + kk];
      }
      f16 a0h=(f16)va0, a1h=(f16)va1, b0h=(f16)vb0, b1h=(f16)vb1;
      f16 a0l=(f16)(va0-(float)a0h), a1l=(f16)(va1-(float)a1h);
      f16 b0l=(f16)(vb0-(float)b0h), b1l=(f16)(vb1-(float)b1h);
      int off = srow*KP + scb + q;
      *(h2*)&Ah[off] = (h2){a0h, a1h};
      *(h2*)&Al[off] = (h2){a0l, a1l};
      *(h2*)&Bh[off] = (h2){b0h, b1h};
      *(h2*)&Bl[off] = (h2){b0l, b1l};
    }
    __syncthreads();

    // ---- fragments + 3-pass MFMA ----
    h8 fah[4], fal[4], fbh[4], fbl[4];
    #pragma unroll
    for (int f = 0; f < 4; f++){
      fah[f] = *(const h8*)&Ah[(wr + f*16 + li)*KP + lk];
      fal[f] = *(const h8*)&Al[(wr + f*16 + li)*KP + lk];
      fbh[f] = *(const h8*)&Bh[(wc + f*16 + li)*KP + lk];
      fbl[f] = *(const h8*)&Bl[(wc + f*16 + li)*KP + lk];
    }
    #pragma unroll
    for (int i = 0; i < 4; i++)
      #pragma unroll
      for (int j = 0; j < 4; j++){
        acc[i][j] = __builtin_amdgcn_mfma_f32_16x16x32_f16(fah[i], fbh[j], acc[i][j], 0,0,0);
        acc[i][j] = __builtin_amdgcn_mfma_f32_16x16x32_f16(fah[i], fbl[j], acc[i][j], 0,0,0);
        acc[i][j] = __builtin_amdgcn_mfma_f32_16x16x32_f16(fal[i], fbh[j], acc[i][j], 0,0,0);
      }
    __syncthreads();
  }

  // ---- epilogue ----
  #pragma unroll
  for (int i = 0; i < 4; i++){
    int r0 = m0 + wr + i*16 + (lane >> 4)*4;
    #pragma unroll
    for (int j = 0; j < 4; j++){
      int c = n0 + wc + j*16 + li;
      if (c < N){
        float badd = bias ? bias[c] : 0.f;
        #pragma unroll
        for (int r = 0; r < 4; r++){
          int row = r0 + r;
          float v = acc[i][j][r] + badd;
          if (rowbias) v += rowbias[(size_t)(row >> 8)*rb_stride + c];
          C[(size_t)row*N + c] = v;
        }
      }
    }
  }
}

// ---------------------------------------------------------------------------
// Small-GRU recurrence (H=150): one block per (seq, dir). 4 lanes/row,
// exact f32 weights in VGPRs, parity double-buffered h, 1 barrier/step.
// ---------------------------------------------------------------------------
__global__ __launch_bounds__(640)
void gru_small_k(const float* xs, int ncols,
                 const float* Whh, const float* bhh,
                 float* ys, float* meanOut, int T)
{
  constexpr int KSTEP = 38;                 // ceil(150/4)
  __shared__ __align__(16) float hl[2][152];
  int tid = threadIdx.x;
  int seq = blockIdx.x, dir = blockIdx.y;
  int row = tid >> 2, l = tid & 3;
  bool comp = (row < 150);
  int k0 = l * KSTEP;

  float w0[KSTEP], w1[KSTEP], w2[KSTEP];
  if (comp){
    const float* base = Whh + (size_t)dir*67500;
    const float* p0 = base + (size_t)(0*150 + row)*150;
    const float* p1 = base + (size_t)(1*150 + row)*150;
    const float* p2 = base + (size_t)(2*150 + row)*150;
    #pragma unroll
    for (int i=0;i<KSTEP;i++){
      int k = k0 + i;
      int kc = (k < 150) ? k : 0;
      float m = (k < 150) ? 1.f : 0.f;
      w0[i] = p0[kc]*m; w1[i] = p1[kc]*m; w2[i] = p2[kc]*m;
    }
  }
  float bR=0.f, bZ=0.f, bN=0.f;
  if (comp && l==0){
    bR = bhh[dir*450 + row];
    bZ = bhh[dir*450 + 150 + row];
    bN = bhh[dir*450 + 300 + row];
  }
  for (int i = tid; i < 2*152; i += 640) (&hl[0][0])[i] = 0.f;
  __syncthreads();

  float msum = 0.f;
  size_t rowbase = (size_t)seq * T;
  for (int tt = 0; tt < T; tt++){
    int t = dir ? (T-1-tt) : tt;
    int par = tt & 1;
    const float* hr = hl[par];
    float* hw = hl[1-par];

    float xr=0.f, xz=0.f, xn=0.f, hprev=0.f;
    if (comp && l==0){
      const float* xp = xs + (rowbase + t)*(size_t)ncols + dir*450;
      xr = xp[row]; xz = xp[150+row]; xn = xp[300+row];
      hprev = hr[row];
    }

    float a0=0.f, a1=0.f, a2=0.f;
    if (comp){
      #pragma unroll
      for (int i=0;i<KSTEP;i++){
        float hv = hr[k0 + i];
        a0 += w0[i]*hv; a1 += w1[i]*hv; a2 += w2[i]*hv;
      }
    }
    a0 += __shfl_xor(a0,1); a0 += __shfl_xor(a0,2);
    a1 += __shfl_xor(a1,1); a1 += __shfl_xor(a1,2);
    a2 += __shfl_xor(a2,1); a2 += __shfl_xor(a2,2);

    if (comp && l==0){
      float rr = sigm(xr + a0 + bR);
      float zz = sigm(xz + a1 + bZ);
      float nn = tanhf(xn + rr*(a2 + bN));
      float hn = (1.f - zz)*nn + zz*hprev;
      hw[row] = hn;
      msum += hn;
      if (ys) ys[(rowbase + t)*(size_t)300 + dir*150 + row] = hn;
    }
    __syncthreads();
  }
  if (meanOut && comp && l==0)
    meanOut[(size_t)seq*300 + dir*150 + row] = msum / (float)T;
}

// ---------------------------------------------------------------------------
// Big-GRU recurrence, BOTH dirs per launch, time-sliced. Weights in VGPRs,
// tagged-pair LLC h exchange, exact f32 hold + HSEED chunk reseed.
// R8: reverted to R6 partition (art 384thr/JB40/bg8, term 448thr/JB50/bg8)
// — R7's SB=8 showed the exchange wait scales with per-block message count
// (LLC-atomic issue/verify is the serial resource) + 100x bank conflicts.
// Small message sets + many blocks is the measured optimum.
// ---------------------------------------------------------------------------
template<int BLK, int JB, int KC, int Hh>
__global__ __launch_bounds__(BLK)
void gru_big_k(const float* xs0, const float* xs1,
               const float* Whh,         // [2][3*Hh][Hh] f32
               const float* bhh,         // [2][3*Hh]
               u64* hbuf,                // [2 parity][2 dir][B][Hh/2] tagged pairs
               float* hseed,             // [2 dir][B][Hh] exact f32 chunk seed
               float* meanOut, int mean_stride,
               u32 tagbase,
               int TT, int TC, int t0)
{
  constexpr int LPR   = 8;
  constexpr int KSTEP = 2*KC;
  constexpr int HS    = LPR*KSTEP;
  constexpr int HP    = Hh/2;
  constexpr int NPAIR = 4*HP;
  constexpr int RMAX  = (NPAIR + BLK - 1)/BLK;
  constexpr int H3    = 3*Hh;

  __shared__ __align__(16) f16 hstage[2][4*HS];

  int tid = threadIdx.x;
  int jc = blockIdx.x, bg = blockIdx.y, dir = blockIdx.z;
  int j0 = jc * JB;
  int row = tid >> 3, l = tid & 7;
  bool comp = (row < JB);
  int jg = j0 + row;
  int k0 = l * KSTEP;

  const float* Wd = Whh + (size_t)dir*H3*Hh;
  const float* xs = dir ? xs1 : xs0;
  int xoff = dir ? (TT - TC - t0) : t0;

  h2 w0[KC], w1[KC], w2[KC];
  if (comp){
    const float* p0 = Wd + ((size_t)0*Hh + jg)*(size_t)Hh;
    const float* p1 = Wd + ((size_t)1*Hh + jg)*(size_t)Hh;
    const float* p2 = Wd + ((size_t)2*Hh + jg)*(size_t)Hh;
    #pragma unroll
    for (int i=0;i<KC;i++){
      int k = k0 + 2*i;
      h2 a; a.x=(f16)0.f; a.y=(f16)0.f;
      h2 b = a, c = a;
      if (k < Hh){   a.x=(f16)p0[k];   b.x=(f16)p1[k];   c.x=(f16)p2[k]; }
      if (k+1 < Hh){ a.y=(f16)p0[k+1]; b.y=(f16)p1[k+1]; c.y=(f16)p2[k+1]; }
      w0[i]=a; w1[i]=b; w2[i]=c;
    }
  } else {
    #pragma unroll
    for (int i=0;i<KC;i++){
      h2 z; z.x=(f16)0.f; z.y=(f16)0.f;
      w0[i]=z; w1[i]=z; w2[i]=z;
    }
  }
  float br=0.f, bz=0.f, bn_=0.f;
  if (comp && l < 4){
    br = bhh[(size_t)dir*H3 + jg];
    bz = bhh[(size_t)dir*H3 + Hh + jg];
    bn_= bhh[(size_t)dir*H3 + 2*Hh + jg];
  }

  {
    f16* hz = &hstage[0][0];
    for (int i = tid; i < 2*4*HS; i += BLK) hz[i] = (f16)0.f;
  }

  float msum_own = 0.f;
  float hold_own = 0.f;                  // batch s = l ownership (l < 4)
  if (t0 > 0 && comp && l < 4){
    const float* hs = hseed + (size_t)dir*Bn*Hh;
    hold_own = hs[(size_t)(bg*4+l)*Hh + jg];
  }
  __syncthreads();

  for (int tt = 0; tt < TC; tt++){
    int g = t0 + tt;
    int t = dir ? (TT-1-g) : g;
    int par = g & 1;
    const u64* hrd = hbuf + (size_t)(par*2 + dir)*Bn*HP;
    u64*       hwr = hbuf + (size_t)((1-par)*2 + dir)*Bn*HP;
    f16* hsb = hstage[par];

    u64 tmp[RMAX];
    const u64* hb = hrd + (size_t)(bg*4)*HP;
    if (g != 0){
      #pragma unroll
      for (int r=0;r<RMAX;r++){
        int idx = tid + r*BLK;
        if (idx < NPAIR) tmp[r] = llc_load64(&hb[idx]);
      }
    }

    // xs prefetch: lane l<4 loads batch l only (3 loads, overlaps tag check)
    float xr=0.f, xz=0.f, xn=0.f;
    if (comp && l < 4){
      const float* xp = xs + ((size_t)(bg*4+l)*TC + (t - xoff))*(size_t)H3;
      xr = xp[jg]; xz = xp[Hh+jg]; xn = xp[2*Hh+jg];
    }

    if (g != 0){
      u32 want = tagbase + (u32)g;
      u32 pend = 0;
      #pragma unroll
      for (int r=0;r<RMAX;r++){
        int idx = tid + r*BLK;
        if (idx < NPAIR && (u32)(tmp[r] >> 32) != want) pend |= (1u << r);
      }
      int guard = 0;
      while (pend){
        __builtin_amdgcn_s_sleep(1);
        #pragma unroll
        for (int r=0;r<RMAX;r++)
          if (pend & (1u << r)) tmp[r] = llc_load64(&hb[tid + r*BLK]);
        #pragma unroll
        for (int r=0;r<RMAX;r++)
          if ((pend & (1u << r)) && (u32)(tmp[r] >> 32) == want) pend &= ~(1u << r);
        if (++guard > 200000) break;   // failsafe: wrong result > GPU hang
      }
      #pragma unroll
      for (int r=0;r<RMAX;r++){
        int idx = tid + r*BLK;
        if (idx < NPAIR){
          int s = idx / HP, jp = idx - s*HP;
          union { u32 i; h2 h; } u; u.i = (u32)tmp[r];
          *(h2*)(hsb + s*HS + 2*jp) = u.h;
        }
      }
    }
    __syncthreads();

    float a0[4]={0,0,0,0}, a1[4]={0,0,0,0}, a2[4]={0,0,0,0};
    if (comp){
      const f16* hp = hsb + k0;
      #pragma unroll
      for (int i=0;i<KC;i++){
        const int kk = 2*i;
        h2 hv0 = *(const h2*)(hp + 0*HS + kk);
        h2 hv1 = *(const h2*)(hp + 1*HS + kk);
        h2 hv2 = *(const h2*)(hp + 2*HS + kk);
        h2 hv3 = *(const h2*)(hp + 3*HS + kk);
        a0[0]=FDOT2(w0[i],hv0,a0[0]); a0[1]=FDOT2(w0[i],hv1,a0[1]);
        a0[2]=FDOT2(w0[i],hv2,a0[2]); a0[3]=FDOT2(w0[i],hv3,a0[3]);
        a1[0]=FDOT2(w1[i],hv0,a1[0]); a1[1]=FDOT2(w1[i],hv1,a1[1]);
        a1[2]=FDOT2(w1[i],hv2,a1[2]); a1[3]=FDOT2(w1[i],hv3,a1[3]);
        a2[0]=FDOT2(w2[i],hv0,a2[0]); a2[1]=FDOT2(w2[i],hv1,a2[1]);
        a2[2]=FDOT2(w2[i],hv2,a2[2]); a2[3]=FDOT2(w2[i],hv3,a2[3]);
      }
    }
    #pragma unroll
    for (int s=0;s<4;s++){
      a0[s] += __shfl_xor(a0[s],1); a0[s] += __shfl_xor(a0[s],2); a0[s] += __shfl_xor(a0[s],4);
      a1[s] += __shfl_xor(a1[s],1); a1[s] += __shfl_xor(a1[s],2); a1[s] += __shfl_xor(a1[s],4);
      a2[s] += __shfl_xor(a2[s],1); a2[s] += __shfl_xor(a2[s],2); a2[s] += __shfl_xor(a2[s],4);
    }
    // select own batch's sums via cndmask chain (no runtime array index)
    float t0a = (l & 1) ? a0[1] : a0[0], t0b = (l & 1) ? a0[3] : a0[2];
    float A0 = (l & 2) ? t0b : t0a;
    float t1a = (l & 1) ? a1[1] : a1[0], t1b = (l & 1) ? a1[3] : a1[2];
    float A1 = (l & 2) ? t1b : t1a;
    float t2a = (l & 1) ? a2[1] : a2[0], t2b = (l & 1) ? a2[3] : a2[2];
    float A2 = (l & 2) ? t2b : t2a;

    float hn_own = 0.f;
    if (comp && l < 4){
      float rr = sigm(xr + A0 + br);
      float zz = sigm(xz + A1 + bz);
      float nn = tanhf(xn + rr*(A2 + bn_));
      hn_own = (1.f - zz)*nn + zz*hold_own;
      hold_own = hn_own;
      msum_own += hn_own;
    }
    // pair adjacent rows: even row's lane l grabs odd row's hn (lane+8)
    u32 wtag = tagbase + (u32)g + 1u;
    float hp2 = __shfl_down(hn_own, 8);
    if (comp && l < 4 && !(row & 1)){
      h2 pk; pk.x = (f16)hn_own; pk.y = (f16)hp2;
      union { h2 h; u32 i; } u; u.h = pk;
      llc_store64(&hwr[(size_t)(bg*4+l)*HP + ((unsigned)(j0+row) >> 1)],
                  ((u64)wtag << 32) | (u64)u.i);
    }
    if (tt == TC-1 && comp && l < 4){
      float* hs = hseed + (size_t)dir*Bn*Hh;
      hs[(size_t)(bg*4+l)*Hh + jg] = hold_own;
    }
  }
  if (comp && l < 4){
    float* mp = meanOut + (size_t)(bg*4+l)*mean_stride + dir*Hh + jg;
    *mp += msum_own / (float)TT;
  }
}

// ---------------------------------------------------------------------------
// mask_att + fact_sep fused: per (b, 8-t chunk).
// R8: softmax + ratio sections parallelized — one 32-lane group per ttl row
// (shfl_xor masks <32 stay within the group). Each lane owns its own v/d
// elements, so no extra barriers.
// ---------------------------------------------------------------------------
__global__ __launch_bounds__(256)
void mask_att_k(const float* ctx, const float* vh, float* simOut, float* diffOut)
{
  __shared__ float vhl[50*300];
  __shared__ float ctxl[8*300];
  __shared__ float attl[8*52];
  __shared__ float scenl[8*300];
  __shared__ float ratio[8];
  int tid = threadIdx.x;
  int b = blockIdx.y, tc = blockIdx.x;
  int grp = tid >> 5, ln = tid & 31;        // 8 groups x 32 lanes
  size_t cbase = ((size_t)b*Tn + tc*8) * 300;
  for (int i = tid; i < 15000; i += 256) vhl[i] = vh[(size_t)b*15000 + i];
  for (int i = tid; i < 2400; i += 256)  ctxl[i] = ctx[cbase + i];
  __syncthreads();
  for (int p = tid; p < 400; p += 256){
    int ttl = p / 50, v = p % 50;
    const float* cp = ctxl + ttl*300;
    const float* vp = vhl + v*300;
    float acc = 0.f;
    for (int d = 0; d < 300; d++) acc += cp[d]*vp[d];
    attl[ttl*52 + v] = acc;
  }
  __syncthreads();
  // masked softmax over v=0..50 per row (group grp owns row grp)
  {
    float mx = -INFINITY;
    for (int v = ln; v < 50; v += 32){
      float a = attl[grp*52+v];
      float msk = (a == 0.f) ? -INFINITY : a;
      attl[grp*52+v] = msk;
      mx = fmaxf(mx, msk);
    }
    #pragma unroll
    for (int m=1; m<32; m<<=1) mx = fmaxf(mx, __shfl_xor(mx, m));
    if (mx == -INFINITY){
      for (int v = ln; v < 50; v += 32) attl[grp*52+v] = 0.f;
    } else {
      float sum = 0.f;
      for (int v = ln; v < 50; v += 32){
        float e = expf(attl[grp*52+v] - mx);
        attl[grp*52+v] = e;
        sum += e;
      }
      #pragma unroll
      for (int m=1; m<32; m<<=1) sum += __shfl_xor(sum, m);
      float inv = 1.f/sum;
      for (int v = ln; v < 50; v += 32) attl[grp*52+v] *= inv;
    }
  }
  __syncthreads();
  for (int p = tid; p < 2400; p += 256){
    int ttl = p / 300, d = p % 300;
    float acc = 0.f;
    for (int v=0; v<50; v++) acc += attl[ttl*52+v] * vhl[v*300+d];
    scenl[p] = acc;
  }
  __syncthreads();
  // ratio = <ctx,scen>/<scen,scen> per row, 32-lane parallel dot
  {
    float x3 = 0.f, x4 = 0.f;
    for (int d = ln; d < 300; d += 32){
      float s = scenl[grp*300+d];
      x3 += ctxl[grp*300+d]*s; x4 += s*s;
    }
    #pragma unroll
    for (int m=1; m<32; m<<=1){ x3 += __shfl_xor(x3, m); x4 += __shfl_xor(x4, m); }
    if (ln == 0) ratio[grp] = x3 / (x4 + 1e-10f);
  }
  __syncthreads();
  for (int p = tid; p < 2400; p += 256){
    float sim = ratio[p/300] * scenl[p];
    simOut[cbase + p]  = sim;
    diffOut[cbase + p] = ctxl[p] - sim;
  }
}

// ---------------------------------------------------------------------------
// code_wise helpers
// ---------------------------------------------------------------------------
__global__ void rowmax_k(const float* S, float* out, int M, int N){
  int row = blockIdx.x*4 + (threadIdx.x >> 6);
  int lane = threadIdx.x & 63;
  if (row >= M) return;
  float mx = -INFINITY;
  for (int n = lane; n < N; n += 64) mx = fmaxf(mx, S[(size_t)row*N + n]);
  for (int off = 32; off; off >>= 1) mx = fmaxf(mx, __shfl_xor(mx, off, 64));
  if (lane == 0) out[row] = mx;
}

__global__ __launch_bounds__(256)
void softmaxT_k(const float* m, float* att){
  __shared__ float red[256];
  int b = blockIdx.x, tid = threadIdx.x;
  float v1 = m[b*512 + tid], v2 = m[b*512 + 256 + tid];
  red[tid] = fmaxf(v1, v2); __syncthreads();
  for (int s=128; s; s>>=1){ if (tid<s) red[tid] = fmaxf(red[tid], red[tid+s]); __syncthreads(); }
  float M = red[0]; __syncthreads();
  float e1 = expf(v1-M), e2 = expf(v2-M);
  red[tid] = e1+e2; __syncthreads();
  for (int s=128; s; s>>=1){ if (tid<s) red[tid] += red[tid+s]; __syncthreads(); }
  float inv = 1.f / red[0];
  att[b*512+tid] = e1*inv; att[b*512+256+tid] = e2*inv;
}

__global__ __launch_bounds__(256)
void wsum_k(const float* att, const float* dh, float* out){
  int b = blockIdx.x, tid = threadIdx.x;
  for (int d = tid; d < 300; d += 256){
    float acc = 0.f;
    #pragma unroll 8
    for (int t = 0; t < 512; t++)
      acc += att[b*512+t] * dh[((size_t)b*512 + t)*300 + d];
    out[b*300+d] = acc;
  }
}

// ---------------------------------------------------------------------------
// graph_decomp helpers
// ---------------------------------------------------------------------------
__global__ void count_k(const int* src, int E, float* counts){
  int e = blockIdx.x*256 + threadIdx.x;
  if (e < E) atomicAdd(&counts[src[e]], 1.f);
}
__global__ void coef_k(const float* L, const int* src, const int* dst, int E, float* coef){
  int e = blockIdx.x*4 + (threadIdx.x >> 6);
  int lane = threadIdx.x & 63;
  if (e >= E) return;
  const float* Li = L + (size_t)src[e]*300;
  const float* Lj = L + (size_t)dst[e]*300;
  float num = 0.f, den = 0.f;
  for (int d = lane; d < 300; d += 64){ float lj = Lj[d]; num += Li[d]*lj; den += lj*lj; }
  for (int off = 32; off; off >>= 1){ num += __shfl_xor(num, off, 64); den += __shfl_xor(den, off, 64); }
  if (lane == 0) coef[e] = num / (den + 1e-10f);
}
__global__ void agg_k(const float* L, const int* src, const int* dst, const float* coef, int E, float* agg){
  int e = blockIdx.x;
  float c = coef[e];
  const float* Lj = L + (size_t)dst[e]*300;
  float* ag = agg + (size_t)src[e]*300;
  for (int d = threadIdx.x; d < 300; d += 256) atomicAdd(&ag[d], c*Lj[d]);
}
__global__ void upd_k(const float* L, const float* agg, const float* counts, float* out, int n){
  int i = blockIdx.x;
  float c = counts[i];
  for (int d = threadIdx.x; d < 300; d += 256){
    float v = L[(size_t)i*300+d];
    out[(size_t)i*300+d] = (c > 0.f) ? v - agg[(size_t)i*300+d]/fmaxf(c, 1.f) : v;
  }
}

// ---------------------------------------------------------------------------
// classifier heads, argmax, gather
// ---------------------------------------------------------------------------
__global__ __launch_bounds__(128)
void logits_k(const float* A0, const float* A1, const float* A2, int srcw,
              const float* W, const float* bias, int C, int K,
              float* outF){
  int b = blockIdx.x, tid = threadIdx.x;
  for (int c = tid; c < C; c += 128){
    float acc = bias[c];
    const float* wp = W + (size_t)c*K;
    for (int k = 0; k < K; k++){
      int s = k / srcw; int kk = k - s*srcw;
      const float* Ap = (s==0) ? A0 : ((s==1) ? A1 : A2);
      acc += Ap[(size_t)b*srcw + kk] * wp[k];
    }
    outF[b*C + c] = acc;
  }
}
__global__ void argmax_k(const float* lf, int C, int* pred){
  int b = threadIdx.x;
  if (b < 32){
    const float* p = lf + (size_t)b*C;
    int best = 0; float bv = p[0];
    for (int c = 1; c < C; c++){ float v = p[c]; if (v > bv){ bv = v; best = c; } }
    pred[b] = best;
  }
}
__global__ void vtok_k(const int* table, const int* pred, int* vt, int L){
  int i = blockIdx.x*256 + threadIdx.x;
  if (i < 32*L) vt[i] = table[pred[i/L]*L + i%L];
}

// ---------------------------------------------------------------------------
extern "C" void kernel_launch(void* const* d_in, const int* in_sizes, int n_in,
                              void* d_out, int out_size, void* d_ws, size_t ws_size,
                              hipStream_t stream)
{
  (void)in_sizes; (void)n_in; (void)out_size;
  const float* E        = (const float*)d_in[0];
  const int* chTok    = (const int*)d_in[1];
  const int* arTok    = (const int*)d_in[2];
  const int* docs     = (const int*)d_in[3];
  const int* chVerd   = (const int*)d_in[4];
  const int* arVerd   = (const int*)d_in[5];
  const int* c_src    = (const int*)d_in[6];
  const int* c_dst    = (const int*)d_in[7];
  const int* a_src    = (const int*)d_in[8];
  const int* a_dst    = (const int*)d_in[9];
  const float* enc_Wih  = (const float*)d_in[10];
  const float* enc_Whh  = (const float*)d_in[11];
  const float* enc_bih  = (const float*)d_in[12];
  const float* enc_bhh  = (const float*)d_in[13];
  const float* ech_Wih  = (const float*)d_in[14];
  const float* ech_Whh  = (const float*)d_in[15];
  const float* ech_bih  = (const float*)d_in[16];
  const float* ech_bhh  = (const float*)d_in[17];
  const float* term_Wih = (const float*)d_in[18];
  const float* term_Whh = (const float*)d_in[19];
  const float* term_bih = (const float*)d_in[20];
  const float* term_bhh = (const float*)d_in[21];
  const float* art_Wih  = (const float*)d_in[22];
  const float* art_Whh  = (const float*)d_in[23];
  const float* art_bih  = (const float*)d_in[24];
  const float* art_bhh  = (const float*)d_in[25];
  const float* W_charge = (const float*)d_in[26];
  const float* b_charge = (const float*)d_in[27];
  const float* W_article= (const float*)d_in[28];
  const float* b_article= (const float*)d_in[29];
  const float* W_time   = (const float*)d_in[30];
  const float* b_time   = (const float*)d_in[31];
  float* out = (float*)d_out;
  float* OUTC = out;            // [32][119]
  float* OUTA = out + 3808;     // [32][103]
  float* OUTT = out + 7104;     // [32][11]

  char* wsb = (char*)d_ws;
  size_t off = 0;
  auto alloc = [&](size_t nf)->float* {
    float* p = (float*)(wsb + off);
    off += ((nf*4 + 255) & ~(size_t)255);
    return p;
  };
  float* XS0   = alloc(14745600ULL);        // 59.0 MB
  float* XS1   = alloc(14745600ULL);        // 59.0 MB
  float* SBUF  = XS0;                       // alias: disjoint lifetime
  float* DH    = alloc(4915200);            // d_hidden [32][512][300]
  float* ADC   = alloc(4915200);            // adc, later dsc
  float* SEC   = alloc(4915200);
  float* SSC   = alloc(4915200);
  float* VHYS  = alloc(480000);             // [32][50][300]
  float* MECH  = alloc(66600);              // encch means [222][300]
  float* LC1   = alloc(35700);
  float* LC0   = alloc(35700);
  float* LA1   = alloc(30900);
  float* LA0   = alloc(30900);
  float* AGG   = alloc(35700);
  float* CNTS  = alloc(256);                // counts_c @0, counts_a @128
  float* COEF  = alloc(640);
  float* DHC   = alloc(9600);
  float* DA    = alloc(9600);
  float* DHNA  = alloc(9600);
  float* DB    = alloc(9600);
  float* MDH   = alloc(9600);               // mean_t d_hidden [32][300]
  float* MFA   = alloc(38400);              // fa mean [32][1200] (accumulated)
  float* MTH   = alloc(28800);              // th mean [32][900] (accumulated)
  float* RB    = alloc(115200);             // art rowbias [32][3600]
  float* RMX   = alloc(16384);
  float* ATTB  = alloc(16384);
  u64*   HBUF  = (u64*)alloc(76800);        // [2][2][32][300] u64 tagged pairs
  float* HSEED = alloc(38400);              // [2][32][600] exact f32 seeds
  int*   PREDC = (int*)alloc(64);
  int*   PREDA = (int*)alloc(64);
  int*   VTOK  = (int*)alloc(1600);
  int*   TCC   = (int*)alloc(11104);

  if (off > ws_size) return;   // diagnostic: leaves out==0 -> absmax==max|ref|

  hipMemsetAsync(HBUF, 0, 2*2*Bn*300*sizeof(u64), stream);  // tags = 0
  hipMemsetAsync(CNTS, 0, 256*4, stream);

  // --- encch on charge+article token sequences (222 seqs, L=50) ---
  hipMemcpyAsync(TCC, chTok, NCn*LCn*4, hipMemcpyDeviceToDevice, stream);
  hipMemcpyAsync(TCC + NCn*LCn, arTok, NAn*LCn*4, hipMemcpyDeviceToDevice, stream);
  {
    dim3 g((900+127)/128, (11100+127)/128);
    gemm_k<1><<<g,256,0,stream>>>(nullptr,nullptr,nullptr, E, TCC,
        ech_Wih, 200, 0,0,0, ech_bih, nullptr, 1, 1, IDIV,0,0,
        XS0, 11100, 900, 200);
  }
  gru_small_k<<<dim3(222,2),640,0,stream>>>(XS0, 900, ech_Whh, ech_bhh, nullptr, MECH, 50);

  // --- enc on documents ---
  {
    dim3 g((900+127)/128, (16384+127)/128);
    gemm_k<1><<<g,256,0,stream>>>(nullptr,nullptr,nullptr, E, docs,
        enc_Wih, 200, 0,0,0, enc_bih, nullptr, 1, 1, IDIV,0,0,
        XS0, 16384, 900, 200);
  }
  gru_small_k<<<dim3(32,2),640,0,stream>>>(XS0, 900, enc_Whh, enc_bhh, DH, MDH, 512);

  // --- graph_decomp (charge, article), 2 layers each ---
  count_k<<<3,256,0,stream>>>(c_src, ECn, CNTS);
  count_k<<<2,256,0,stream>>>(a_src, EAn, CNTS+128);
  coef_k<<<150,256,0,stream>>>(MECH, c_src, c_dst, ECn, COEF);
  hipMemsetAsync(AGG, 0, 35700*4, stream);
  agg_k<<<ECn,256,0,stream>>>(MECH, c_src, c_dst, COEF, ECn, AGG);
  upd_k<<<NCn,256,0,stream>>>(MECH, AGG, CNTS, LC1, NCn);
  coef_k<<<150,256,0,stream>>>(LC1, c_src, c_dst, ECn, COEF);
  hipMemsetAsync(AGG, 0, 35700*4, stream);
  agg_k<<<ECn,256,0,stream>>>(LC1, c_src, c_dst, COEF, ECn, AGG);
  upd_k<<<NCn,256,0,stream>>>(LC1, AGG, CNTS, LC0, NCn);

  const float* MEAR = MECH + (size_t)NCn*300;
  coef_k<<<125,256,0,stream>>>(MEAR, a_src, a_dst, EAn, COEF);
  hipMemsetAsync(AGG, 0, 30900*4, stream);
  agg_k<<<EAn,256,0,stream>>>(MEAR, a_src, a_dst, COEF, EAn, AGG);
  upd_k<<<NAn,256,0,stream>>>(MEAR, AGG, CNTS+128, LA1, NAn);
  coef_k<<<125,256,0,stream>>>(LA1, a_src, a_dst, EAn, COEF);
  hipMemsetAsync(AGG, 0, 30900*4, stream);
  agg_k<<<EAn,256,0,stream>>>(LA1, a_src, a_dst, COEF, EAn, AGG);
  upd_k<<<NAn,256,0,stream>>>(LA1, AGG, CNTS+128, LA0, NAn);

  // --- code_wise x4 (S-buffer aliased into XS0) ---
  auto codewise = [&](const float* q, int Nq, float* outv){
    dim3 g((Nq+127)/128, 128);
    gemm_k<0><<<g,256,0,stream>>>(DH, nullptr, nullptr, nullptr, nullptr,
        q, 300, 0,0,0, nullptr, nullptr, 1, 1, IDIV,0,0,
        SBUF, 16384, Nq, 300);
    rowmax_k<<<4096,256,0,stream>>>(SBUF, RMX, 16384, Nq);
    softmaxT_k<<<32,256,0,stream>>>(RMX, ATTB);
    wsum_k<<<32,256,0,stream>>>(ATTB, DH, outv);
  };
  codewise(LC0,  NCn, DHC);    // new_charge
  codewise(MECH, NCn, DA);     // ori charge
  codewise(LA0,  NAn, DHNA);   // new_article
  codewise(MEAR, NAn, DB);     // ori article

  // --- charge head ---
  logits_k<<<32,128,0,stream>>>(MDH, DHC, DA, 300, W_charge, b_charge, NCn, 900, OUTC);
  argmax_k<<<1,64,0,stream>>>(OUTC, NCn, PREDC);

  // --- fact_sep #1 ---
  vtok_k<<<7,256,0,stream>>>(chVerd, PREDC, VTOK, LVn);
  {
    dim3 g((900+127)/128, (1600+127)/128);
    gemm_k<1><<<g,256,0,stream>>>(nullptr,nullptr,nullptr, E, VTOK,
        enc_Wih, 200, 0,0,0, enc_bih, nullptr, 1, 1, IDIV,0,0,
        XS0, 1600, 900, 200);
  }
  gru_small_k<<<dim3(32,2),640,0,stream>>>(XS0, 900, enc_Whh, enc_bhh, VHYS, nullptr, 50);
  mask_att_k<<<dim3(64,32),256,0,stream>>>(DH, VHYS, ADC, SEC);

  // --- article bigru: rowbias, then time-sliced dual-dir chunks ---
  {
    dim3 g((3600+127)/128, 1);
    gemm_k<0><<<g,256,0,stream>>>(DHNA, DB, nullptr, nullptr, nullptr,
        art_Wih, 1200, 300, 900, 0, art_bih, nullptr, 1, 1, IDIV,0,0,
        RB, 32, 3600, 600);
  }
  hipMemsetAsync(MFA, 0, 38400*4, stream);
  for (int L = 0; L < 2; L++){
    stage_mfma_k<<<dim3(15,64),256,0,stream>>>(DH, ADC, nullptr,
        art_Wih, 1200, 0, 600, 0,
        nullptr, RB, 3600, 256*L,
        XS0, 1800, 600);
    stage_mfma_k<<<dim3(15,64),256,0,stream>>>(DH, ADC, nullptr,
        art_Wih + (size_t)1800*1200, 1200, 0, 600, 0,
        nullptr, RB + 1800, 3600, 256*(1-L),
        XS1, 1800, 600);
    gru_big_k<384,40,38,600><<<dim3(15,8,2),384,0,stream>>>(XS0, XS1,
        art_Whh, art_bhh, HBUF, HSEED, MFA, 1200, 0u,
        512, 256, 256*L);
  }
  logits_k<<<32,128,0,stream>>>(MFA, nullptr, nullptr, 1200, W_article, b_article, NAn, 1200, OUTA);
  argmax_k<<<1,64,0,stream>>>(OUTA, NAn, PREDA);

  // --- fact_sep #2 (context = sec_vector) ---
  vtok_k<<<7,256,0,stream>>>(arVerd, PREDA, VTOK, LVn);
  {
    dim3 g((900+127)/128, (1600+127)/128);
    gemm_k<1><<<g,256,0,stream>>>(nullptr,nullptr,nullptr, E, VTOK,
        enc_Wih, 200, 0,0,0, enc_bih, nullptr, 1, 1, IDIV,0,0,
        XS0, 1600, 900, 200);
  }
  gru_small_k<<<dim3(32,2),640,0,stream>>>(XS0, 900, enc_Whh, enc_bhh, VHYS, nullptr, 50);
  mask_att_k<<<dim3(64,32),256,0,stream>>>(SEC, VHYS, SSC, ADC);   // ssc, dsc(=ADC)

  // --- term bigru, time-sliced dual-dir chunks ---
  hipMemsetAsync(MTH, 0, 28800*4, stream);
  for (int L = 0; L < 2; L++){
    stage_mfma_k<<<dim3(11,64),256,0,stream>>>(DH, SSC, ADC,
        term_Wih, 900, 0, 300, 600,
        term_bih, nullptr, 0, 256*L,
        XS0, 1350, 900);
    stage_mfma_k<<<dim3(11,64),256,0,stream>>>(DH, SSC, ADC,
        term_Wih + (size_t)1350*900, 900, 0, 300, 600,
        term_bih + 1350, nullptr, 0, 256*(1-L),
        XS1, 1350, 900);
    gru_big_k<448,50,29,450><<<dim3(9,8,2),448,0,stream>>>(XS0, XS1,
        term_Whh, term_bhh, HBUF, HSEED, MTH, 900, 512u,
        512, 256, 256*L);
  }
  logits_k<<<32,128,0,stream>>>(MTH, nullptr, nullptr, 900, W_time, b_time, NTn, 900, OUTT);
}

// Round 9
// 11854.169 us; speedup vs baseline: 1.4030x; 1.0327x over previous
//
#include <hip/hip_runtime.h>
#include <stdint.h>
#include <math.h>

typedef unsigned int u32;
typedef unsigned long long u64;
typedef _Float16 f16;
typedef _Float16 h4 __attribute__((ext_vector_type(4)));
typedef _Float16 h2 __attribute__((ext_vector_type(2)));
typedef _Float16 h8 __attribute__((ext_vector_type(8)));
typedef float f4 __attribute__((ext_vector_type(4)));

// Problem constants
#define Vn     50000
#define DEMBn  200
#define Hn     150
#define NCn    119
#define NAn    103
#define NTn    11
#define Bn     32
#define Tn     512
#define LCn    50
#define LVn    50
#define ECn    600
#define EAn    500

#define IDIV 1073741824 // identity arow mapping

__device__ __forceinline__ float sigm(float x){ return 1.0f / (1.0f + expf(-x)); }

#if __has_builtin(__builtin_amdgcn_fdot2)
__device__ __forceinline__ float FDOT2(h2 a, h2 b, float c){
  return __builtin_amdgcn_fdot2(a, b, c, false);
}
#else
__device__ __forceinline__ float FDOT2(h2 a, h2 b, float c){
  return c + (float)a.x*(float)b.x + (float)a.y*(float)b.y;
}
#endif

// LLC-coherent agent-scope 64-bit ops (bypass non-coherent L1/L2).
__device__ __forceinline__ u64 llc_load64(const u64* p){
  return __hip_atomic_load(p, __ATOMIC_RELAXED, __HIP_MEMORY_SCOPE_AGENT);
}
__device__ __forceinline__ void llc_store64(u64* p, u64 v){
  __hip_atomic_store(p, v, __ATOMIC_RELAXED, __HIP_MEMORY_SCOPE_AGENT);
}

// ---------------------------------------------------------------------------
// Tiled fp32 GEMM (small cases): C[M][N] = A[arow(m)][K] @ B[N][K]^T
// ---------------------------------------------------------------------------
template<int AMODE>
__global__ __launch_bounds__(256)
void gemm_k(const float* A0, const float* A1, const float* A2,
            const float* Etab, const int* tok,
            const float* Bm, int ldb, int bc0, int bc1, int bc2,
            const float* bias, const float* rowbias, int rb_div, int rb_stride,
            int arow_div, int arow_stride, int arow_off,
            float* C, int M, int N, int K)
{
  __shared__ float As[8][132];
  __shared__ float Bs[8][132];
  __shared__ int tokS[128];
  int tid = threadIdx.x;
  int m0 = blockIdx.y * 128, n0 = blockIdx.x * 128;
  if (AMODE == 1){
    for (int i = tid; i < 128; i += 256){
      int m = m0 + i;
      tokS[i] = (m < M) ? tok[m] : 0;
    }
  }
  __syncthreads();
  float acc[8][8];
  #pragma unroll
  for (int i=0;i<8;i++)
    #pragma unroll
    for (int j=0;j<8;j++) acc[i][j] = 0.f;

  int tx = tid & 15, ty = tid >> 4;

  for (int k0 = 0; k0 < K; k0 += 8){
    #pragma unroll
    for (int r = 0; r < 4; r++){
      int i = tid + 256*r;          // [0,1024)
      int ml = i >> 3, kl = i & 7;
      int k = k0 + kl;
      {
        int m = m0 + ml;
        float v = 0.f;
        if (m < M && k < K){
          if (AMODE == 0){
            int s = k / 300; int kk = k - s*300;
            const float* Ap = (s==0) ? A0 : ((s==1) ? A1 : A2);
            int ar = (m / arow_div)*arow_stride + (m % arow_div) + arow_off;
            v = Ap[(size_t)ar*300 + kk];
          } else {
            v = Etab[(size_t)tokS[ml]*DEMBn + k];
          }
        }
        As[kl][ml] = v;
      }
      {
        int n = n0 + ml;
        float v = 0.f;
        if (n < N && k < K){
          int col;
          if (AMODE == 0){ int s = k / 300; int kk = k - s*300; col = ((s==0)?bc0:((s==1)?bc1:bc2)) + kk; }
          else col = k;
          v = Bm[(size_t)n*ldb + col];
        }
        Bs[kl][ml] = v;
      }
    }
    __syncthreads();
    #pragma unroll
    for (int kk = 0; kk < 8; kk++){
      float a[8], b[8];
      #pragma unroll
      for (int i=0;i<8;i++) a[i] = As[kk][ty*8+i];
      #pragma unroll
      for (int i=0;i<8;i++) b[i] = Bs[kk][tx*8+i];
      #pragma unroll
      for (int i=0;i<8;i++)
        #pragma unroll
        for (int j=0;j<8;j++) acc[i][j] += a[i]*b[j];
    }
    __syncthreads();
  }
  #pragma unroll
  for (int i=0;i<8;i++){
    int m = m0 + ty*8 + i; if (m >= M) continue;
    #pragma unroll
    for (int j=0;j<8;j++){
      int n = n0 + tx*8 + j; if (n >= N) continue;
      float v = acc[i][j];
      if (bias)    v += bias[n];
      if (rowbias) v += rowbias[(size_t)(m / rb_div)*rb_stride + n];
      C[(size_t)m*N + n] = v;
    }
  }
}

// ---------------------------------------------------------------------------
// MFMA split-f16 staging GEMM for the big xs gemms (art/term).
// Precision: A=Ahi+Alo, B=Bhi+Blo (f16 split); acc += AhBh + AhBl + AlBh in
// f32 MFMA -> ~2^-22 relative error (f32-grade), at MFMA rates.
// ---------------------------------------------------------------------------
__global__ __launch_bounds__(256)
void stage_mfma_k(const float* A0, const float* A1, const float* A2,
                  const float* Bm, int ldb, int bc0, int bc1, int bc2,
                  const float* bias, const float* rowbias, int rb_stride,
                  int arow_off,
                  float* C, int N, int K)
{
  constexpr int KP = 40;                    // f16 row stride (80B: 16B-aligned rows)
  __shared__ __align__(16) f16 Ah[128*KP];
  __shared__ __align__(16) f16 Al[128*KP];
  __shared__ __align__(16) f16 Bh[128*KP];
  __shared__ __align__(16) f16 Bl[128*KP];

  int tid = threadIdx.x;
  int n0 = blockIdx.x * 128, m0 = blockIdx.y * 128;
  int lane = tid & 63, w = tid >> 6;
  int wr = (w >> 1) * 64, wc = (w & 1) * 64;   // wave tile origin in block tile
  int li = lane & 15, lk = (lane >> 4) * 8;

  f4 acc[4][4];
  #pragma unroll
  for (int i=0;i<4;i++)
    #pragma unroll
    for (int j=0;j<4;j++) acc[i][j] = (f4){0.f,0.f,0.f,0.f};

  int srow = tid >> 1, scb = (tid & 1) << 4;   // staging: row, col-base (16 k each)
  int sm = m0 + srow;
  size_t abase = (size_t)(((sm >> 8) * 512) + (sm & 255) + arow_off) * 300;
  int sn = n0 + srow;

  for (int k0 = 0; k0 < K; k0 += 32){
    // ---- stage A,B k-tile as hi/lo f16 ----
    #pragma unroll
    for (int q = 0; q < 16; q += 2){
      float va0=0.f, va1=0.f, vb0=0.f, vb1=0.f;
      int k = k0 + scb + q;
      if (k < K){
        int s = (k >= 600) ? 2 : ((k >= 300) ? 1 : 0);
        int kk = k - s*300;
        const float* Ap = (s==0) ? A0 : ((s==1) ? A1 : A2);
        va0 = Ap[abase + kk];
        if (sn < N) vb0 = Bm[(size_t)sn*ldb + ((s==0)?bc0:((s==1)?bc1:bc2)) + kk];
      }
      int k1 = k + 1;
      if (k1 < K){
        int s = (k1 >= 600) ? 2 : ((k1 >= 300) ? 1 : 0);
        int kk = k1 - s*300;
        const float* Ap = (s==0) ? A0 : ((s==1) ? A1 : A2);
        va1 = Ap[abase + kk];
        if (sn < N) vb1 = Bm[(size_t)sn*ldb + ((s==0)?bc0:((s==1)?bc1:bc2)) + kk];
      }
      f16 a0h=(f16)va0, a1h=(f16)va1, b0h=(f16)vb0, b1h=(f16)vb1;
      f16 a0l=(f16)(va0-(float)a0h), a1l=(f16)(va1-(float)a1h);
      f16 b0l=(f16)(vb0-(float)b0h), b1l=(f16)(vb1-(float)b1h);
      int off = srow*KP + scb + q;
      *(h2*)&Ah[off] = (h2){a0h, a1h};
      *(h2*)&Al[off] = (h2){a0l, a1l};
      *(h2*)&Bh[off] = (h2){b0h, b1h};
      *(h2*)&Bl[off] = (h2){b0l, b1l};
    }
    __syncthreads();

    // ---- fragments + 3-pass MFMA ----
    h8 fah[4], fal[4], fbh[4], fbl[4];
    #pragma unroll
    for (int f = 0; f < 4; f++){
      fah[f] = *(const h8*)&Ah[(wr + f*16 + li)*KP + lk];
      fal[f] = *(const h8*)&Al[(wr + f*16 + li)*KP + lk];
      fbh[f] = *(const h8*)&Bh[(wc + f*16 + li)*KP + lk];
      fbl[f] = *(const h8*)&Bl[(wc + f*16 + li)*KP + lk];
    }
    #pragma unroll
    for (int i = 0; i < 4; i++)
      #pragma unroll
      for (int j = 0; j < 4; j++){
        acc[i][j] = __builtin_amdgcn_mfma_f32_16x16x32_f16(fah[i], fbh[j], acc[i][j], 0,0,0);
        acc[i][j] = __builtin_amdgcn_mfma_f32_16x16x32_f16(fah[i], fbl[j], acc[i][j], 0,0,0);
        acc[i][j] = __builtin_amdgcn_mfma_f32_16x16x32_f16(fal[i], fbh[j], acc[i][j], 0,0,0);
      }
    __syncthreads();
  }

  // ---- epilogue ----
  #pragma unroll
  for (int i = 0; i < 4; i++){
    int r0 = m0 + wr + i*16 + (lane >> 4)*4;
    #pragma unroll
    for (int j = 0; j < 4; j++){
      int c = n0 + wc + j*16 + li;
      if (c < N){
        float badd = bias ? bias[c] : 0.f;
        #pragma unroll
        for (int r = 0; r < 4; r++){
          int row = r0 + r;
          float v = acc[i][j][r] + badd;
          if (rowbias) v += rowbias[(size_t)(row >> 8)*rb_stride + c];
          C[(size_t)row*N + c] = v;
        }
      }
    }
  }
}

// ---------------------------------------------------------------------------
// MFMA split-f16 embedding-gather GEMM: C[m][n] = E[tok[m]][:K] . B[n][:K] + bias[n]
// Same verified 3-pass split-f16 structure; A row gathered via tok, M/N guards.
// ---------------------------------------------------------------------------
__global__ __launch_bounds__(256)
void embed_mfma_k(const float* Etab, const int* tok,
                  const float* Bm, const float* bias,
                  float* C, int M, int N, int K)
{
  constexpr int KP = 40;
  __shared__ __align__(16) f16 Ah[128*KP];
  __shared__ __align__(16) f16 Al[128*KP];
  __shared__ __align__(16) f16 Bh[128*KP];
  __shared__ __align__(16) f16 Bl[128*KP];
  __shared__ int tokS[128];

  int tid = threadIdx.x;
  int n0 = blockIdx.x * 128, m0 = blockIdx.y * 128;
  int lane = tid & 63, w = tid >> 6;
  int wr = (w >> 1) * 64, wc = (w & 1) * 64;
  int li = lane & 15, lk = (lane >> 4) * 8;

  for (int i = tid; i < 128; i += 256){
    int m = m0 + i;
    tokS[i] = (m < M) ? tok[m] : 0;
  }
  __syncthreads();

  f4 acc[4][4];
  #pragma unroll
  for (int i=0;i<4;i++)
    #pragma unroll
    for (int j=0;j<4;j++) acc[i][j] = (f4){0.f,0.f,0.f,0.f};

  int srow = tid >> 1, scb = (tid & 1) << 4;
  size_t abase = (size_t)tokS[srow] * (size_t)K;
  int sn = n0 + srow;

  for (int k0 = 0; k0 < K; k0 += 32){
    #pragma unroll
    for (int q = 0; q < 16; q += 2){
      float va0=0.f, va1=0.f, vb0=0.f, vb1=0.f;
      int k = k0 + scb + q;
      if (k < K){
        va0 = Etab[abase + k];
        if (sn < N) vb0 = Bm[(size_t)sn*K + k];
      }
      if (k + 1 < K){
        va1 = Etab[abase + k + 1];
        if (sn < N) vb1 = Bm[(size_t)sn*K + k + 1];
      }
      f16 a0h=(f16)va0, a1h=(f16)va1, b0h=(f16)vb0, b1h=(f16)vb1;
      f16 a0l=(f16)(va0-(float)a0h), a1l=(f16)(va1-(float)a1h);
      f16 b0l=(f16)(vb0-(float)b0h), b1l=(f16)(vb1-(float)b1h);
      int off = srow*KP + scb + q;
      *(h2*)&Ah[off] = (h2){a0h, a1h};
      *(h2*)&Al[off] = (h2){a0l, a1l};
      *(h2*)&Bh[off] = (h2){b0h, b1h};
      *(h2*)&Bl[off] = (h2){b0l, b1l};
    }
    __syncthreads();

    h8 fah[4], fal[4], fbh[4], fbl[4];
    #pragma unroll
    for (int f = 0; f < 4; f++){
      fah[f] = *(const h8*)&Ah[(wr + f*16 + li)*KP + lk];
      fal[f] = *(const h8*)&Al[(wr + f*16 + li)*KP + lk];
      fbh[f] = *(const h8*)&Bh[(wc + f*16 + li)*KP + lk];
      fbl[f] = *(const h8*)&Bl[(wc + f*16 + li)*KP + lk];
    }
    #pragma unroll
    for (int i = 0; i < 4; i++)
      #pragma unroll
      for (int j = 0; j < 4; j++){
        acc[i][j] = __builtin_amdgcn_mfma_f32_16x16x32_f16(fah[i], fbh[j], acc[i][j], 0,0,0);
        acc[i][j] = __builtin_amdgcn_mfma_f32_16x16x32_f16(fah[i], fbl[j], acc[i][j], 0,0,0);
        acc[i][j] = __builtin_amdgcn_mfma_f32_16x16x32_f16(fal[i], fbh[j], acc[i][j], 0,0,0);
      }
    __syncthreads();
  }

  #pragma unroll
  for (int i = 0; i < 4; i++){
    int r0 = m0 + wr + i*16 + (lane >> 4)*4;
    #pragma unroll
    for (int j = 0; j < 4; j++){
      int c = n0 + wc + j*16 + li;
      if (c < N){
        float badd = bias ? bias[c] : 0.f;
        #pragma unroll
        for (int r = 0; r < 4; r++){
          int row = r0 + r;
          if (row < M) C[(size_t)row*N + c] = acc[i][j][r] + badd;
        }
      }
    }
  }
}

// ---------------------------------------------------------------------------
// Small-GRU recurrence (H=150): one block per (seq, dir). 4 lanes/row,
// exact f32 weights in VGPRs, parity double-buffered h, 1 barrier/step.
// ---------------------------------------------------------------------------
__global__ __launch_bounds__(640)
void gru_small_k(const float* xs, int ncols,
                 const float* Whh, const float* bhh,
                 float* ys, float* meanOut, int T)
{
  constexpr int KSTEP = 38;                 // ceil(150/4)
  __shared__ __align__(16) float hl[2][152];
  int tid = threadIdx.x;
  int seq = blockIdx.x, dir = blockIdx.y;
  int row = tid >> 2, l = tid & 3;
  bool comp = (row < 150);
  int k0 = l * KSTEP;

  float w0[KSTEP], w1[KSTEP], w2[KSTEP];
  if (comp){
    const float* base = Whh + (size_t)dir*67500;
    const float* p0 = base + (size_t)(0*150 + row)*150;
    const float* p1 = base + (size_t)(1*150 + row)*150;
    const float* p2 = base + (size_t)(2*150 + row)*150;
    #pragma unroll
    for (int i=0;i<KSTEP;i++){
      int k = k0 + i;
      int kc = (k < 150) ? k : 0;
      float m = (k < 150) ? 1.f : 0.f;
      w0[i] = p0[kc]*m; w1[i] = p1[kc]*m; w2[i] = p2[kc]*m;
    }
  }
  float bR=0.f, bZ=0.f, bN=0.f;
  if (comp && l==0){
    bR = bhh[dir*450 + row];
    bZ = bhh[dir*450 + 150 + row];
    bN = bhh[dir*450 + 300 + row];
  }
  for (int i = tid; i < 2*152; i += 640) (&hl[0][0])[i] = 0.f;
  __syncthreads();

  float msum = 0.f;
  size_t rowbase = (size_t)seq * T;
  for (int tt = 0; tt < T; tt++){
    int t = dir ? (T-1-tt) : tt;
    int par = tt & 1;
    const float* hr = hl[par];
    float* hw = hl[1-par];

    float xr=0.f, xz=0.f, xn=0.f, hprev=0.f;
    if (comp && l==0){
      const float* xp = xs + (rowbase + t)*(size_t)ncols + dir*450;
      xr = xp[row]; xz = xp[150+row]; xn = xp[300+row];
      hprev = hr[row];
    }

    float a0=0.f, a1=0.f, a2=0.f;
    if (comp){
      #pragma unroll
      for (int i=0;i<KSTEP;i++){
        float hv = hr[k0 + i];
        a0 += w0[i]*hv; a1 += w1[i]*hv; a2 += w2[i]*hv;
      }
    }
    a0 += __shfl_xor(a0,1); a0 += __shfl_xor(a0,2);
    a1 += __shfl_xor(a1,1); a1 += __shfl_xor(a1,2);
    a2 += __shfl_xor(a2,1); a2 += __shfl_xor(a2,2);

    if (comp && l==0){
      float rr = sigm(xr + a0 + bR);
      float zz = sigm(xz + a1 + bZ);
      float nn = tanhf(xn + rr*(a2 + bN));
      float hn = (1.f - zz)*nn + zz*hprev;
      hw[row] = hn;
      msum += hn;
      if (ys) ys[(rowbase + t)*(size_t)300 + dir*150 + row] = hn;
    }
    __syncthreads();
  }
  if (meanOut && comp && l==0)
    meanOut[(size_t)seq*300 + dir*150 + row] = msum / (float)T;
}

// ---------------------------------------------------------------------------
// Big-GRU recurrence, BOTH dirs per launch, time-sliced. Weights in VGPRs
// (unified AGPR file), tagged-pair LLC h exchange, exact f32 hold + HSEED.
// R6-measured-best partition: small per-block message sets, many blocks.
// ---------------------------------------------------------------------------
template<int BLK, int JB, int KC, int Hh>
__global__ __launch_bounds__(BLK)
void gru_big_k(const float* xs0, const float* xs1,
               const float* Whh,         // [2][3*Hh][Hh] f32
               const float* bhh,         // [2][3*Hh]
               u64* hbuf,                // [2 parity][2 dir][B][Hh/2] tagged pairs
               float* hseed,             // [2 dir][B][Hh] exact f32 chunk seed
               float* meanOut, int mean_stride,
               u32 tagbase,
               int TT, int TC, int t0)
{
  constexpr int LPR   = 8;
  constexpr int KSTEP = 2*KC;
  constexpr int HS    = LPR*KSTEP;
  constexpr int HP    = Hh/2;
  constexpr int NPAIR = 4*HP;
  constexpr int RMAX  = (NPAIR + BLK - 1)/BLK;
  constexpr int H3    = 3*Hh;

  __shared__ __align__(16) f16 hstage[2][4*HS];

  int tid = threadIdx.x;
  int jc = blockIdx.x, bg = blockIdx.y, dir = blockIdx.z;
  int j0 = jc * JB;
  int row = tid >> 3, l = tid & 7;
  bool comp = (row < JB);
  int jg = j0 + row;
  int k0 = l * KSTEP;

  const float* Wd = Whh + (size_t)dir*H3*Hh;
  const float* xs = dir ? xs1 : xs0;
  int xoff = dir ? (TT - TC - t0) : t0;

  h2 w0[KC], w1[KC], w2[KC];
  if (comp){
    const float* p0 = Wd + ((size_t)0*Hh + jg)*(size_t)Hh;
    const float* p1 = Wd + ((size_t)1*Hh + jg)*(size_t)Hh;
    const float* p2 = Wd + ((size_t)2*Hh + jg)*(size_t)Hh;
    #pragma unroll
    for (int i=0;i<KC;i++){
      int k = k0 + 2*i;
      h2 a; a.x=(f16)0.f; a.y=(f16)0.f;
      h2 b = a, c = a;
      if (k < Hh){   a.x=(f16)p0[k];   b.x=(f16)p1[k];   c.x=(f16)p2[k]; }
      if (k+1 < Hh){ a.y=(f16)p0[k+1]; b.y=(f16)p1[k+1]; c.y=(f16)p2[k+1]; }
      w0[i]=a; w1[i]=b; w2[i]=c;
    }
  } else {
    #pragma unroll
    for (int i=0;i<KC;i++){
      h2 z; z.x=(f16)0.f; z.y=(f16)0.f;
      w0[i]=z; w1[i]=z; w2[i]=z;
    }
  }
  float br=0.f, bz=0.f, bn_=0.f;
  if (comp && l < 4){
    br = bhh[(size_t)dir*H3 + jg];
    bz = bhh[(size_t)dir*H3 + Hh + jg];
    bn_= bhh[(size_t)dir*H3 + 2*Hh + jg];
  }

  {
    f16* hz = &hstage[0][0];
    for (int i = tid; i < 2*4*HS; i += BLK) hz[i] = (f16)0.f;
  }

  float msum_own = 0.f;
  float hold_own = 0.f;                  // batch s = l ownership (l < 4)
  if (t0 > 0 && comp && l < 4){
    const float* hs = hseed + (size_t)dir*Bn*Hh;
    hold_own = hs[(size_t)(bg*4+l)*Hh + jg];
  }
  __syncthreads();

  for (int tt = 0; tt < TC; tt++){
    int g = t0 + tt;
    int t = dir ? (TT-1-g) : g;
    int par = g & 1;
    const u64* hrd = hbuf + (size_t)(par*2 + dir)*Bn*HP;
    u64*       hwr = hbuf + (size_t)((1-par)*2 + dir)*Bn*HP;
    f16* hsb = hstage[par];

    u64 tmp[RMAX];
    const u64* hb = hrd + (size_t)(bg*4)*HP;
    if (g != 0){
      #pragma unroll
      for (int r=0;r<RMAX;r++){
        int idx = tid + r*BLK;
        if (idx < NPAIR) tmp[r] = llc_load64(&hb[idx]);
      }
    }

    // xs prefetch: lane l<4 loads batch l only (3 loads, overlaps tag check)
    float xr=0.f, xz=0.f, xn=0.f;
    if (comp && l < 4){
      const float* xp = xs + ((size_t)(bg*4+l)*TC + (t - xoff))*(size_t)H3;
      xr = xp[jg]; xz = xp[Hh+jg]; xn = xp[2*Hh+jg];
    }

    if (g != 0){
      u32 want = tagbase + (u32)g;
      u32 pend = 0;
      #pragma unroll
      for (int r=0;r<RMAX;r++){
        int idx = tid + r*BLK;
        if (idx < NPAIR && (u32)(tmp[r] >> 32) != want) pend |= (1u << r);
      }
      int guard = 0;
      while (pend){
        __builtin_amdgcn_s_sleep(1);
        #pragma unroll
        for (int r=0;r<RMAX;r++)
          if (pend & (1u << r)) tmp[r] = llc_load64(&hb[tid + r*BLK]);
        #pragma unroll
        for (int r=0;r<RMAX;r++)
          if ((pend & (1u << r)) && (u32)(tmp[r] >> 32) == want) pend &= ~(1u << r);
        if (++guard > 200000) break;   // failsafe: wrong result > GPU hang
      }
      #pragma unroll
      for (int r=0;r<RMAX;r++){
        int idx = tid + r*BLK;
        if (idx < NPAIR){
          int s = idx / HP, jp = idx - s*HP;
          union { u32 i; h2 h; } u; u.i = (u32)tmp[r];
          *(h2*)(hsb + s*HS + 2*jp) = u.h;
        }
      }
    }
    __syncthreads();

    float a0[4]={0,0,0,0}, a1[4]={0,0,0,0}, a2[4]={0,0,0,0};
    if (comp){
      const f16* hp = hsb + k0;
      #pragma unroll
      for (int i=0;i<KC;i++){
        const int kk = 2*i;
        h2 hv0 = *(const h2*)(hp + 0*HS + kk);
        h2 hv1 = *(const h2*)(hp + 1*HS + kk);
        h2 hv2 = *(const h2*)(hp + 2*HS + kk);
        h2 hv3 = *(const h2*)(hp + 3*HS + kk);
        a0[0]=FDOT2(w0[i],hv0,a0[0]); a0[1]=FDOT2(w0[i],hv1,a0[1]);
        a0[2]=FDOT2(w0[i],hv2,a0[2]); a0[3]=FDOT2(w0[i],hv3,a0[3]);
        a1[0]=FDOT2(w1[i],hv0,a1[0]); a1[1]=FDOT2(w1[i],hv1,a1[1]);
        a1[2]=FDOT2(w1[i],hv2,a1[2]); a1[3]=FDOT2(w1[i],hv3,a1[3]);
        a2[0]=FDOT2(w2[i],hv0,a2[0]); a2[1]=FDOT2(w2[i],hv1,a2[1]);
        a2[2]=FDOT2(w2[i],hv2,a2[2]); a2[3]=FDOT2(w2[i],hv3,a2[3]);
      }
    }
    #pragma unroll
    for (int s=0;s<4;s++){
      a0[s] += __shfl_xor(a0[s],1); a0[s] += __shfl_xor(a0[s],2); a0[s] += __shfl_xor(a0[s],4);
      a1[s] += __shfl_xor(a1[s],1); a1[s] += __shfl_xor(a1[s],2); a1[s] += __shfl_xor(a1[s],4);
      a2[s] += __shfl_xor(a2[s],1); a2[s] += __shfl_xor(a2[s],2); a2[s] += __shfl_xor(a2[s],4);
    }
    // select own batch's sums via cndmask chain (no runtime array index)
    float t0a = (l & 1) ? a0[1] : a0[0], t0b = (l & 1) ? a0[3] : a0[2];
    float A0 = (l & 2) ? t0b : t0a;
    float t1a = (l & 1) ? a1[1] : a1[0], t1b = (l & 1) ? a1[3] : a1[2];
    float A1 = (l & 2) ? t1b : t1a;
    float t2a = (l & 1) ? a2[1] : a2[0], t2b = (l & 1) ? a2[3] : a2[2];
    float A2 = (l & 2) ? t2b : t2a;

    float hn_own = 0.f;
    if (comp && l < 4){
      float rr = sigm(xr + A0 + br);
      float zz = sigm(xz + A1 + bz);
      float nn = tanhf(xn + rr*(A2 + bn_));
      hn_own = (1.f - zz)*nn + zz*hold_own;
      hold_own = hn_own;
      msum_own += hn_own;
    }
    // pair adjacent rows: even row's lane l grabs odd row's hn (lane+8)
    u32 wtag = tagbase + (u32)g + 1u;
    float hp2 = __shfl_down(hn_own, 8);
    if (comp && l < 4 && !(row & 1)){
      h2 pk; pk.x = (f16)hn_own; pk.y = (f16)hp2;
      union { h2 h; u32 i; } u; u.h = pk;
      llc_store64(&hwr[(size_t)(bg*4+l)*HP + ((unsigned)(j0+row) >> 1)],
                  ((u64)wtag << 32) | (u64)u.i);
    }
    if (tt == TC-1 && comp && l < 4){
      float* hs = hseed + (size_t)dir*Bn*Hh;
      hs[(size_t)(bg*4+l)*Hh + jg] = hold_own;
    }
  }
  if (comp && l < 4){
    float* mp = meanOut + (size_t)(bg*4+l)*mean_stride + dir*Hh + jg;
    *mp += msum_own / (float)TT;
  }
}

// ---------------------------------------------------------------------------
// mask_att + fact_sep fused: per (b, 8-t chunk). Softmax/ratio 32-lane par.
// ---------------------------------------------------------------------------
__global__ __launch_bounds__(256)
void mask_att_k(const float* ctx, const float* vh, float* simOut, float* diffOut)
{
  __shared__ float vhl[50*300];
  __shared__ float ctxl[8*300];
  __shared__ float attl[8*52];
  __shared__ float scenl[8*300];
  __shared__ float ratio[8];
  int tid = threadIdx.x;
  int b = blockIdx.y, tc = blockIdx.x;
  int grp = tid >> 5, ln = tid & 31;        // 8 groups x 32 lanes
  size_t cbase = ((size_t)b*Tn + tc*8) * 300;
  for (int i = tid; i < 15000; i += 256) vhl[i] = vh[(size_t)b*15000 + i];
  for (int i = tid; i < 2400; i += 256)  ctxl[i] = ctx[cbase + i];
  __syncthreads();
  for (int p = tid; p < 400; p += 256){
    int ttl = p / 50, v = p % 50;
    const float* cp = ctxl + ttl*300;
    const float* vp = vhl + v*300;
    float acc = 0.f;
    for (int d = 0; d < 300; d++) acc += cp[d]*vp[d];
    attl[ttl*52 + v] = acc;
  }
  __syncthreads();
  // masked softmax over v=0..50 per row (group grp owns row grp)
  {
    float mx = -INFINITY;
    for (int v = ln; v < 50; v += 32){
      float a = attl[grp*52+v];
      float msk = (a == 0.f) ? -INFINITY : a;
      attl[grp*52+v] = msk;
      mx = fmaxf(mx, msk);
    }
    #pragma unroll
    for (int m=1; m<32; m<<=1) mx = fmaxf(mx, __shfl_xor(mx, m));
    if (mx == -INFINITY){
      for (int v = ln; v < 50; v += 32) attl[grp*52+v] = 0.f;
    } else {
      float sum = 0.f;
      for (int v = ln; v < 50; v += 32){
        float e = expf(attl[grp*52+v] - mx);
        attl[grp*52+v] = e;
        sum += e;
      }
      #pragma unroll
      for (int m=1; m<32; m<<=1) sum += __shfl_xor(sum, m);
      float inv = 1.f/sum;
      for (int v = ln; v < 50; v += 32) attl[grp*52+v] *= inv;
    }
  }
  __syncthreads();
  for (int p = tid; p < 2400; p += 256){
    int ttl = p / 300, d = p % 300;
    float acc = 0.f;
    for (int v=0; v<50; v++) acc += attl[ttl*52+v] * vhl[v*300+d];
    scenl[p] = acc;
  }
  __syncthreads();
  // ratio = <ctx,scen>/<scen,scen> per row, 32-lane parallel dot
  {
    float x3 = 0.f, x4 = 0.f;
    for (int d = ln; d < 300; d += 32){
      float s = scenl[grp*300+d];
      x3 += ctxl[grp*300+d]*s; x4 += s*s;
    }
    #pragma unroll
    for (int m=1; m<32; m<<=1){ x3 += __shfl_xor(x3, m); x4 += __shfl_xor(x4, m); }
    if (ln == 0) ratio[grp] = x3 / (x4 + 1e-10f);
  }
  __syncthreads();
  for (int p = tid; p < 2400; p += 256){
    float sim = ratio[p/300] * scenl[p];
    simOut[cbase + p]  = sim;
    diffOut[cbase + p] = ctxl[p] - sim;
  }
}

// ---------------------------------------------------------------------------
// code_wise helpers
// ---------------------------------------------------------------------------
__global__ void rowmax_k(const float* S, float* out, int M, int N){
  int row = blockIdx.x*4 + (threadIdx.x >> 6);
  int lane = threadIdx.x & 63;
  if (row >= M) return;
  float mx = -INFINITY;
  for (int n = lane; n < N; n += 64) mx = fmaxf(mx, S[(size_t)row*N + n]);
  for (int off = 32; off; off >>= 1) mx = fmaxf(mx, __shfl_xor(mx, off, 64));
  if (lane == 0) out[row] = mx;
}

__global__ __launch_bounds__(256)
void softmaxT_k(const float* m, float* att){
  __shared__ float red[256];
  int b = blockIdx.x, tid = threadIdx.x;
  float v1 = m[b*512 + tid], v2 = m[b*512 + 256 + tid];
  red[tid] = fmaxf(v1, v2); __syncthreads();
  for (int s=128; s; s>>=1){ if (tid<s) red[tid] = fmaxf(red[tid], red[tid+s]); __syncthreads(); }
  float M = red[0]; __syncthreads();
  float e1 = expf(v1-M), e2 = expf(v2-M);
  red[tid] = e1+e2; __syncthreads();
  for (int s=128; s; s>>=1){ if (tid<s) red[tid] += red[tid+s]; __syncthreads(); }
  float inv = 1.f / red[0];
  att[b*512+tid] = e1*inv; att[b*512+256+tid] = e2*inv;
}

// R9: split t over 8 blocks (grid (32,8)), partial sums via atomicAdd.
// out must be zeroed first. 8x parallelism on a latency-bound reduction.
__global__ __launch_bounds__(256)
void wsum_k(const float* att, const float* dh, float* out){
  int b = blockIdx.x, c = blockIdx.y, tid = threadIdx.x;
  int t0 = c * 64;
  for (int d = tid; d < 300; d += 256){
    float acc = 0.f;
    #pragma unroll 8
    for (int t = t0; t < t0 + 64; t++)
      acc += att[b*512+t] * dh[((size_t)b*512 + t)*300 + d];
    atomicAdd(&out[b*300+d], acc);
  }
}

// ---------------------------------------------------------------------------
// graph_decomp helpers
// ---------------------------------------------------------------------------
__global__ void count_k(const int* src, int E, float* counts){
  int e = blockIdx.x*256 + threadIdx.x;
  if (e < E) atomicAdd(&counts[src[e]], 1.f);
}
__global__ void coef_k(const float* L, const int* src, const int* dst, int E, float* coef){
  int e = blockIdx.x*4 + (threadIdx.x >> 6);
  int lane = threadIdx.x & 63;
  if (e >= E) return;
  const float* Li = L + (size_t)src[e]*300;
  const float* Lj = L + (size_t)dst[e]*300;
  float num = 0.f, den = 0.f;
  for (int d = lane; d < 300; d += 64){ float lj = Lj[d]; num += Li[d]*lj; den += lj*lj; }
  for (int off = 32; off; off >>= 1){ num += __shfl_xor(num, off, 64); den += __shfl_xor(den, off, 64); }
  if (lane == 0) coef[e] = num / (den + 1e-10f);
}
__global__ void agg_k(const float* L, const int* src, const int* dst, const float* coef, int E, float* agg){
  int e = blockIdx.x;
  float c = coef[e];
  const float* Lj = L + (size_t)dst[e]*300;
  float* ag = agg + (size_t)src[e]*300;
  for (int d = threadIdx.x; d < 300; d += 256) atomicAdd(&ag[d], c*Lj[d]);
}
__global__ void upd_k(const float* L, const float* agg, const float* counts, float* out, int n){
  int i = blockIdx.x;
  float c = counts[i];
  for (int d = threadIdx.x; d < 300; d += 256){
    float v = L[(size_t)i*300+d];
    out[(size_t)i*300+d] = (c > 0.f) ? v - agg[(size_t)i*300+d]/fmaxf(c, 1.f) : v;
  }
}

// ---------------------------------------------------------------------------
// classifier heads, argmax, gather
// ---------------------------------------------------------------------------
__global__ __launch_bounds__(128)
void logits_k(const float* A0, const float* A1, const float* A2, int srcw,
              const float* W, const float* bias, int C, int K,
              float* outF){
  int b = blockIdx.x, tid = threadIdx.x;
  for (int c = tid; c < C; c += 128){
    float acc = bias[c];
    const float* wp = W + (size_t)c*K;
    for (int k = 0; k < K; k++){
      int s = k / srcw; int kk = k - s*srcw;
      const float* Ap = (s==0) ? A0 : ((s==1) ? A1 : A2);
      acc += Ap[(size_t)b*srcw + kk] * wp[k];
    }
    outF[b*C + c] = acc;
  }
}
__global__ void argmax_k(const float* lf, int C, int* pred){
  int b = threadIdx.x;
  if (b < 32){
    const float* p = lf + (size_t)b*C;
    int best = 0; float bv = p[0];
    for (int c = 1; c < C; c++){ float v = p[c]; if (v > bv){ bv = v; best = c; } }
    pred[b] = best;
  }
}
__global__ void vtok_k(const int* table, const int* pred, int* vt, int L){
  int i = blockIdx.x*256 + threadIdx.x;
  if (i < 32*L) vt[i] = table[pred[i/L]*L + i%L];
}

// ---------------------------------------------------------------------------
extern "C" void kernel_launch(void* const* d_in, const int* in_sizes, int n_in,
                              void* d_out, int out_size, void* d_ws, size_t ws_size,
                              hipStream_t stream)
{
  (void)in_sizes; (void)n_in; (void)out_size;
  const float* E        = (const float*)d_in[0];
  const int* chTok    = (const int*)d_in[1];
  const int* arTok    = (const int*)d_in[2];
  const int* docs     = (const int*)d_in[3];
  const int* chVerd   = (const int*)d_in[4];
  const int* arVerd   = (const int*)d_in[5];
  const int* c_src    = (const int*)d_in[6];
  const int* c_dst    = (const int*)d_in[7];
  const int* a_src    = (const int*)d_in[8];
  const int* a_dst    = (const int*)d_in[9];
  const float* enc_Wih  = (const float*)d_in[10];
  const float* enc_Whh  = (const float*)d_in[11];
  const float* enc_bih  = (const float*)d_in[12];
  const float* enc_bhh  = (const float*)d_in[13];
  const float* ech_Wih  = (const float*)d_in[14];
  const float* ech_Whh  = (const float*)d_in[15];
  const float* ech_bih  = (const float*)d_in[16];
  const float* ech_bhh  = (const float*)d_in[17];
  const float* term_Wih = (const float*)d_in[18];
  const float* term_Whh = (const float*)d_in[19];
  const float* term_bih = (const float*)d_in[20];
  const float* term_bhh = (const float*)d_in[21];
  const float* art_Wih  = (const float*)d_in[22];
  const float* art_Whh  = (const float*)d_in[23];
  const float* art_bih  = (const float*)d_in[24];
  const float* art_bhh  = (const float*)d_in[25];
  const float* W_charge = (const float*)d_in[26];
  const float* b_charge = (const float*)d_in[27];
  const float* W_article= (const float*)d_in[28];
  const float* b_article= (const float*)d_in[29];
  const float* W_time   = (const float*)d_in[30];
  const float* b_time   = (const float*)d_in[31];
  float* out = (float*)d_out;
  float* OUTC = out;            // [32][119]
  float* OUTA = out + 3808;     // [32][103]
  float* OUTT = out + 7104;     // [32][11]

  char* wsb = (char*)d_ws;
  size_t off = 0;
  auto alloc = [&](size_t nf)->float* {
    float* p = (float*)(wsb + off);
    off += ((nf*4 + 255) & ~(size_t)255);
    return p;
  };
  float* XS0   = alloc(14745600ULL);        // 59.0 MB
  float* XS1   = alloc(14745600ULL);        // 59.0 MB
  float* SBUF  = XS0;                       // alias: disjoint lifetime
  float* DH    = alloc(4915200);            // d_hidden [32][512][300]
  float* ADC   = alloc(4915200);            // adc, later dsc
  float* SEC   = alloc(4915200);
  float* SSC   = alloc(4915200);
  float* VHYS  = alloc(480000);             // [32][50][300]
  float* MECH  = alloc(66600);              // encch means [222][300]
  float* LC1   = alloc(35700);
  float* LC0   = alloc(35700);
  float* LA1   = alloc(30900);
  float* LA0   = alloc(30900);
  float* AGG   = alloc(35700);
  float* CNTS  = alloc(256);                // counts_c @0, counts_a @128
  float* COEF  = alloc(640);
  float* DHC   = alloc(9600);
  float* DA    = alloc(9600);
  float* DHNA  = alloc(9600);
  float* DB    = alloc(9600);
  float* MDH   = alloc(9600);               // mean_t d_hidden [32][300]
  float* MFA   = alloc(38400);              // fa mean [32][1200] (accumulated)
  float* MTH   = alloc(28800);              // th mean [32][900] (accumulated)
  float* RB    = alloc(115200);             // art rowbias [32][3600]
  float* RMX   = alloc(16384);
  float* ATTB  = alloc(16384);
  u64*   HBUF  = (u64*)alloc(76800);        // [2][2][32][300] u64 tagged pairs
  float* HSEED = alloc(38400);              // [2][32][600] exact f32 seeds
  int*   PREDC = (int*)alloc(64);
  int*   PREDA = (int*)alloc(64);
  int*   VTOK  = (int*)alloc(1600);
  int*   TCC   = (int*)alloc(11104);

  if (off > ws_size) return;   // diagnostic: leaves out==0 -> absmax==max|ref|

  hipMemsetAsync(HBUF, 0, 2*2*Bn*300*sizeof(u64), stream);  // tags = 0
  hipMemsetAsync(CNTS, 0, 256*4, stream);

  // --- encch on charge+article token sequences (222 seqs, L=50) ---
  hipMemcpyAsync(TCC, chTok, NCn*LCn*4, hipMemcpyDeviceToDevice, stream);
  hipMemcpyAsync(TCC + NCn*LCn, arTok, NAn*LCn*4, hipMemcpyDeviceToDevice, stream);
  embed_mfma_k<<<dim3(8,87),256,0,stream>>>(E, TCC, ech_Wih, ech_bih,
      XS0, 11100, 900, 200);
  gru_small_k<<<dim3(222,2),640,0,stream>>>(XS0, 900, ech_Whh, ech_bhh, nullptr, MECH, 50);

  // --- enc on documents ---
  embed_mfma_k<<<dim3(8,128),256,0,stream>>>(E, docs, enc_Wih, enc_bih,
      XS0, 16384, 900, 200);
  gru_small_k<<<dim3(32,2),640,0,stream>>>(XS0, 900, enc_Whh, enc_bhh, DH, MDH, 512);

  // --- graph_decomp (charge, article), 2 layers each ---
  count_k<<<3,256,0,stream>>>(c_src, ECn, CNTS);
  count_k<<<2,256,0,stream>>>(a_src, EAn, CNTS+128);
  coef_k<<<150,256,0,stream>>>(MECH, c_src, c_dst, ECn, COEF);
  hipMemsetAsync(AGG, 0, 35700*4, stream);
  agg_k<<<ECn,256,0,stream>>>(MECH, c_src, c_dst, COEF, ECn, AGG);
  upd_k<<<NCn,256,0,stream>>>(MECH, AGG, CNTS, LC1, NCn);
  coef_k<<<150,256,0,stream>>>(LC1, c_src, c_dst, ECn, COEF);
  hipMemsetAsync(AGG, 0, 35700*4, stream);
  agg_k<<<ECn,256,0,stream>>>(LC1, c_src, c_dst, COEF, ECn, AGG);
  upd_k<<<NCn,256,0,stream>>>(LC1, AGG, CNTS, LC0, NCn);

  const float* MEAR = MECH + (size_t)NCn*300;
  coef_k<<<125,256,0,stream>>>(MEAR, a_src, a_dst, EAn, COEF);
  hipMemsetAsync(AGG, 0, 30900*4, stream);
  agg_k<<<EAn,256,0,stream>>>(MEAR, a_src, a_dst, COEF, EAn, AGG);
  upd_k<<<NAn,256,0,stream>>>(MEAR, AGG, CNTS+128, LA1, NAn);
  coef_k<<<125,256,0,stream>>>(LA1, a_src, a_dst, EAn, COEF);
  hipMemsetAsync(AGG, 0, 30900*4, stream);
  agg_k<<<EAn,256,0,stream>>>(LA1, a_src, a_dst, COEF, EAn, AGG);
  upd_k<<<NAn,256,0,stream>>>(LA1, AGG, CNTS+128, LA0, NAn);

  // --- code_wise x4 (S-buffer aliased into XS0) ---
  auto codewise = [&](const float* q, int Nq, float* outv){
    dim3 g((Nq+127)/128, 128);
    gemm_k<0><<<g,256,0,stream>>>(DH, nullptr, nullptr, nullptr, nullptr,
        q, 300, 0,0,0, nullptr, nullptr, 1, 1, IDIV,0,0,
        SBUF, 16384, Nq, 300);
    rowmax_k<<<4096,256,0,stream>>>(SBUF, RMX, 16384, Nq);
    softmaxT_k<<<32,256,0,stream>>>(RMX, ATTB);
    hipMemsetAsync(outv, 0, 9600*4, stream);
    wsum_k<<<dim3(32,8),256,0,stream>>>(ATTB, DH, outv);
  };
  codewise(LC0,  NCn, DHC);    // new_charge
  codewise(MECH, NCn, DA);     // ori charge
  codewise(LA0,  NAn, DHNA);   // new_article
  codewise(MEAR, NAn, DB);     // ori article

  // --- charge head ---
  logits_k<<<32,128,0,stream>>>(MDH, DHC, DA, 300, W_charge, b_charge, NCn, 900, OUTC);
  argmax_k<<<1,64,0,stream>>>(OUTC, NCn, PREDC);

  // --- fact_sep #1 ---
  vtok_k<<<7,256,0,stream>>>(chVerd, PREDC, VTOK, LVn);
  embed_mfma_k<<<dim3(8,13),256,0,stream>>>(E, VTOK, enc_Wih, enc_bih,
      XS0, 1600, 900, 200);
  gru_small_k<<<dim3(32,2),640,0,stream>>>(XS0, 900, enc_Whh, enc_bhh, VHYS, nullptr, 50);
  mask_att_k<<<dim3(64,32),256,0,stream>>>(DH, VHYS, ADC, SEC);

  // --- article bigru: rowbias, then time-sliced dual-dir chunks ---
  {
    dim3 g((3600+127)/128, 1);
    gemm_k<0><<<g,256,0,stream>>>(DHNA, DB, nullptr, nullptr, nullptr,
        art_Wih, 1200, 300, 900, 0, art_bih, nullptr, 1, 1, IDIV,0,0,
        RB, 32, 3600, 600);
  }
  hipMemsetAsync(MFA, 0, 38400*4, stream);
  for (int L = 0; L < 2; L++){
    stage_mfma_k<<<dim3(15,64),256,0,stream>>>(DH, ADC, nullptr,
        art_Wih, 1200, 0, 600, 0,
        nullptr, RB, 3600, 256*L,
        XS0, 1800, 600);
    stage_mfma_k<<<dim3(15,64),256,0,stream>>>(DH, ADC, nullptr,
        art_Wih + (size_t)1800*1200, 1200, 0, 600, 0,
        nullptr, RB + 1800, 3600, 256*(1-L),
        XS1, 1800, 600);
    gru_big_k<384,40,38,600><<<dim3(15,8,2),384,0,stream>>>(XS0, XS1,
        art_Whh, art_bhh, HBUF, HSEED, MFA, 1200, 0u,
        512, 256, 256*L);
  }
  logits_k<<<32,128,0,stream>>>(MFA, nullptr, nullptr, 1200, W_article, b_article, NAn, 1200, OUTA);
  argmax_k<<<1,64,0,stream>>>(OUTA, NAn, PREDA);

  // --- fact_sep #2 (context = sec_vector) ---
  vtok_k<<<7,256,0,stream>>>(arVerd, PREDA, VTOK, LVn);
  embed_mfma_k<<<dim3(8,13),256,0,stream>>>(E, VTOK, enc_Wih, enc_bih,
      XS0, 1600, 900, 200);
  gru_small_k<<<dim3(32,2),640,0,stream>>>(XS0, 900, enc_Whh, enc_bhh, VHYS, nullptr, 50);
  mask_att_k<<<dim3(64,32),256,0,stream>>>(SEC, VHYS, SSC, ADC);   // ssc, dsc(=ADC)

  // --- term bigru, time-sliced dual-dir chunks ---
  hipMemsetAsync(MTH, 0, 28800*4, stream);
  for (int L = 0; L < 2; L++){
    stage_mfma_k<<<dim3(11,64),256,0,stream>>>(DH, SSC, ADC,
        term_Wih, 900, 0, 300, 600,
        term_bih, nullptr, 0, 256*L,
        XS0, 1350, 900);
    stage_mfma_k<<<dim3(11,64),256,0,stream>>>(DH, SSC, ADC,
        term_Wih + (size_t)1350*900, 900, 0, 300, 600,
        term_bih + 1350, nullptr, 0, 256*(1-L),
        XS1, 1350, 900);
    gru_big_k<448,50,29,450><<<dim3(9,8,2),448,0,stream>>>(XS0, XS1,
        term_Whh, term_bhh, HBUF, HSEED, MTH, 900, 512u,
        512, 256, 256*L);
  }
  logits_k<<<32,128,0,stream>>>(MTH, nullptr, nullptr, 900, W_time, b_time, NTn, 900, OUTT);
}

// Round 10
// 11270.969 us; speedup vs baseline: 1.4756x; 1.0517x over previous
//
#include <hip/hip_runtime.h>
#include <stdint.h>
#include <math.h>

typedef unsigned int u32;
typedef unsigned long long u64;
typedef _Float16 f16;
typedef _Float16 h4 __attribute__((ext_vector_type(4)));
typedef _Float16 h2 __attribute__((ext_vector_type(2)));
typedef _Float16 h8 __attribute__((ext_vector_type(8)));
typedef float f4 __attribute__((ext_vector_type(4)));

// Problem constants
#define Vn     50000
#define DEMBn  200
#define Hn     150
#define NCn    119
#define NAn    103
#define NTn    11
#define Bn     32
#define Tn     512
#define LCn    50
#define LVn    50
#define ECn    600
#define EAn    500

#define IDIV 1073741824 // identity arow mapping

__device__ __forceinline__ float sigm(float x){ return 1.0f / (1.0f + expf(-x)); }

#if __has_builtin(__builtin_amdgcn_fdot2)
__device__ __forceinline__ float FDOT2(h2 a, h2 b, float c){
  return __builtin_amdgcn_fdot2(a, b, c, false);
}
#else
__device__ __forceinline__ float FDOT2(h2 a, h2 b, float c){
  return c + (float)a.x*(float)b.x + (float)a.y*(float)b.y;
}
#endif

// LLC-coherent agent-scope 64-bit ops (bypass non-coherent L1/L2).
__device__ __forceinline__ u64 llc_load64(const u64* p){
  return __hip_atomic_load(p, __ATOMIC_RELAXED, __HIP_MEMORY_SCOPE_AGENT);
}
__device__ __forceinline__ void llc_store64(u64* p, u64 v){
  __hip_atomic_store(p, v, __ATOMIC_RELAXED, __HIP_MEMORY_SCOPE_AGENT);
}

// ---------------------------------------------------------------------------
// Tiled fp32 GEMM (small cases): C[M][N] = A[arow(m)][K] @ B[N][K]^T
// ---------------------------------------------------------------------------
template<int AMODE>
__global__ __launch_bounds__(256)
void gemm_k(const float* A0, const float* A1, const float* A2,
            const float* Etab, const int* tok,
            const float* Bm, int ldb, int bc0, int bc1, int bc2,
            const float* bias, const float* rowbias, int rb_div, int rb_stride,
            int arow_div, int arow_stride, int arow_off,
            float* C, int M, int N, int K)
{
  __shared__ float As[8][132];
  __shared__ float Bs[8][132];
  __shared__ int tokS[128];
  int tid = threadIdx.x;
  int m0 = blockIdx.y * 128, n0 = blockIdx.x * 128;
  if (AMODE == 1){
    for (int i = tid; i < 128; i += 256){
      int m = m0 + i;
      tokS[i] = (m < M) ? tok[m] : 0;
    }
  }
  __syncthreads();
  float acc[8][8];
  #pragma unroll
  for (int i=0;i<8;i++)
    #pragma unroll
    for (int j=0;j<8;j++) acc[i][j] = 0.f;

  int tx = tid & 15, ty = tid >> 4;

  for (int k0 = 0; k0 < K; k0 += 8){
    #pragma unroll
    for (int r = 0; r < 4; r++){
      int i = tid + 256*r;          // [0,1024)
      int ml = i >> 3, kl = i & 7;
      int k = k0 + kl;
      {
        int m = m0 + ml;
        float v = 0.f;
        if (m < M && k < K){
          if (AMODE == 0){
            int s = k / 300; int kk = k - s*300;
            const float* Ap = (s==0) ? A0 : ((s==1) ? A1 : A2);
            int ar = (m / arow_div)*arow_stride + (m % arow_div) + arow_off;
            v = Ap[(size_t)ar*300 + kk];
          } else {
            v = Etab[(size_t)tokS[ml]*DEMBn + k];
          }
        }
        As[kl][ml] = v;
      }
      {
        int n = n0 + ml;
        float v = 0.f;
        if (n < N && k < K){
          int col;
          if (AMODE == 0){ int s = k / 300; int kk = k - s*300; col = ((s==0)?bc0:((s==1)?bc1:bc2)) + kk; }
          else col = k;
          v = Bm[(size_t)n*ldb + col];
        }
        Bs[kl][ml] = v;
      }
    }
    __syncthreads();
    #pragma unroll
    for (int kk = 0; kk < 8; kk++){
      float a[8], b[8];
      #pragma unroll
      for (int i=0;i<8;i++) a[i] = As[kk][ty*8+i];
      #pragma unroll
      for (int i=0;i<8;i++) b[i] = Bs[kk][tx*8+i];
      #pragma unroll
      for (int i=0;i<8;i++)
        #pragma unroll
        for (int j=0;j<8;j++) acc[i][j] += a[i]*b[j];
    }
    __syncthreads();
  }
  #pragma unroll
  for (int i=0;i<8;i++){
    int m = m0 + ty*8 + i; if (m >= M) continue;
    #pragma unroll
    for (int j=0;j<8;j++){
      int n = n0 + tx*8 + j; if (n >= N) continue;
      float v = acc[i][j];
      if (bias)    v += bias[n];
      if (rowbias) v += rowbias[(size_t)(m / rb_div)*rb_stride + n];
      C[(size_t)m*N + n] = v;
    }
  }
}

// ---------------------------------------------------------------------------
// Fused code_wise score + row-max: RMX[m] = max_n (DH[m]. q[n]) for n<Nq.
// Nq <= 128 so one block covers the full row; S never materialized.
// M fixed 16384, K fixed 300.
// ---------------------------------------------------------------------------
__global__ __launch_bounds__(256)
void score_rowmax_k(const float* A, const float* Bq, int Nq, float* RMX)
{
  __shared__ float As[8][132];
  __shared__ float Bs[8][132];
  int tid = threadIdx.x;
  int m0 = blockIdx.x * 128;
  float acc[8][8];
  #pragma unroll
  for (int i=0;i<8;i++)
    #pragma unroll
    for (int j=0;j<8;j++) acc[i][j] = 0.f;
  int tx = tid & 15, ty = tid >> 4;

  for (int k0 = 0; k0 < 300; k0 += 8){
    #pragma unroll
    for (int r = 0; r < 4; r++){
      int i = tid + 256*r;
      int ml = i >> 3, kl = i & 7;
      int k = k0 + kl;
      As[kl][ml] = (k < 300) ? A[(size_t)(m0 + ml)*300 + k] : 0.f;
      Bs[kl][ml] = (ml < Nq && k < 300) ? Bq[(size_t)ml*300 + k] : 0.f;
    }
    __syncthreads();
    #pragma unroll
    for (int kk = 0; kk < 8; kk++){
      float a[8], b[8];
      #pragma unroll
      for (int i=0;i<8;i++) a[i] = As[kk][ty*8+i];
      #pragma unroll
      for (int i=0;i<8;i++) b[i] = Bs[kk][tx*8+i];
      #pragma unroll
      for (int i=0;i<8;i++)
        #pragma unroll
        for (int j=0;j<8;j++) acc[i][j] += a[i]*b[j];
    }
    __syncthreads();
  }
  // row-max: local over valid j, then across the 16 tx lanes (consecutive)
  #pragma unroll
  for (int i=0;i<8;i++){
    float mx = -INFINITY;
    #pragma unroll
    for (int j=0;j<8;j++){
      int n = tx*8 + j;
      if (n < Nq) mx = fmaxf(mx, acc[i][j]);
    }
    mx = fmaxf(mx, __shfl_xor(mx, 1));
    mx = fmaxf(mx, __shfl_xor(mx, 2));
    mx = fmaxf(mx, __shfl_xor(mx, 4));
    mx = fmaxf(mx, __shfl_xor(mx, 8));
    if (tx == 0) RMX[m0 + ty*8 + i] = mx;
  }
}

// ---------------------------------------------------------------------------
// MFMA split-f16 staging GEMM for the big xs gemms (art/term).
// Precision: A=Ahi+Alo, B=Bhi+Blo (f16 split); acc += AhBh + AhBl + AlBh in
// f32 MFMA -> ~2^-22 relative error (f32-grade), at MFMA rates.
// ---------------------------------------------------------------------------
__global__ __launch_bounds__(256)
void stage_mfma_k(const float* A0, const float* A1, const float* A2,
                  const float* Bm, int ldb, int bc0, int bc1, int bc2,
                  const float* bias, const float* rowbias, int rb_stride,
                  int arow_off,
                  float* C, int N, int K)
{
  constexpr int KP = 40;                    // f16 row stride (80B: 16B-aligned rows)
  __shared__ __align__(16) f16 Ah[128*KP];
  __shared__ __align__(16) f16 Al[128*KP];
  __shared__ __align__(16) f16 Bh[128*KP];
  __shared__ __align__(16) f16 Bl[128*KP];

  int tid = threadIdx.x;
  int n0 = blockIdx.x * 128, m0 = blockIdx.y * 128;
  int lane = tid & 63, w = tid >> 6;
  int wr = (w >> 1) * 64, wc = (w & 1) * 64;   // wave tile origin in block tile
  int li = lane & 15, lk = (lane >> 4) * 8;

  f4 acc[4][4];
  #pragma unroll
  for (int i=0;i<4;i++)
    #pragma unroll
    for (int j=0;j<4;j++) acc[i][j] = (f4){0.f,0.f,0.f,0.f};

  int srow = tid >> 1, scb = (tid & 1) << 4;   // staging: row, col-base (16 k each)
  int sm = m0 + srow;
  size_t abase = (size_t)(((sm >> 8) * 512) + (sm & 255) + arow_off) * 300;
  int sn = n0 + srow;

  for (int k0 = 0; k0 < K; k0 += 32){
    // ---- stage A,B k-tile as hi/lo f16 ----
    #pragma unroll
    for (int q = 0; q < 16; q += 2){
      float va0=0.f, va1=0.f, vb0=0.f, vb1=0.f;
      int k = k0 + scb + q;
      if (k < K){
        int s = (k >= 600) ? 2 : ((k >= 300) ? 1 : 0);
        int kk = k - s*300;
        const float* Ap = (s==0) ? A0 : ((s==1) ? A1 : A2);
        va0 = Ap[abase + kk];
        if (sn < N) vb0 = Bm[(size_t)sn*ldb + ((s==0)?bc0:((s==1)?bc1:bc2)) + kk];
      }
      int k1 = k + 1;
      if (k1 < K){
        int s = (k1 >= 600) ? 2 : ((k1 >= 300) ? 1 : 0);
        int kk = k1 - s*300;
        const float* Ap = (s==0) ? A0 : ((s==1) ? A1 : A2);
        va1 = Ap[abase + kk];
        if (sn < N) vb1 = Bm[(size_t)sn*ldb + ((s==0)?bc0:((s==1)?bc1:bc2)) + kk];
      }
      f16 a0h=(f16)va0, a1h=(f16)va1, b0h=(f16)vb0, b1h=(f16)vb1;
      f16 a0l=(f16)(va0-(float)a0h), a1l=(f16)(va1-(float)a1h);
      f16 b0l=(f16)(vb0-(float)b0h), b1l=(f16)(vb1-(float)b1h);
      int off = srow*KP + scb + q;
      *(h2*)&Ah[off] = (h2){a0h, a1h};
      *(h2*)&Al[off] = (h2){a0l, a1l};
      *(h2*)&Bh[off] = (h2){b0h, b1h};
      *(h2*)&Bl[off] = (h2){b0l, b1l};
    }
    __syncthreads();

    // ---- fragments + 3-pass MFMA ----
    h8 fah[4], fal[4], fbh[4], fbl[4];
    #pragma unroll
    for (int f = 0; f < 4; f++){
      fah[f] = *(const h8*)&Ah[(wr + f*16 + li)*KP + lk];
      fal[f] = *(const h8*)&Al[(wr + f*16 + li)*KP + lk];
      fbh[f] = *(const h8*)&Bh[(wc + f*16 + li)*KP + lk];
      fbl[f] = *(const h8*)&Bl[(wc + f*16 + li)*KP + lk];
    }
    #pragma unroll
    for (int i = 0; i < 4; i++)
      #pragma unroll
      for (int j = 0; j < 4; j++){
        acc[i][j] = __builtin_amdgcn_mfma_f32_16x16x32_f16(fah[i], fbh[j], acc[i][j], 0,0,0);
        acc[i][j] = __builtin_amdgcn_mfma_f32_16x16x32_f16(fah[i], fbl[j], acc[i][j], 0,0,0);
        acc[i][j] = __builtin_amdgcn_mfma_f32_16x16x32_f16(fal[i], fbh[j], acc[i][j], 0,0,0);
      }
    __syncthreads();
  }

  // ---- epilogue ----
  #pragma unroll
  for (int i = 0; i < 4; i++){
    int r0 = m0 + wr + i*16 + (lane >> 4)*4;
    #pragma unroll
    for (int j = 0; j < 4; j++){
      int c = n0 + wc + j*16 + li;
      if (c < N){
        float badd = bias ? bias[c] : 0.f;
        #pragma unroll
        for (int r = 0; r < 4; r++){
          int row = r0 + r;
          float v = acc[i][j][r] + badd;
          if (rowbias) v += rowbias[(size_t)(row >> 8)*rb_stride + c];
          C[(size_t)row*N + c] = v;
        }
      }
    }
  }
}

// ---------------------------------------------------------------------------
// MFMA split-f16 embedding-gather GEMM: C[m][n] = E[tok[m]][:K] . B[n][:K] + bias[n]
// ---------------------------------------------------------------------------
__global__ __launch_bounds__(256)
void embed_mfma_k(const float* Etab, const int* tok,
                  const float* Bm, const float* bias,
                  float* C, int M, int N, int K)
{
  constexpr int KP = 40;
  __shared__ __align__(16) f16 Ah[128*KP];
  __shared__ __align__(16) f16 Al[128*KP];
  __shared__ __align__(16) f16 Bh[128*KP];
  __shared__ __align__(16) f16 Bl[128*KP];
  __shared__ int tokS[128];

  int tid = threadIdx.x;
  int n0 = blockIdx.x * 128, m0 = blockIdx.y * 128;
  int lane = tid & 63, w = tid >> 6;
  int wr = (w >> 1) * 64, wc = (w & 1) * 64;
  int li = lane & 15, lk = (lane >> 4) * 8;

  for (int i = tid; i < 128; i += 256){
    int m = m0 + i;
    tokS[i] = (m < M) ? tok[m] : 0;
  }
  __syncthreads();

  f4 acc[4][4];
  #pragma unroll
  for (int i=0;i<4;i++)
    #pragma unroll
    for (int j=0;j<4;j++) acc[i][j] = (f4){0.f,0.f,0.f,0.f};

  int srow = tid >> 1, scb = (tid & 1) << 4;
  size_t abase = (size_t)tokS[srow] * (size_t)K;
  int sn = n0 + srow;

  for (int k0 = 0; k0 < K; k0 += 32){
    #pragma unroll
    for (int q = 0; q < 16; q += 2){
      float va0=0.f, va1=0.f, vb0=0.f, vb1=0.f;
      int k = k0 + scb + q;
      if (k < K){
        va0 = Etab[abase + k];
        if (sn < N) vb0 = Bm[(size_t)sn*K + k];
      }
      if (k + 1 < K){
        va1 = Etab[abase + k + 1];
        if (sn < N) vb1 = Bm[(size_t)sn*K + k + 1];
      }
      f16 a0h=(f16)va0, a1h=(f16)va1, b0h=(f16)vb0, b1h=(f16)vb1;
      f16 a0l=(f16)(va0-(float)a0h), a1l=(f16)(va1-(float)a1h);
      f16 b0l=(f16)(vb0-(float)b0h), b1l=(f16)(vb1-(float)b1h);
      int off = srow*KP + scb + q;
      *(h2*)&Ah[off] = (h2){a0h, a1h};
      *(h2*)&Al[off] = (h2){a0l, a1l};
      *(h2*)&Bh[off] = (h2){b0h, b1h};
      *(h2*)&Bl[off] = (h2){b0l, b1l};
    }
    __syncthreads();

    h8 fah[4], fal[4], fbh[4], fbl[4];
    #pragma unroll
    for (int f = 0; f < 4; f++){
      fah[f] = *(const h8*)&Ah[(wr + f*16 + li)*KP + lk];
      fal[f] = *(const h8*)&Al[(wr + f*16 + li)*KP + lk];
      fbh[f] = *(const h8*)&Bh[(wc + f*16 + li)*KP + lk];
      fbl[f] = *(const h8*)&Bl[(wc + f*16 + li)*KP + lk];
    }
    #pragma unroll
    for (int i = 0; i < 4; i++)
      #pragma unroll
      for (int j = 0; j < 4; j++){
        acc[i][j] = __builtin_amdgcn_mfma_f32_16x16x32_f16(fah[i], fbh[j], acc[i][j], 0,0,0);
        acc[i][j] = __builtin_amdgcn_mfma_f32_16x16x32_f16(fah[i], fbl[j], acc[i][j], 0,0,0);
        acc[i][j] = __builtin_amdgcn_mfma_f32_16x16x32_f16(fal[i], fbh[j], acc[i][j], 0,0,0);
      }
    __syncthreads();
  }

  #pragma unroll
  for (int i = 0; i < 4; i++){
    int r0 = m0 + wr + i*16 + (lane >> 4)*4;
    #pragma unroll
    for (int j = 0; j < 4; j++){
      int c = n0 + wc + j*16 + li;
      if (c < N){
        float badd = bias ? bias[c] : 0.f;
        #pragma unroll
        for (int r = 0; r < 4; r++){
          int row = r0 + r;
          if (row < M) C[(size_t)row*N + c] = acc[i][j][r] + badd;
        }
      }
    }
  }
}

// ---------------------------------------------------------------------------
// Small-GRU recurrence (H=150): one block per (seq, dir). 4 lanes/row,
// exact f32 weights in VGPRs, parity double-buffered h, 1 barrier/step.
// ---------------------------------------------------------------------------
__global__ __launch_bounds__(640)
void gru_small_k(const float* xs, int ncols,
                 const float* Whh, const float* bhh,
                 float* ys, float* meanOut, int T)
{
  constexpr int KSTEP = 38;                 // ceil(150/4)
  __shared__ __align__(16) float hl[2][152];
  int tid = threadIdx.x;
  int seq = blockIdx.x, dir = blockIdx.y;
  int row = tid >> 2, l = tid & 3;
  bool comp = (row < 150);
  int k0 = l * KSTEP;

  float w0[KSTEP], w1[KSTEP], w2[KSTEP];
  if (comp){
    const float* base = Whh + (size_t)dir*67500;
    const float* p0 = base + (size_t)(0*150 + row)*150;
    const float* p1 = base + (size_t)(1*150 + row)*150;
    const float* p2 = base + (size_t)(2*150 + row)*150;
    #pragma unroll
    for (int i=0;i<KSTEP;i++){
      int k = k0 + i;
      int kc = (k < 150) ? k : 0;
      float m = (k < 150) ? 1.f : 0.f;
      w0[i] = p0[kc]*m; w1[i] = p1[kc]*m; w2[i] = p2[kc]*m;
    }
  }
  float bR=0.f, bZ=0.f, bN=0.f;
  if (comp && l==0){
    bR = bhh[dir*450 + row];
    bZ = bhh[dir*450 + 150 + row];
    bN = bhh[dir*450 + 300 + row];
  }
  for (int i = tid; i < 2*152; i += 640) (&hl[0][0])[i] = 0.f;
  __syncthreads();

  float msum = 0.f;
  size_t rowbase = (size_t)seq * T;
  for (int tt = 0; tt < T; tt++){
    int t = dir ? (T-1-tt) : tt;
    int par = tt & 1;
    const float* hr = hl[par];
    float* hw = hl[1-par];

    float xr=0.f, xz=0.f, xn=0.f, hprev=0.f;
    if (comp && l==0){
      const float* xp = xs + (rowbase + t)*(size_t)ncols + dir*450;
      xr = xp[row]; xz = xp[150+row]; xn = xp[300+row];
      hprev = hr[row];
    }

    float a0=0.f, a1=0.f, a2=0.f;
    if (comp){
      #pragma unroll
      for (int i=0;i<KSTEP;i++){
        float hv = hr[k0 + i];
        a0 += w0[i]*hv; a1 += w1[i]*hv; a2 += w2[i]*hv;
      }
    }
    a0 += __shfl_xor(a0,1); a0 += __shfl_xor(a0,2);
    a1 += __shfl_xor(a1,1); a1 += __shfl_xor(a1,2);
    a2 += __shfl_xor(a2,1); a2 += __shfl_xor(a2,2);

    if (comp && l==0){
      float rr = sigm(xr + a0 + bR);
      float zz = sigm(xz + a1 + bZ);
      float nn = tanhf(xn + rr*(a2 + bN));
      float hn = (1.f - zz)*nn + zz*hprev;
      hw[row] = hn;
      msum += hn;
      if (ys) ys[(rowbase + t)*(size_t)300 + dir*150 + row] = hn;
    }
    __syncthreads();
  }
  if (meanOut && comp && l==0)
    meanOut[(size_t)seq*300 + dir*150 + row] = msum / (float)T;
}

// ---------------------------------------------------------------------------
// Big-GRU recurrence, BOTH dirs per launch, time-sliced. Weights in VGPRs
// (unified AGPR file), tagged-pair LLC h exchange, exact f32 hold + HSEED.
// R6-measured-best partition: small per-block message sets, many blocks.
// ---------------------------------------------------------------------------
template<int BLK, int JB, int KC, int Hh>
__global__ __launch_bounds__(BLK)
void gru_big_k(const float* xs0, const float* xs1,
               const float* Whh,         // [2][3*Hh][Hh] f32
               const float* bhh,         // [2][3*Hh]
               u64* hbuf,                // [2 parity][2 dir][B][Hh/2] tagged pairs
               float* hseed,             // [2 dir][B][Hh] exact f32 chunk seed
               float* meanOut, int mean_stride,
               u32 tagbase,
               int TT, int TC, int t0)
{
  constexpr int LPR   = 8;
  constexpr int KSTEP = 2*KC;
  constexpr int HS    = LPR*KSTEP;
  constexpr int HP    = Hh/2;
  constexpr int NPAIR = 4*HP;
  constexpr int RMAX  = (NPAIR + BLK - 1)/BLK;
  constexpr int H3    = 3*Hh;

  __shared__ __align__(16) f16 hstage[2][4*HS];

  int tid = threadIdx.x;
  int jc = blockIdx.x, bg = blockIdx.y, dir = blockIdx.z;
  int j0 = jc * JB;
  int row = tid >> 3, l = tid & 7;
  bool comp = (row < JB);
  int jg = j0 + row;
  int k0 = l * KSTEP;

  const float* Wd = Whh + (size_t)dir*H3*Hh;
  const float* xs = dir ? xs1 : xs0;
  int xoff = dir ? (TT - TC - t0) : t0;

  h2 w0[KC], w1[KC], w2[KC];
  if (comp){
    const float* p0 = Wd + ((size_t)0*Hh + jg)*(size_t)Hh;
    const float* p1 = Wd + ((size_t)1*Hh + jg)*(size_t)Hh;
    const float* p2 = Wd + ((size_t)2*Hh + jg)*(size_t)Hh;
    #pragma unroll
    for (int i=0;i<KC;i++){
      int k = k0 + 2*i;
      h2 a; a.x=(f16)0.f; a.y=(f16)0.f;
      h2 b = a, c = a;
      if (k < Hh){   a.x=(f16)p0[k];   b.x=(f16)p1[k];   c.x=(f16)p2[k]; }
      if (k+1 < Hh){ a.y=(f16)p0[k+1]; b.y=(f16)p1[k+1]; c.y=(f16)p2[k+1]; }
      w0[i]=a; w1[i]=b; w2[i]=c;
    }
  } else {
    #pragma unroll
    for (int i=0;i<KC;i++){
      h2 z; z.x=(f16)0.f; z.y=(f16)0.f;
      w0[i]=z; w1[i]=z; w2[i]=z;
    }
  }
  float br=0.f, bz=0.f, bn_=0.f;
  if (comp && l < 4){
    br = bhh[(size_t)dir*H3 + jg];
    bz = bhh[(size_t)dir*H3 + Hh + jg];
    bn_= bhh[(size_t)dir*H3 + 2*Hh + jg];
  }

  {
    f16* hz = &hstage[0][0];
    for (int i = tid; i < 2*4*HS; i += BLK) hz[i] = (f16)0.f;
  }

  float msum_own = 0.f;
  float hold_own = 0.f;                  // batch s = l ownership (l < 4)
  if (t0 > 0 && comp && l < 4){
    const float* hs = hseed + (size_t)dir*Bn*Hh;
    hold_own = hs[(size_t)(bg*4+l)*Hh + jg];
  }
  __syncthreads();

  for (int tt = 0; tt < TC; tt++){
    int g = t0 + tt;
    int t = dir ? (TT-1-g) : g;
    int par = g & 1;
    const u64* hrd = hbuf + (size_t)(par*2 + dir)*Bn*HP;
    u64*       hwr = hbuf + (size_t)((1-par)*2 + dir)*Bn*HP;
    f16* hsb = hstage[par];

    u64 tmp[RMAX];
    const u64* hb = hrd + (size_t)(bg*4)*HP;
    if (g != 0){
      #pragma unroll
      for (int r=0;r<RMAX;r++){
        int idx = tid + r*BLK;
        if (idx < NPAIR) tmp[r] = llc_load64(&hb[idx]);
      }
    }

    // xs prefetch: lane l<4 loads batch l only (3 loads, overlaps tag check)
    float xr=0.f, xz=0.f, xn=0.f;
    if (comp && l < 4){
      const float* xp = xs + ((size_t)(bg*4+l)*TC + (t - xoff))*(size_t)H3;
      xr = xp[jg]; xz = xp[Hh+jg]; xn = xp[2*Hh+jg];
    }

    if (g != 0){
      u32 want = tagbase + (u32)g;
      u32 pend = 0;
      #pragma unroll
      for (int r=0;r<RMAX;r++){
        int idx = tid + r*BLK;
        if (idx < NPAIR && (u32)(tmp[r] >> 32) != want) pend |= (1u << r);
      }
      int guard = 0;
      while (pend){
        __builtin_amdgcn_s_sleep(1);
        #pragma unroll
        for (int r=0;r<RMAX;r++)
          if (pend & (1u << r)) tmp[r] = llc_load64(&hb[tid + r*BLK]);
        #pragma unroll
        for (int r=0;r<RMAX;r++)
          if ((pend & (1u << r)) && (u32)(tmp[r] >> 32) == want) pend &= ~(1u << r);
        if (++guard > 200000) break;   // failsafe: wrong result > GPU hang
      }
      #pragma unroll
      for (int r=0;r<RMAX;r++){
        int idx = tid + r*BLK;
        if (idx < NPAIR){
          int s = idx / HP, jp = idx - s*HP;
          union { u32 i; h2 h; } u; u.i = (u32)tmp[r];
          *(h2*)(hsb + s*HS + 2*jp) = u.h;
        }
      }
    }
    __syncthreads();

    float a0[4]={0,0,0,0}, a1[4]={0,0,0,0}, a2[4]={0,0,0,0};
    if (comp){
      const f16* hp = hsb + k0;
      #pragma unroll
      for (int i=0;i<KC;i++){
        const int kk = 2*i;
        h2 hv0 = *(const h2*)(hp + 0*HS + kk);
        h2 hv1 = *(const h2*)(hp + 1*HS + kk);
        h2 hv2 = *(const h2*)(hp + 2*HS + kk);
        h2 hv3 = *(const h2*)(hp + 3*HS + kk);
        a0[0]=FDOT2(w0[i],hv0,a0[0]); a0[1]=FDOT2(w0[i],hv1,a0[1]);
        a0[2]=FDOT2(w0[i],hv2,a0[2]); a0[3]=FDOT2(w0[i],hv3,a0[3]);
        a1[0]=FDOT2(w1[i],hv0,a1[0]); a1[1]=FDOT2(w1[i],hv1,a1[1]);
        a1[2]=FDOT2(w1[i],hv2,a1[2]); a1[3]=FDOT2(w1[i],hv3,a1[3]);
        a2[0]=FDOT2(w2[i],hv0,a2[0]); a2[1]=FDOT2(w2[i],hv1,a2[1]);
        a2[2]=FDOT2(w2[i],hv2,a2[2]); a2[3]=FDOT2(w2[i],hv3,a2[3]);
      }
    }
    #pragma unroll
    for (int s=0;s<4;s++){
      a0[s] += __shfl_xor(a0[s],1); a0[s] += __shfl_xor(a0[s],2); a0[s] += __shfl_xor(a0[s],4);
      a1[s] += __shfl_xor(a1[s],1); a1[s] += __shfl_xor(a1[s],2); a1[s] += __shfl_xor(a1[s],4);
      a2[s] += __shfl_xor(a2[s],1); a2[s] += __shfl_xor(a2[s],2); a2[s] += __shfl_xor(a2[s],4);
    }
    // select own batch's sums via cndmask chain (no runtime array index)
    float t0a = (l & 1) ? a0[1] : a0[0], t0b = (l & 1) ? a0[3] : a0[2];
    float A0 = (l & 2) ? t0b : t0a;
    float t1a = (l & 1) ? a1[1] : a1[0], t1b = (l & 1) ? a1[3] : a1[2];
    float A1 = (l & 2) ? t1b : t1a;
    float t2a = (l & 1) ? a2[1] : a2[0], t2b = (l & 1) ? a2[3] : a2[2];
    float A2 = (l & 2) ? t2b : t2a;

    float hn_own = 0.f;
    if (comp && l < 4){
      float rr = sigm(xr + A0 + br);
      float zz = sigm(xz + A1 + bz);
      float nn = tanhf(xn + rr*(A2 + bn_));
      hn_own = (1.f - zz)*nn + zz*hold_own;
      hold_own = hn_own;
      msum_own += hn_own;
    }
    // pair adjacent rows: even row's lane l grabs odd row's hn (lane+8)
    u32 wtag = tagbase + (u32)g + 1u;
    float hp2 = __shfl_down(hn_own, 8);
    if (comp && l < 4 && !(row & 1)){
      h2 pk; pk.x = (f16)hn_own; pk.y = (f16)hp2;
      union { h2 h; u32 i; } u; u.h = pk;
      llc_store64(&hwr[(size_t)(bg*4+l)*HP + ((unsigned)(j0+row) >> 1)],
                  ((u64)wtag << 32) | (u64)u.i);
    }
    if (tt == TC-1 && comp && l < 4){
      float* hs = hseed + (size_t)dir*Bn*Hh;
      hs[(size_t)(bg*4+l)*Hh + jg] = hold_own;
    }
  }
  if (comp && l < 4){
    float* mp = meanOut + (size_t)(bg*4+l)*mean_stride + dir*Hh + jg;
    *mp += msum_own / (float)TT;
  }
}

// ---------------------------------------------------------------------------
// mask_att + fact_sep fused: per (b, 8-t chunk). Softmax/ratio 32-lane par.
// ---------------------------------------------------------------------------
__global__ __launch_bounds__(256)
void mask_att_k(const float* ctx, const float* vh, float* simOut, float* diffOut)
{
  __shared__ float vhl[50*300];
  __shared__ float ctxl[8*300];
  __shared__ float attl[8*52];
  __shared__ float scenl[8*300];
  __shared__ float ratio[8];
  int tid = threadIdx.x;
  int b = blockIdx.y, tc = blockIdx.x;
  int grp = tid >> 5, ln = tid & 31;        // 8 groups x 32 lanes
  size_t cbase = ((size_t)b*Tn + tc*8) * 300;
  for (int i = tid; i < 15000; i += 256) vhl[i] = vh[(size_t)b*15000 + i];
  for (int i = tid; i < 2400; i += 256)  ctxl[i] = ctx[cbase + i];
  __syncthreads();
  for (int p = tid; p < 400; p += 256){
    int ttl = p / 50, v = p % 50;
    const float* cp = ctxl + ttl*300;
    const float* vp = vhl + v*300;
    float acc = 0.f;
    for (int d = 0; d < 300; d++) acc += cp[d]*vp[d];
    attl[ttl*52 + v] = acc;
  }
  __syncthreads();
  // masked softmax over v=0..50 per row (group grp owns row grp)
  {
    float mx = -INFINITY;
    for (int v = ln; v < 50; v += 32){
      float a = attl[grp*52+v];
      float msk = (a == 0.f) ? -INFINITY : a;
      attl[grp*52+v] = msk;
      mx = fmaxf(mx, msk);
    }
    #pragma unroll
    for (int m=1; m<32; m<<=1) mx = fmaxf(mx, __shfl_xor(mx, m));
    if (mx == -INFINITY){
      for (int v = ln; v < 50; v += 32) attl[grp*52+v] = 0.f;
    } else {
      float sum = 0.f;
      for (int v = ln; v < 50; v += 32){
        float e = expf(attl[grp*52+v] - mx);
        attl[grp*52+v] = e;
        sum += e;
      }
      #pragma unroll
      for (int m=1; m<32; m<<=1) sum += __shfl_xor(sum, m);
      float inv = 1.f/sum;
      for (int v = ln; v < 50; v += 32) attl[grp*52+v] *= inv;
    }
  }
  __syncthreads();
  for (int p = tid; p < 2400; p += 256){
    int ttl = p / 300, d = p % 300;
    float acc = 0.f;
    for (int v=0; v<50; v++) acc += attl[ttl*52+v] * vhl[v*300+d];
    scenl[p] = acc;
  }
  __syncthreads();
  // ratio = <ctx,scen>/<scen,scen> per row, 32-lane parallel dot
  {
    float x3 = 0.f, x4 = 0.f;
    for (int d = ln; d < 300; d += 32){
      float s = scenl[grp*300+d];
      x3 += ctxl[grp*300+d]*s; x4 += s*s;
    }
    #pragma unroll
    for (int m=1; m<32; m<<=1){ x3 += __shfl_xor(x3, m); x4 += __shfl_xor(x4, m); }
    if (ln == 0) ratio[grp] = x3 / (x4 + 1e-10f);
  }
  __syncthreads();
  for (int p = tid; p < 2400; p += 256){
    float sim = ratio[p/300] * scenl[p];
    simOut[cbase + p]  = sim;
    diffOut[cbase + p] = ctxl[p] - sim;
  }
}

// ---------------------------------------------------------------------------
// code_wise helpers
// ---------------------------------------------------------------------------
__global__ __launch_bounds__(256)
void softmaxT_k(const float* m, float* att){
  __shared__ float red[256];
  int b = blockIdx.x, tid = threadIdx.x;
  float v1 = m[b*512 + tid], v2 = m[b*512 + 256 + tid];
  red[tid] = fmaxf(v1, v2); __syncthreads();
  for (int s=128; s; s>>=1){ if (tid<s) red[tid] = fmaxf(red[tid], red[tid+s]); __syncthreads(); }
  float M = red[0]; __syncthreads();
  float e1 = expf(v1-M), e2 = expf(v2-M);
  red[tid] = e1+e2; __syncthreads();
  for (int s=128; s; s>>=1){ if (tid<s) red[tid] += red[tid+s]; __syncthreads(); }
  float inv = 1.f / red[0];
  att[b*512+tid] = e1*inv; att[b*512+256+tid] = e2*inv;
}

// t split over 8 blocks (grid (32,8)), partial sums via atomicAdd; out zeroed.
__global__ __launch_bounds__(256)
void wsum_k(const float* att, const float* dh, float* out){
  int b = blockIdx.x, c = blockIdx.y, tid = threadIdx.x;
  int t0 = c * 64;
  for (int d = tid; d < 300; d += 256){
    float acc = 0.f;
    #pragma unroll 8
    for (int t = t0; t < t0 + 64; t++)
      acc += att[b*512+t] * dh[((size_t)b*512 + t)*300 + d];
    atomicAdd(&out[b*300+d], acc);
  }
}

// ---------------------------------------------------------------------------
// graph_decomp helpers
// ---------------------------------------------------------------------------
__global__ void count_k(const int* src, int E, float* counts){
  int e = blockIdx.x*256 + threadIdx.x;
  if (e < E) atomicAdd(&counts[src[e]], 1.f);
}
__global__ void coef_k(const float* L, const int* src, const int* dst, int E, float* coef){
  int e = blockIdx.x*4 + (threadIdx.x >> 6);
  int lane = threadIdx.x & 63;
  if (e >= E) return;
  const float* Li = L + (size_t)src[e]*300;
  const float* Lj = L + (size_t)dst[e]*300;
  float num = 0.f, den = 0.f;
  for (int d = lane; d < 300; d += 64){ float lj = Lj[d]; num += Li[d]*lj; den += lj*lj; }
  for (int off = 32; off; off >>= 1){ num += __shfl_xor(num, off, 64); den += __shfl_xor(den, off, 64); }
  if (lane == 0) coef[e] = num / (den + 1e-10f);
}
__global__ void agg_k(const float* L, const int* src, const int* dst, const float* coef, int E, float* agg){
  int e = blockIdx.x;
  float c = coef[e];
  const float* Lj = L + (size_t)dst[e]*300;
  float* ag = agg + (size_t)src[e]*300;
  for (int d = threadIdx.x; d < 300; d += 256) atomicAdd(&ag[d], c*Lj[d]);
}
__global__ void upd_k(const float* L, const float* agg, const float* counts, float* out, int n){
  int i = blockIdx.x;
  float c = counts[i];
  for (int d = threadIdx.x; d < 300; d += 256){
    float v = L[(size_t)i*300+d];
    out[(size_t)i*300+d] = (c > 0.f) ? v - agg[(size_t)i*300+d]/fmaxf(c, 1.f) : v;
  }
}

// ---------------------------------------------------------------------------
// classifier heads: one 64-lane wave per (b, c), k strided by lane.
// ---------------------------------------------------------------------------
__global__ __launch_bounds__(256)
void logits_k(const float* A0, const float* A1, const float* A2, int srcw,
              const float* W, const float* bias, int C, int K,
              float* outF){
  int b = blockIdx.x;
  int c = blockIdx.y*4 + (threadIdx.x >> 6);
  int lane = threadIdx.x & 63;
  if (c >= C) return;
  const float* wp = W + (size_t)c*K;
  float acc = 0.f;
  for (int k = lane; k < K; k += 64){
    int s = k / srcw; int kk = k - s*srcw;
    const float* Ap = (s==0) ? A0 : ((s==1) ? A1 : A2);
    acc += Ap[(size_t)b*srcw + kk] * wp[k];
  }
  for (int off = 32; off; off >>= 1) acc += __shfl_xor(acc, off, 64);
  if (lane == 0) outF[b*C + c] = acc + bias[c];
}
__global__ void argmax_k(const float* lf, int C, int* pred){
  int b = threadIdx.x;
  if (b < 32){
    const float* p = lf + (size_t)b*C;
    int best = 0; float bv = p[0];
    for (int c = 1; c < C; c++){ float v = p[c]; if (v > bv){ bv = v; best = c; } }
    pred[b] = best;
  }
}
__global__ void vtok_k(const int* table, const int* pred, int* vt, int L){
  int i = blockIdx.x*256 + threadIdx.x;
  if (i < 32*L) vt[i] = table[pred[i/L]*L + i%L];
}

// ---------------------------------------------------------------------------
extern "C" void kernel_launch(void* const* d_in, const int* in_sizes, int n_in,
                              void* d_out, int out_size, void* d_ws, size_t ws_size,
                              hipStream_t stream)
{
  (void)in_sizes; (void)n_in; (void)out_size;
  const float* E        = (const float*)d_in[0];
  const int* chTok    = (const int*)d_in[1];
  const int* arTok    = (const int*)d_in[2];
  const int* docs     = (const int*)d_in[3];
  const int* chVerd   = (const int*)d_in[4];
  const int* arVerd   = (const int*)d_in[5];
  const int* c_src    = (const int*)d_in[6];
  const int* c_dst    = (const int*)d_in[7];
  const int* a_src    = (const int*)d_in[8];
  const int* a_dst    = (const int*)d_in[9];
  const float* enc_Wih  = (const float*)d_in[10];
  const float* enc_Whh  = (const float*)d_in[11];
  const float* enc_bih  = (const float*)d_in[12];
  const float* enc_bhh  = (const float*)d_in[13];
  const float* ech_Wih  = (const float*)d_in[14];
  const float* ech_Whh  = (const float*)d_in[15];
  const float* ech_bih  = (const float*)d_in[16];
  const float* ech_bhh  = (const float*)d_in[17];
  const float* term_Wih = (const float*)d_in[18];
  const float* term_Whh = (const float*)d_in[19];
  const float* term_bih = (const float*)d_in[20];
  const float* term_bhh = (const float*)d_in[21];
  const float* art_Wih  = (const float*)d_in[22];
  const float* art_Whh  = (const float*)d_in[23];
  const float* art_bih  = (const float*)d_in[24];
  const float* art_bhh  = (const float*)d_in[25];
  const float* W_charge = (const float*)d_in[26];
  const float* b_charge = (const float*)d_in[27];
  const float* W_article= (const float*)d_in[28];
  const float* b_article= (const float*)d_in[29];
  const float* W_time   = (const float*)d_in[30];
  const float* b_time   = (const float*)d_in[31];
  float* out = (float*)d_out;
  float* OUTC = out;            // [32][119]
  float* OUTA = out + 3808;     // [32][103]
  float* OUTT = out + 7104;     // [32][11]

  char* wsb = (char*)d_ws;
  size_t off = 0;
  auto alloc = [&](size_t nf)->float* {
    float* p = (float*)(wsb + off);
    off += ((nf*4 + 255) & ~(size_t)255);
    return p;
  };
  float* XS0   = alloc(14745600ULL);        // 59.0 MB
  float* XS1   = alloc(14745600ULL);        // 59.0 MB
  float* DH    = alloc(4915200);            // d_hidden [32][512][300]
  float* ADC   = alloc(4915200);            // adc, later dsc
  float* SEC   = alloc(4915200);
  float* SSC   = alloc(4915200);
  float* VHYS  = alloc(480000);             // [32][50][300]
  float* MECH  = alloc(66600);              // encch means [222][300]
  float* LC1   = alloc(35700);
  float* LC0   = alloc(35700);
  float* LA1   = alloc(30900);
  float* LA0   = alloc(30900);
  float* AGG   = alloc(35700);
  float* CNTS  = alloc(256);                // counts_c @0, counts_a @128
  float* COEF  = alloc(640);
  float* DHC   = alloc(9600);               // DHC,DA,DHNA,DB contiguous (1 memset)
  float* DA    = alloc(9600);
  float* DHNA  = alloc(9600);
  float* DB    = alloc(9600);
  float* MDH   = alloc(9600);               // mean_t d_hidden [32][300]
  float* MFA   = alloc(38400);              // fa mean [32][1200] (accumulated)
  float* MTH   = alloc(28800);              // th mean [32][900] (accumulated)
  float* RB    = alloc(115200);             // art rowbias [32][3600]
  float* RMX   = alloc(16384);
  float* ATTB  = alloc(16384);
  u64*   HBUF  = (u64*)alloc(76800);        // [2][2][32][300] u64 tagged pairs
  float* HSEED = alloc(38400);              // [2][32][600] exact f32 seeds
  int*   PREDC = (int*)alloc(64);
  int*   PREDA = (int*)alloc(64);
  int*   VTOK  = (int*)alloc(1600);
  int*   TCC   = (int*)alloc(11104);

  if (off > ws_size) return;   // diagnostic: leaves out==0 -> absmax==max|ref|

  hipMemsetAsync(HBUF, 0, 2*2*Bn*300*sizeof(u64), stream);  // tags = 0
  hipMemsetAsync(CNTS, 0, 256*4, stream);
  hipMemsetAsync(DHC, 0, 4*9600*4, stream);   // DHC..DB contiguous

  // --- encch on charge+article token sequences (222 seqs, L=50) ---
  hipMemcpyAsync(TCC, chTok, NCn*LCn*4, hipMemcpyDeviceToDevice, stream);
  hipMemcpyAsync(TCC + NCn*LCn, arTok, NAn*LCn*4, hipMemcpyDeviceToDevice, stream);
  embed_mfma_k<<<dim3(8,87),256,0,stream>>>(E, TCC, ech_Wih, ech_bih,
      XS0, 11100, 900, 200);
  gru_small_k<<<dim3(222,2),640,0,stream>>>(XS0, 900, ech_Whh, ech_bhh, nullptr, MECH, 50);

  // --- enc on documents ---
  embed_mfma_k<<<dim3(8,128),256,0,stream>>>(E, docs, enc_Wih, enc_bih,
      XS0, 16384, 900, 200);
  gru_small_k<<<dim3(32,2),640,0,stream>>>(XS0, 900, enc_Whh, enc_bhh, DH, MDH, 512);

  // --- graph_decomp (charge, article), 2 layers each ---
  count_k<<<3,256,0,stream>>>(c_src, ECn, CNTS);
  count_k<<<2,256,0,stream>>>(a_src, EAn, CNTS+128);
  coef_k<<<150,256,0,stream>>>(MECH, c_src, c_dst, ECn, COEF);
  hipMemsetAsync(AGG, 0, 35700*4, stream);
  agg_k<<<ECn,256,0,stream>>>(MECH, c_src, c_dst, COEF, ECn, AGG);
  upd_k<<<NCn,256,0,stream>>>(MECH, AGG, CNTS, LC1, NCn);
  coef_k<<<150,256,0,stream>>>(LC1, c_src, c_dst, ECn, COEF);
  hipMemsetAsync(AGG, 0, 35700*4, stream);
  agg_k<<<ECn,256,0,stream>>>(LC1, c_src, c_dst, COEF, ECn, AGG);
  upd_k<<<NCn,256,0,stream>>>(LC1, AGG, CNTS, LC0, NCn);

  const float* MEAR = MECH + (size_t)NCn*300;
  coef_k<<<125,256,0,stream>>>(MEAR, a_src, a_dst, EAn, COEF);
  hipMemsetAsync(AGG, 0, 30900*4, stream);
  agg_k<<<EAn,256,0,stream>>>(MEAR, a_src, a_dst, COEF, EAn, AGG);
  upd_k<<<NAn,256,0,stream>>>(MEAR, AGG, CNTS+128, LA1, NAn);
  coef_k<<<125,256,0,stream>>>(LA1, a_src, a_dst, EAn, COEF);
  hipMemsetAsync(AGG, 0, 30900*4, stream);
  agg_k<<<EAn,256,0,stream>>>(LA1, a_src, a_dst, COEF, EAn, AGG);
  upd_k<<<NAn,256,0,stream>>>(LA1, AGG, CNTS+128, LA0, NAn);

  // --- code_wise x4: fused score+rowmax (S never materialized) ---
  auto codewise = [&](const float* q, int Nq, float* outv){
    score_rowmax_k<<<128,256,0,stream>>>(DH, q, Nq, RMX);
    softmaxT_k<<<32,256,0,stream>>>(RMX, ATTB);
    wsum_k<<<dim3(32,8),256,0,stream>>>(ATTB, DH, outv);
  };
  codewise(LC0,  NCn, DHC);    // new_charge
  codewise(MECH, NCn, DA);     // ori charge
  codewise(LA0,  NAn, DHNA);   // new_article
  codewise(MEAR, NAn, DB);     // ori article

  // --- charge head ---
  logits_k<<<dim3(32,30),256,0,stream>>>(MDH, DHC, DA, 300, W_charge, b_charge, NCn, 900, OUTC);
  argmax_k<<<1,64,0,stream>>>(OUTC, NCn, PREDC);

  // --- fact_sep #1 ---
  vtok_k<<<7,256,0,stream>>>(chVerd, PREDC, VTOK, LVn);
  embed_mfma_k<<<dim3(8,13),256,0,stream>>>(E, VTOK, enc_Wih, enc_bih,
      XS0, 1600, 900, 200);
  gru_small_k<<<dim3(32,2),640,0,stream>>>(XS0, 900, enc_Whh, enc_bhh, VHYS, nullptr, 50);
  mask_att_k<<<dim3(64,32),256,0,stream>>>(DH, VHYS, ADC, SEC);

  // --- article bigru: rowbias, then time-sliced dual-dir chunks ---
  {
    dim3 g((3600+127)/128, 1);
    gemm_k<0><<<g,256,0,stream>>>(DHNA, DB, nullptr, nullptr, nullptr,
        art_Wih, 1200, 300, 900, 0, art_bih, nullptr, 1, 1, IDIV,0,0,
        RB, 32, 3600, 600);
  }
  hipMemsetAsync(MFA, 0, 38400*4, stream);
  for (int L = 0; L < 2; L++){
    stage_mfma_k<<<dim3(15,64),256,0,stream>>>(DH, ADC, nullptr,
        art_Wih, 1200, 0, 600, 0,
        nullptr, RB, 3600, 256*L,
        XS0, 1800, 600);
    stage_mfma_k<<<dim3(15,64),256,0,stream>>>(DH, ADC, nullptr,
        art_Wih + (size_t)1800*1200, 1200, 0, 600, 0,
        nullptr, RB + 1800, 3600, 256*(1-L),
        XS1, 1800, 600);
    gru_big_k<384,40,38,600><<<dim3(15,8,2),384,0,stream>>>(XS0, XS1,
        art_Whh, art_bhh, HBUF, HSEED, MFA, 1200, 0u,
        512, 256, 256*L);
  }
  logits_k<<<dim3(32,26),256,0,stream>>>(MFA, nullptr, nullptr, 1200, W_article, b_article, NAn, 1200, OUTA);
  argmax_k<<<1,64,0,stream>>>(OUTA, NAn, PREDA);

  // --- fact_sep #2 (context = sec_vector) ---
  vtok_k<<<7,256,0,stream>>>(arVerd, PREDA, VTOK, LVn);
  embed_mfma_k<<<dim3(8,13),256,0,stream>>>(E, VTOK, enc_Wih, enc_bih,
      XS0, 1600, 900, 200);
  gru_small_k<<<dim3(32,2),640,0,stream>>>(XS0, 900, enc_Whh, enc_bhh, VHYS, nullptr, 50);
  mask_att_k<<<dim3(64,32),256,0,stream>>>(SEC, VHYS, SSC, ADC);   // ssc, dsc(=ADC)

  // --- term bigru, time-sliced dual-dir chunks ---
  hipMemsetAsync(MTH, 0, 28800*4, stream);
  for (int L = 0; L < 2; L++){
    stage_mfma_k<<<dim3(11,64),256,0,stream>>>(DH, SSC, ADC,
        term_Wih, 900, 0, 300, 600,
        term_bih, nullptr, 0, 256*L,
        XS0, 1350, 900);
    stage_mfma_k<<<dim3(11,64),256,0,stream>>>(DH, SSC, ADC,
        term_Wih + (size_t)1350*900, 900, 0, 300, 600,
        term_bih + 1350, nullptr, 0, 256*(1-L),
        XS1, 1350, 900);
    gru_big_k<448,50,29,450><<<dim3(9,8,2),448,0,stream>>>(XS0, XS1,
        term_Whh, term_bhh, HBUF, HSEED, MTH, 900, 512u,
        512, 256, 256*L);
  }
  logits_k<<<dim3(32,3),256,0,stream>>>(MTH, nullptr, nullptr, 900, W_time, b_time, NTn, 900, OUTT);
}

// Round 11
// 9456.760 us; speedup vs baseline: 1.7587x; 1.1918x over previous
//
#include <hip/hip_runtime.h>
#include <stdint.h>
#include <math.h>

typedef unsigned int u32;
typedef unsigned long long u64;
typedef _Float16 f16;
typedef _Float16 h4 __attribute__((ext_vector_type(4)));
typedef _Float16 h2 __attribute__((ext_vector_type(2)));
typedef _Float16 h8 __attribute__((ext_vector_type(8)));
typedef float f4 __attribute__((ext_vector_type(4)));

// Problem constants
#define Vn     50000
#define DEMBn  200
#define Hn     150
#define NCn    119
#define NAn    103
#define NTn    11
#define Bn     32
#define Tn     512
#define LCn    50
#define LVn    50
#define ECn    600
#define EAn    500

#define IDIV 1073741824 // identity arow mapping

__device__ __forceinline__ float sigm(float x){ return 1.0f / (1.0f + expf(-x)); }

#if __has_builtin(__builtin_amdgcn_fdot2)
__device__ __forceinline__ float FDOT2(h2 a, h2 b, float c){
  return __builtin_amdgcn_fdot2(a, b, c, false);
}
#else
__device__ __forceinline__ float FDOT2(h2 a, h2 b, float c){
  return c + (float)a.x*(float)b.x + (float)a.y*(float)b.y;
}
#endif

// LLC-coherent agent-scope 64-bit ops (bypass non-coherent L1/L2).
__device__ __forceinline__ u64 llc_load64(const u64* p){
  return __hip_atomic_load(p, __ATOMIC_RELAXED, __HIP_MEMORY_SCOPE_AGENT);
}
__device__ __forceinline__ void llc_store64(u64* p, u64 v){
  __hip_atomic_store(p, v, __ATOMIC_RELAXED, __HIP_MEMORY_SCOPE_AGENT);
}

// ---------------------------------------------------------------------------
// Tiled fp32 GEMM (small cases): C[M][N] = A[arow(m)][K] @ B[N][K]^T
// ---------------------------------------------------------------------------
template<int AMODE>
__global__ __launch_bounds__(256)
void gemm_k(const float* A0, const float* A1, const float* A2,
            const float* Etab, const int* tok,
            const float* Bm, int ldb, int bc0, int bc1, int bc2,
            const float* bias, const float* rowbias, int rb_div, int rb_stride,
            int arow_div, int arow_stride, int arow_off,
            float* C, int M, int N, int K)
{
  __shared__ float As[8][132];
  __shared__ float Bs[8][132];
  __shared__ int tokS[128];
  int tid = threadIdx.x;
  int m0 = blockIdx.y * 128, n0 = blockIdx.x * 128;
  if (AMODE == 1){
    for (int i = tid; i < 128; i += 256){
      int m = m0 + i;
      tokS[i] = (m < M) ? tok[m] : 0;
    }
  }
  __syncthreads();
  float acc[8][8];
  #pragma unroll
  for (int i=0;i<8;i++)
    #pragma unroll
    for (int j=0;j<8;j++) acc[i][j] = 0.f;

  int tx = tid & 15, ty = tid >> 4;

  for (int k0 = 0; k0 < K; k0 += 8){
    #pragma unroll
    for (int r = 0; r < 4; r++){
      int i = tid + 256*r;          // [0,1024)
      int ml = i >> 3, kl = i & 7;
      int k = k0 + kl;
      {
        int m = m0 + ml;
        float v = 0.f;
        if (m < M && k < K){
          if (AMODE == 0){
            int s = k / 300; int kk = k - s*300;
            const float* Ap = (s==0) ? A0 : ((s==1) ? A1 : A2);
            int ar = (m / arow_div)*arow_stride + (m % arow_div) + arow_off;
            v = Ap[(size_t)ar*300 + kk];
          } else {
            v = Etab[(size_t)tokS[ml]*DEMBn + k];
          }
        }
        As[kl][ml] = v;
      }
      {
        int n = n0 + ml;
        float v = 0.f;
        if (n < N && k < K){
          int col;
          if (AMODE == 0){ int s = k / 300; int kk = k - s*300; col = ((s==0)?bc0:((s==1)?bc1:bc2)) + kk; }
          else col = k;
          v = Bm[(size_t)n*ldb + col];
        }
        Bs[kl][ml] = v;
      }
    }
    __syncthreads();
    #pragma unroll
    for (int kk = 0; kk < 8; kk++){
      float a[8], b[8];
      #pragma unroll
      for (int i=0;i<8;i++) a[i] = As[kk][ty*8+i];
      #pragma unroll
      for (int i=0;i<8;i++) b[i] = Bs[kk][tx*8+i];
      #pragma unroll
      for (int i=0;i<8;i++)
        #pragma unroll
        for (int j=0;j<8;j++) acc[i][j] += a[i]*b[j];
    }
    __syncthreads();
  }
  #pragma unroll
  for (int i=0;i<8;i++){
    int m = m0 + ty*8 + i; if (m >= M) continue;
    #pragma unroll
    for (int j=0;j<8;j++){
      int n = n0 + tx*8 + j; if (n >= N) continue;
      float v = acc[i][j];
      if (bias)    v += bias[n];
      if (rowbias) v += rowbias[(size_t)(m / rb_div)*rb_stride + n];
      C[(size_t)m*N + n] = v;
    }
  }
}

// ---------------------------------------------------------------------------
// Fused code_wise score + row-max: RMX[m] = max_n (DH[m]. q[n]) for n<Nq.
// Nq <= 128 so one block covers the full row; S never materialized.
// ---------------------------------------------------------------------------
__global__ __launch_bounds__(256)
void score_rowmax_k(const float* A, const float* Bq, int Nq, float* RMX)
{
  __shared__ float As[8][132];
  __shared__ float Bs[8][132];
  int tid = threadIdx.x;
  int m0 = blockIdx.x * 128;
  float acc[8][8];
  #pragma unroll
  for (int i=0;i<8;i++)
    #pragma unroll
    for (int j=0;j<8;j++) acc[i][j] = 0.f;
  int tx = tid & 15, ty = tid >> 4;

  for (int k0 = 0; k0 < 300; k0 += 8){
    #pragma unroll
    for (int r = 0; r < 4; r++){
      int i = tid + 256*r;
      int ml = i >> 3, kl = i & 7;
      int k = k0 + kl;
      As[kl][ml] = (k < 300) ? A[(size_t)(m0 + ml)*300 + k] : 0.f;
      Bs[kl][ml] = (ml < Nq && k < 300) ? Bq[(size_t)ml*300 + k] : 0.f;
    }
    __syncthreads();
    #pragma unroll
    for (int kk = 0; kk < 8; kk++){
      float a[8], b[8];
      #pragma unroll
      for (int i=0;i<8;i++) a[i] = As[kk][ty*8+i];
      #pragma unroll
      for (int i=0;i<8;i++) b[i] = Bs[kk][tx*8+i];
      #pragma unroll
      for (int i=0;i<8;i++)
        #pragma unroll
        for (int j=0;j<8;j++) acc[i][j] += a[i]*b[j];
    }
    __syncthreads();
  }
  #pragma unroll
  for (int i=0;i<8;i++){
    float mx = -INFINITY;
    #pragma unroll
    for (int j=0;j<8;j++){
      int n = tx*8 + j;
      if (n < Nq) mx = fmaxf(mx, acc[i][j]);
    }
    mx = fmaxf(mx, __shfl_xor(mx, 1));
    mx = fmaxf(mx, __shfl_xor(mx, 2));
    mx = fmaxf(mx, __shfl_xor(mx, 4));
    mx = fmaxf(mx, __shfl_xor(mx, 8));
    if (tx == 0) RMX[m0 + ty*8 + i] = mx;
  }
}

// ---------------------------------------------------------------------------
// MFMA split-f16 staging GEMM for the big xs gemms (art/term).
// R11: staging loads widened to float2 — (k,k+1) pairs are provably
// same-segment (boundaries at even 300) and jointly in-bounds (K even),
// offsets even -> 8B-aligned global_load_dwordx2.
// ---------------------------------------------------------------------------
__global__ __launch_bounds__(256)
void stage_mfma_k(const float* A0, const float* A1, const float* A2,
                  const float* Bm, int ldb, int bc0, int bc1, int bc2,
                  const float* bias, const float* rowbias, int rb_stride,
                  int arow_off,
                  float* C, int N, int K)
{
  constexpr int KP = 40;                    // f16 row stride (80B: 16B-aligned rows)
  __shared__ __align__(16) f16 Ah[128*KP];
  __shared__ __align__(16) f16 Al[128*KP];
  __shared__ __align__(16) f16 Bh[128*KP];
  __shared__ __align__(16) f16 Bl[128*KP];

  int tid = threadIdx.x;
  int n0 = blockIdx.x * 128, m0 = blockIdx.y * 128;
  int lane = tid & 63, w = tid >> 6;
  int wr = (w >> 1) * 64, wc = (w & 1) * 64;   // wave tile origin in block tile
  int li = lane & 15, lk = (lane >> 4) * 8;

  f4 acc[4][4];
  #pragma unroll
  for (int i=0;i<4;i++)
    #pragma unroll
    for (int j=0;j<4;j++) acc[i][j] = (f4){0.f,0.f,0.f,0.f};

  int srow = tid >> 1, scb = (tid & 1) << 4;   // staging: row, col-base (16 k each)
  int sm = m0 + srow;
  size_t abase = (size_t)(((sm >> 8) * 512) + (sm & 255) + arow_off) * 300;
  int sn = n0 + srow;

  for (int k0 = 0; k0 < K; k0 += 32){
    // ---- stage A,B k-tile as hi/lo f16 (float2 loads) ----
    #pragma unroll
    for (int q = 0; q < 16; q += 2){
      float2 va = {0.f, 0.f}, vb = {0.f, 0.f};
      int k = k0 + scb + q;                  // even; pair (k,k+1) same segment
      if (k < K){
        int s = (k >= 600) ? 2 : ((k >= 300) ? 1 : 0);
        int kk = k - s*300;
        const float* Ap = (s==0) ? A0 : ((s==1) ? A1 : A2);
        va = *(const float2*)&Ap[abase + kk];
        if (sn < N) vb = *(const float2*)&Bm[(size_t)sn*ldb + ((s==0)?bc0:((s==1)?bc1:bc2)) + kk];
      }
      f16 a0h=(f16)va.x, a1h=(f16)va.y, b0h=(f16)vb.x, b1h=(f16)vb.y;
      f16 a0l=(f16)(va.x-(float)a0h), a1l=(f16)(va.y-(float)a1h);
      f16 b0l=(f16)(vb.x-(float)b0h), b1l=(f16)(vb.y-(float)b1h);
      int off = srow*KP + scb + q;
      *(h2*)&Ah[off] = (h2){a0h, a1h};
      *(h2*)&Al[off] = (h2){a0l, a1l};
      *(h2*)&Bh[off] = (h2){b0h, b1h};
      *(h2*)&Bl[off] = (h2){b0l, b1l};
    }
    __syncthreads();

    // ---- fragments + 3-pass MFMA ----
    h8 fah[4], fal[4], fbh[4], fbl[4];
    #pragma unroll
    for (int f = 0; f < 4; f++){
      fah[f] = *(const h8*)&Ah[(wr + f*16 + li)*KP + lk];
      fal[f] = *(const h8*)&Al[(wr + f*16 + li)*KP + lk];
      fbh[f] = *(const h8*)&Bh[(wc + f*16 + li)*KP + lk];
      fbl[f] = *(const h8*)&Bl[(wc + f*16 + li)*KP + lk];
    }
    #pragma unroll
    for (int i = 0; i < 4; i++)
      #pragma unroll
      for (int j = 0; j < 4; j++){
        acc[i][j] = __builtin_amdgcn_mfma_f32_16x16x32_f16(fah[i], fbh[j], acc[i][j], 0,0,0);
        acc[i][j] = __builtin_amdgcn_mfma_f32_16x16x32_f16(fah[i], fbl[j], acc[i][j], 0,0,0);
        acc[i][j] = __builtin_amdgcn_mfma_f32_16x16x32_f16(fal[i], fbh[j], acc[i][j], 0,0,0);
      }
    __syncthreads();
  }

  // ---- epilogue ----
  #pragma unroll
  for (int i = 0; i < 4; i++){
    int r0 = m0 + wr + i*16 + (lane >> 4)*4;
    #pragma unroll
    for (int j = 0; j < 4; j++){
      int c = n0 + wc + j*16 + li;
      if (c < N){
        float badd = bias ? bias[c] : 0.f;
        #pragma unroll
        for (int r = 0; r < 4; r++){
          int row = r0 + r;
          float v = acc[i][j][r] + badd;
          if (rowbias) v += rowbias[(size_t)(row >> 8)*rb_stride + c];
          C[(size_t)row*N + c] = v;
        }
      }
    }
  }
}

// ---------------------------------------------------------------------------
// MFMA split-f16 embedding-gather GEMM (float2 staging loads; K even).
// ---------------------------------------------------------------------------
__global__ __launch_bounds__(256)
void embed_mfma_k(const float* Etab, const int* tok,
                  const float* Bm, const float* bias,
                  float* C, int M, int N, int K)
{
  constexpr int KP = 40;
  __shared__ __align__(16) f16 Ah[128*KP];
  __shared__ __align__(16) f16 Al[128*KP];
  __shared__ __align__(16) f16 Bh[128*KP];
  __shared__ __align__(16) f16 Bl[128*KP];
  __shared__ int tokS[128];

  int tid = threadIdx.x;
  int n0 = blockIdx.x * 128, m0 = blockIdx.y * 128;
  int lane = tid & 63, w = tid >> 6;
  int wr = (w >> 1) * 64, wc = (w & 1) * 64;
  int li = lane & 15, lk = (lane >> 4) * 8;

  for (int i = tid; i < 128; i += 256){
    int m = m0 + i;
    tokS[i] = (m < M) ? tok[m] : 0;
  }
  __syncthreads();

  f4 acc[4][4];
  #pragma unroll
  for (int i=0;i<4;i++)
    #pragma unroll
    for (int j=0;j<4;j++) acc[i][j] = (f4){0.f,0.f,0.f,0.f};

  int srow = tid >> 1, scb = (tid & 1) << 4;
  size_t abase = (size_t)tokS[srow] * (size_t)K;
  int sn = n0 + srow;

  for (int k0 = 0; k0 < K; k0 += 32){
    #pragma unroll
    for (int q = 0; q < 16; q += 2){
      float2 va = {0.f, 0.f}, vb = {0.f, 0.f};
      int k = k0 + scb + q;                 // even; k<K (even) => k+1<K
      if (k < K){
        va = *(const float2*)&Etab[abase + k];
        if (sn < N) vb = *(const float2*)&Bm[(size_t)sn*K + k];
      }
      f16 a0h=(f16)va.x, a1h=(f16)va.y, b0h=(f16)vb.x, b1h=(f16)vb.y;
      f16 a0l=(f16)(va.x-(float)a0h), a1l=(f16)(va.y-(float)a1h);
      f16 b0l=(f16)(vb.x-(float)b0h), b1l=(f16)(vb.y-(float)b1h);
      int off = srow*KP + scb + q;
      *(h2*)&Ah[off] = (h2){a0h, a1h};
      *(h2*)&Al[off] = (h2){a0l, a1l};
      *(h2*)&Bh[off] = (h2){b0h, b1h};
      *(h2*)&Bl[off] = (h2){b0l, b1l};
    }
    __syncthreads();

    h8 fah[4], fal[4], fbh[4], fbl[4];
    #pragma unroll
    for (int f = 0; f < 4; f++){
      fah[f] = *(const h8*)&Ah[(wr + f*16 + li)*KP + lk];
      fal[f] = *(const h8*)&Al[(wr + f*16 + li)*KP + lk];
      fbh[f] = *(const h8*)&Bh[(wc + f*16 + li)*KP + lk];
      fbl[f] = *(const h8*)&Bl[(wc + f*16 + li)*KP + lk];
    }
    #pragma unroll
    for (int i = 0; i < 4; i++)
      #pragma unroll
      for (int j = 0; j < 4; j++){
        acc[i][j] = __builtin_amdgcn_mfma_f32_16x16x32_f16(fah[i], fbh[j], acc[i][j], 0,0,0);
        acc[i][j] = __builtin_amdgcn_mfma_f32_16x16x32_f16(fah[i], fbl[j], acc[i][j], 0,0,0);
        acc[i][j] = __builtin_amdgcn_mfma_f32_16x16x32_f16(fal[i], fbh[j], acc[i][j], 0,0,0);
      }
    __syncthreads();
  }

  #pragma unroll
  for (int i = 0; i < 4; i++){
    int r0 = m0 + wr + i*16 + (lane >> 4)*4;
    #pragma unroll
    for (int j = 0; j < 4; j++){
      int c = n0 + wc + j*16 + li;
      if (c < N){
        float badd = bias ? bias[c] : 0.f;
        #pragma unroll
        for (int r = 0; r < 4; r++){
          int row = r0 + r;
          if (row < M) C[(size_t)row*N + c] = acc[i][j][r] + badd;
        }
      }
    }
  }
}

// ---------------------------------------------------------------------------
// Small-GRU recurrence (H=150): one block per (seq, dir). 4 lanes/row,
// exact f32 weights in VGPRs, parity double-buffered h, 1 barrier/step.
// ---------------------------------------------------------------------------
__global__ __launch_bounds__(640)
void gru_small_k(const float* xs, int ncols,
                 const float* Whh, const float* bhh,
                 float* ys, float* meanOut, int T)
{
  constexpr int KSTEP = 38;                 // ceil(150/4)
  __shared__ __align__(16) float hl[2][152];
  int tid = threadIdx.x;
  int seq = blockIdx.x, dir = blockIdx.y;
  int row = tid >> 2, l = tid & 3;
  bool comp = (row < 150);
  int k0 = l * KSTEP;

  float w0[KSTEP], w1[KSTEP], w2[KSTEP];
  if (comp){
    const float* base = Whh + (size_t)dir*67500;
    const float* p0 = base + (size_t)(0*150 + row)*150;
    const float* p1 = base + (size_t)(1*150 + row)*150;
    const float* p2 = base + (size_t)(2*150 + row)*150;
    #pragma unroll
    for (int i=0;i<KSTEP;i++){
      int k = k0 + i;
      int kc = (k < 150) ? k : 0;
      float m = (k < 150) ? 1.f : 0.f;
      w0[i] = p0[kc]*m; w1[i] = p1[kc]*m; w2[i] = p2[kc]*m;
    }
  }
  float bR=0.f, bZ=0.f, bN=0.f;
  if (comp && l==0){
    bR = bhh[dir*450 + row];
    bZ = bhh[dir*450 + 150 + row];
    bN = bhh[dir*450 + 300 + row];
  }
  for (int i = tid; i < 2*152; i += 640) (&hl[0][0])[i] = 0.f;
  __syncthreads();

  float msum = 0.f;
  size_t rowbase = (size_t)seq * T;
  for (int tt = 0; tt < T; tt++){
    int t = dir ? (T-1-tt) : tt;
    int par = tt & 1;
    const float* hr = hl[par];
    float* hw = hl[1-par];

    float xr=0.f, xz=0.f, xn=0.f, hprev=0.f;
    if (comp && l==0){
      const float* xp = xs + (rowbase + t)*(size_t)ncols + dir*450;
      xr = xp[row]; xz = xp[150+row]; xn = xp[300+row];
      hprev = hr[row];
    }

    float a0=0.f, a1=0.f, a2=0.f;
    if (comp){
      #pragma unroll
      for (int i=0;i<KSTEP;i++){
        float hv = hr[k0 + i];
        a0 += w0[i]*hv; a1 += w1[i]*hv; a2 += w2[i]*hv;
      }
    }
    a0 += __shfl_xor(a0,1); a0 += __shfl_xor(a0,2);
    a1 += __shfl_xor(a1,1); a1 += __shfl_xor(a1,2);
    a2 += __shfl_xor(a2,1); a2 += __shfl_xor(a2,2);

    if (comp && l==0){
      float rr = sigm(xr + a0 + bR);
      float zz = sigm(xz + a1 + bZ);
      float nn = tanhf(xn + rr*(a2 + bN));
      float hn = (1.f - zz)*nn + zz*hprev;
      hw[row] = hn;
      msum += hn;
      if (ys) ys[(rowbase + t)*(size_t)300 + dir*150 + row] = hn;
    }
    __syncthreads();
  }
  if (meanOut && comp && l==0)
    meanOut[(size_t)seq*300 + dir*150 + row] = msum / (float)T;
}

// ---------------------------------------------------------------------------
// Big-GRU recurrence, BOTH dirs per launch, time-sliced. Weights in VGPRs
// (unified AGPR file), tagged-pair LLC h exchange, exact f32 hold + HSEED.
// R6-measured-best partition: small per-block message sets, many blocks.
// ---------------------------------------------------------------------------
template<int BLK, int JB, int KC, int Hh>
__global__ __launch_bounds__(BLK)
void gru_big_k(const float* xs0, const float* xs1,
               const float* Whh,         // [2][3*Hh][Hh] f32
               const float* bhh,         // [2][3*Hh]
               u64* hbuf,                // [2 parity][2 dir][B][Hh/2] tagged pairs
               float* hseed,             // [2 dir][B][Hh] exact f32 chunk seed
               float* meanOut, int mean_stride,
               u32 tagbase,
               int TT, int TC, int t0)
{
  constexpr int LPR   = 8;
  constexpr int KSTEP = 2*KC;
  constexpr int HS    = LPR*KSTEP;
  constexpr int HP    = Hh/2;
  constexpr int NPAIR = 4*HP;
  constexpr int RMAX  = (NPAIR + BLK - 1)/BLK;
  constexpr int H3    = 3*Hh;

  __shared__ __align__(16) f16 hstage[2][4*HS];

  int tid = threadIdx.x;
  int jc = blockIdx.x, bg = blockIdx.y, dir = blockIdx.z;
  int j0 = jc * JB;
  int row = tid >> 3, l = tid & 7;
  bool comp = (row < JB);
  int jg = j0 + row;
  int k0 = l * KSTEP;

  const float* Wd = Whh + (size_t)dir*H3*Hh;
  const float* xs = dir ? xs1 : xs0;
  int xoff = dir ? (TT - TC - t0) : t0;

  h2 w0[KC], w1[KC], w2[KC];
  if (comp){
    const float* p0 = Wd + ((size_t)0*Hh + jg)*(size_t)Hh;
    const float* p1 = Wd + ((size_t)1*Hh + jg)*(size_t)Hh;
    const float* p2 = Wd + ((size_t)2*Hh + jg)*(size_t)Hh;
    #pragma unroll
    for (int i=0;i<KC;i++){
      int k = k0 + 2*i;
      h2 a; a.x=(f16)0.f; a.y=(f16)0.f;
      h2 b = a, c = a;
      if (k < Hh){   a.x=(f16)p0[k];   b.x=(f16)p1[k];   c.x=(f16)p2[k]; }
      if (k+1 < Hh){ a.y=(f16)p0[k+1]; b.y=(f16)p1[k+1]; c.y=(f16)p2[k+1]; }
      w0[i]=a; w1[i]=b; w2[i]=c;
    }
  } else {
    #pragma unroll
    for (int i=0;i<KC;i++){
      h2 z; z.x=(f16)0.f; z.y=(f16)0.f;
      w0[i]=z; w1[i]=z; w2[i]=z;
    }
  }
  float br=0.f, bz=0.f, bn_=0.f;
  if (comp && l < 4){
    br = bhh[(size_t)dir*H3 + jg];
    bz = bhh[(size_t)dir*H3 + Hh + jg];
    bn_= bhh[(size_t)dir*H3 + 2*Hh + jg];
  }

  {
    f16* hz = &hstage[0][0];
    for (int i = tid; i < 2*4*HS; i += BLK) hz[i] = (f16)0.f;
  }

  float msum_own = 0.f;
  float hold_own = 0.f;                  // batch s = l ownership (l < 4)
  if (t0 > 0 && comp && l < 4){
    const float* hs = hseed + (size_t)dir*Bn*Hh;
    hold_own = hs[(size_t)(bg*4+l)*Hh + jg];
  }
  __syncthreads();

  for (int tt = 0; tt < TC; tt++){
    int g = t0 + tt;
    int t = dir ? (TT-1-g) : g;
    int par = g & 1;
    const u64* hrd = hbuf + (size_t)(par*2 + dir)*Bn*HP;
    u64*       hwr = hbuf + (size_t)((1-par)*2 + dir)*Bn*HP;
    f16* hsb = hstage[par];

    u64 tmp[RMAX];
    const u64* hb = hrd + (size_t)(bg*4)*HP;
    if (g != 0){
      #pragma unroll
      for (int r=0;r<RMAX;r++){
        int idx = tid + r*BLK;
        if (idx < NPAIR) tmp[r] = llc_load64(&hb[idx]);
      }
    }

    // xs prefetch: lane l<4 loads batch l only (3 loads, overlaps tag check)
    float xr=0.f, xz=0.f, xn=0.f;
    if (comp && l < 4){
      const float* xp = xs + ((size_t)(bg*4+l)*TC + (t - xoff))*(size_t)H3;
      xr = xp[jg]; xz = xp[Hh+jg]; xn = xp[2*Hh+jg];
    }

    if (g != 0){
      u32 want = tagbase + (u32)g;
      u32 pend = 0;
      #pragma unroll
      for (int r=0;r<RMAX;r++){
        int idx = tid + r*BLK;
        if (idx < NPAIR && (u32)(tmp[r] >> 32) != want) pend |= (1u << r);
      }
      int guard = 0;
      while (pend){
        __builtin_amdgcn_s_sleep(1);
        #pragma unroll
        for (int r=0;r<RMAX;r++)
          if (pend & (1u << r)) tmp[r] = llc_load64(&hb[tid + r*BLK]);
        #pragma unroll
        for (int r=0;r<RMAX;r++)
          if ((pend & (1u << r)) && (u32)(tmp[r] >> 32) == want) pend &= ~(1u << r);
        if (++guard > 200000) break;   // failsafe: wrong result > GPU hang
      }
      #pragma unroll
      for (int r=0;r<RMAX;r++){
        int idx = tid + r*BLK;
        if (idx < NPAIR){
          int s = idx / HP, jp = idx - s*HP;
          union { u32 i; h2 h; } u; u.i = (u32)tmp[r];
          *(h2*)(hsb + s*HS + 2*jp) = u.h;
        }
      }
    }
    __syncthreads();

    float a0[4]={0,0,0,0}, a1[4]={0,0,0,0}, a2[4]={0,0,0,0};
    if (comp){
      const f16* hp = hsb + k0;
      #pragma unroll
      for (int i=0;i<KC;i++){
        const int kk = 2*i;
        h2 hv0 = *(const h2*)(hp + 0*HS + kk);
        h2 hv1 = *(const h2*)(hp + 1*HS + kk);
        h2 hv2 = *(const h2*)(hp + 2*HS + kk);
        h2 hv3 = *(const h2*)(hp + 3*HS + kk);
        a0[0]=FDOT2(w0[i],hv0,a0[0]); a0[1]=FDOT2(w0[i],hv1,a0[1]);
        a0[2]=FDOT2(w0[i],hv2,a0[2]); a0[3]=FDOT2(w0[i],hv3,a0[3]);
        a1[0]=FDOT2(w1[i],hv0,a1[0]); a1[1]=FDOT2(w1[i],hv1,a1[1]);
        a1[2]=FDOT2(w1[i],hv2,a1[2]); a1[3]=FDOT2(w1[i],hv3,a1[3]);
        a2[0]=FDOT2(w2[i],hv0,a2[0]); a2[1]=FDOT2(w2[i],hv1,a2[1]);
        a2[2]=FDOT2(w2[i],hv2,a2[2]); a2[3]=FDOT2(w2[i],hv3,a2[3]);
      }
    }
    #pragma unroll
    for (int s=0;s<4;s++){
      a0[s] += __shfl_xor(a0[s],1); a0[s] += __shfl_xor(a0[s],2); a0[s] += __shfl_xor(a0[s],4);
      a1[s] += __shfl_xor(a1[s],1); a1[s] += __shfl_xor(a1[s],2); a1[s] += __shfl_xor(a1[s],4);
      a2[s] += __shfl_xor(a2[s],1); a2[s] += __shfl_xor(a2[s],2); a2[s] += __shfl_xor(a2[s],4);
    }
    // select own batch's sums via cndmask chain (no runtime array index)
    float t0a = (l & 1) ? a0[1] : a0[0], t0b = (l & 1) ? a0[3] : a0[2];
    float A0 = (l & 2) ? t0b : t0a;
    float t1a = (l & 1) ? a1[1] : a1[0], t1b = (l & 1) ? a1[3] : a1[2];
    float A1 = (l & 2) ? t1b : t1a;
    float t2a = (l & 1) ? a2[1] : a2[0], t2b = (l & 1) ? a2[3] : a2[2];
    float A2 = (l & 2) ? t2b : t2a;

    float hn_own = 0.f;
    if (comp && l < 4){
      float rr = sigm(xr + A0 + br);
      float zz = sigm(xz + A1 + bz);
      float nn = tanhf(xn + rr*(A2 + bn_));
      hn_own = (1.f - zz)*nn + zz*hold_own;
      hold_own = hn_own;
      msum_own += hn_own;
    }
    // pair adjacent rows: even row's lane l grabs odd row's hn (lane+8)
    u32 wtag = tagbase + (u32)g + 1u;
    float hp2 = __shfl_down(hn_own, 8);
    if (comp && l < 4 && !(row & 1)){
      h2 pk; pk.x = (f16)hn_own; pk.y = (f16)hp2;
      union { h2 h; u32 i; } u; u.h = pk;
      llc_store64(&hwr[(size_t)(bg*4+l)*HP + ((unsigned)(j0+row) >> 1)],
                  ((u64)wtag << 32) | (u64)u.i);
    }
    if (tt == TC-1 && comp && l < 4){
      float* hs = hseed + (size_t)dir*Bn*Hh;
      hs[(size_t)(bg*4+l)*Hh + jg] = hold_own;
    }
  }
  if (comp && l < 4){
    float* mp = meanOut + (size_t)(bg*4+l)*mean_stride + dir*Hh + jg;
    *mp += msum_own / (float)TT;
  }
}

// ---------------------------------------------------------------------------
// mask_att + fact_sep fused: per (b, 8-t chunk). R11: float4 staging,
// float4 LDS dot-reads, float4 final writes (all 16B-aligned).
// ---------------------------------------------------------------------------
__global__ __launch_bounds__(256)
void mask_att_k(const float* ctx, const float* vh, float* simOut, float* diffOut)
{
  __shared__ __align__(16) float vhl[50*300];
  __shared__ __align__(16) float ctxl[8*300];
  __shared__ float attl[8*52];
  __shared__ __align__(16) float scenl[8*300];
  __shared__ float ratio[8];
  int tid = threadIdx.x;
  int b = blockIdx.y, tc = blockIdx.x;
  int grp = tid >> 5, ln = tid & 31;        // 8 groups x 32 lanes
  size_t cbase = ((size_t)b*Tn + tc*8) * 300;
  {
    const f4* vsrc = (const f4*)(vh + (size_t)b*15000);
    f4* vdst = (f4*)vhl;
    for (int i = tid; i < 3750; i += 256) vdst[i] = vsrc[i];
    const f4* csrc = (const f4*)(ctx + cbase);
    f4* cdst = (f4*)ctxl;
    for (int i = tid; i < 600; i += 256) cdst[i] = csrc[i];
  }
  __syncthreads();
  for (int p = tid; p < 400; p += 256){
    int ttl = p / 50, v = p % 50;
    const f4* cp = (const f4*)(ctxl + ttl*300);
    const f4* vp = (const f4*)(vhl + v*300);
    float acc = 0.f;
    for (int d4 = 0; d4 < 75; d4++){
      f4 c = cp[d4], vv = vp[d4];
      acc += c.x*vv.x + c.y*vv.y + c.z*vv.z + c.w*vv.w;
    }
    attl[ttl*52 + v] = acc;
  }
  __syncthreads();
  // masked softmax over v=0..50 per row (group grp owns row grp)
  {
    float mx = -INFINITY;
    for (int v = ln; v < 50; v += 32){
      float a = attl[grp*52+v];
      float msk = (a == 0.f) ? -INFINITY : a;
      attl[grp*52+v] = msk;
      mx = fmaxf(mx, msk);
    }
    #pragma unroll
    for (int m=1; m<32; m<<=1) mx = fmaxf(mx, __shfl_xor(mx, m));
    if (mx == -INFINITY){
      for (int v = ln; v < 50; v += 32) attl[grp*52+v] = 0.f;
    } else {
      float sum = 0.f;
      for (int v = ln; v < 50; v += 32){
        float e = expf(attl[grp*52+v] - mx);
        attl[grp*52+v] = e;
        sum += e;
      }
      #pragma unroll
      for (int m=1; m<32; m<<=1) sum += __shfl_xor(sum, m);
      float inv = 1.f/sum;
      for (int v = ln; v < 50; v += 32) attl[grp*52+v] *= inv;
    }
  }
  __syncthreads();
  for (int p = tid; p < 2400; p += 256){
    int ttl = p / 300, d = p % 300;
    float acc = 0.f;
    for (int v=0; v<50; v++) acc += attl[ttl*52+v] * vhl[v*300+d];
    scenl[p] = acc;
  }
  __syncthreads();
  // ratio = <ctx,scen>/<scen,scen> per row, 32-lane parallel dot
  {
    float x3 = 0.f, x4 = 0.f;
    for (int d = ln; d < 300; d += 32){
      float s = scenl[grp*300+d];
      x3 += ctxl[grp*300+d]*s; x4 += s*s;
    }
    #pragma unroll
    for (int m=1; m<32; m<<=1){ x3 += __shfl_xor(x3, m); x4 += __shfl_xor(x4, m); }
    if (ln == 0) ratio[grp] = x3 / (x4 + 1e-10f);
  }
  __syncthreads();
  {
    f4* so = (f4*)(simOut + cbase);
    f4* dfo = (f4*)(diffOut + cbase);
    const f4* sc = (const f4*)scenl;
    const f4* cl = (const f4*)ctxl;
    for (int p4 = tid; p4 < 600; p4 += 256){
      float rt = ratio[p4 / 75];
      f4 s = sc[p4], c = cl[p4];
      f4 sim = (f4){rt*s.x, rt*s.y, rt*s.z, rt*s.w};
      so[p4] = sim;
      dfo[p4] = (f4){c.x - sim.x, c.y - sim.y, c.z - sim.z, c.w - sim.w};
    }
  }
}

// ---------------------------------------------------------------------------
// code_wise helpers
// ---------------------------------------------------------------------------
__global__ __launch_bounds__(256)
void softmaxT_k(const float* m, float* att){
  __shared__ float red[256];
  int b = blockIdx.x, tid = threadIdx.x;
  float v1 = m[b*512 + tid], v2 = m[b*512 + 256 + tid];
  red[tid] = fmaxf(v1, v2); __syncthreads();
  for (int s=128; s; s>>=1){ if (tid<s) red[tid] = fmaxf(red[tid], red[tid+s]); __syncthreads(); }
  float M = red[0]; __syncthreads();
  float e1 = expf(v1-M), e2 = expf(v2-M);
  red[tid] = e1+e2; __syncthreads();
  for (int s=128; s; s>>=1){ if (tid<s) red[tid] += red[tid+s]; __syncthreads(); }
  float inv = 1.f / red[0];
  att[b*512+tid] = e1*inv; att[b*512+256+tid] = e2*inv;
}

// t split over 8 blocks (grid (32,8)), partial sums via atomicAdd; out zeroed.
__global__ __launch_bounds__(256)
void wsum_k(const float* att, const float* dh, float* out){
  int b = blockIdx.x, c = blockIdx.y, tid = threadIdx.x;
  int t0 = c * 64;
  for (int d = tid; d < 300; d += 256){
    float acc = 0.f;
    #pragma unroll 8
    for (int t = t0; t < t0 + 64; t++)
      acc += att[b*512+t] * dh[((size_t)b*512 + t)*300 + d];
    atomicAdd(&out[b*300+d], acc);
  }
}

// ---------------------------------------------------------------------------
// graph_decomp helpers
// ---------------------------------------------------------------------------
__global__ void count_k(const int* src, int E, float* counts){
  int e = blockIdx.x*256 + threadIdx.x;
  if (e < E) atomicAdd(&counts[src[e]], 1.f);
}
__global__ void coef_k(const float* L, const int* src, const int* dst, int E, float* coef){
  int e = blockIdx.x*4 + (threadIdx.x >> 6);
  int lane = threadIdx.x & 63;
  if (e >= E) return;
  const float* Li = L + (size_t)src[e]*300;
  const float* Lj = L + (size_t)dst[e]*300;
  float num = 0.f, den = 0.f;
  for (int d = lane; d < 300; d += 64){ float lj = Lj[d]; num += Li[d]*lj; den += lj*lj; }
  for (int off = 32; off; off >>= 1){ num += __shfl_xor(num, off, 64); den += __shfl_xor(den, off, 64); }
  if (lane == 0) coef[e] = num / (den + 1e-10f);
}
__global__ void agg_k(const float* L, const int* src, const int* dst, const float* coef, int E, float* agg){
  int e = blockIdx.x;
  float c = coef[e];
  const float* Lj = L + (size_t)dst[e]*300;
  float* ag = agg + (size_t)src[e]*300;
  for (int d = threadIdx.x; d < 300; d += 256) atomicAdd(&ag[d], c*Lj[d]);
}
__global__ void upd_k(const float* L, const float* agg, const float* counts, float* out, int n){
  int i = blockIdx.x;
  float c = counts[i];
  for (int d = threadIdx.x; d < 300; d += 256){
    float v = L[(size_t)i*300+d];
    out[(size_t)i*300+d] = (c > 0.f) ? v - agg[(size_t)i*300+d]/fmaxf(c, 1.f) : v;
  }
}

// ---------------------------------------------------------------------------
// classifier heads: one 64-lane wave per (b, c), k strided by lane.
// ---------------------------------------------------------------------------
__global__ __launch_bounds__(256)
void logits_k(const float* A0, const float* A1, const float* A2, int srcw,
              const float* W, const float* bias, int C, int K,
              float* outF){
  int b = blockIdx.x;
  int c = blockIdx.y*4 + (threadIdx.x >> 6);
  int lane = threadIdx.x & 63;
  if (c >= C) return;
  const float* wp = W + (size_t)c*K;
  float acc = 0.f;
  for (int k = lane; k < K; k += 64){
    int s = k / srcw; int kk = k - s*srcw;
    const float* Ap = (s==0) ? A0 : ((s==1) ? A1 : A2);
    acc += Ap[(size_t)b*srcw + kk] * wp[k];
  }
  for (int off = 32; off; off >>= 1) acc += __shfl_xor(acc, off, 64);
  if (lane == 0) outF[b*C + c] = acc + bias[c];
}
__global__ void argmax_k(const float* lf, int C, int* pred){
  int b = threadIdx.x;
  if (b < 32){
    const float* p = lf + (size_t)b*C;
    int best = 0; float bv = p[0];
    for (int c = 1; c < C; c++){ float v = p[c]; if (v > bv){ bv = v; best = c; } }
    pred[b] = best;
  }
}
__global__ void vtok_k(const int* table, const int* pred, int* vt, int L){
  int i = blockIdx.x*256 + threadIdx.x;
  if (i < 32*L) vt[i] = table[pred[i/L]*L + i%L];
}

// ---------------------------------------------------------------------------
extern "C" void kernel_launch(void* const* d_in, const int* in_sizes, int n_in,
                              void* d_out, int out_size, void* d_ws, size_t ws_size,
                              hipStream_t stream)
{
  (void)in_sizes; (void)n_in; (void)out_size;
  const float* E        = (const float*)d_in[0];
  const int* chTok    = (const int*)d_in[1];
  const int* arTok    = (const int*)d_in[2];
  const int* docs     = (const int*)d_in[3];
  const int* chVerd   = (const int*)d_in[4];
  const int* arVerd   = (const int*)d_in[5];
  const int* c_src    = (const int*)d_in[6];
  const int* c_dst    = (const int*)d_in[7];
  const int* a_src    = (const int*)d_in[8];
  const int* a_dst    = (const int*)d_in[9];
  const float* enc_Wih  = (const float*)d_in[10];
  const float* enc_Whh  = (const float*)d_in[11];
  const float* enc_bih  = (const float*)d_in[12];
  const float* enc_bhh  = (const float*)d_in[13];
  const float* ech_Wih  = (const float*)d_in[14];
  const float* ech_Whh  = (const float*)d_in[15];
  const float* ech_bih  = (const float*)d_in[16];
  const float* ech_bhh  = (const float*)d_in[17];
  const float* term_Wih = (const float*)d_in[18];
  const float* term_Whh = (const float*)d_in[19];
  const float* term_bih = (const float*)d_in[20];
  const float* term_bhh = (const float*)d_in[21];
  const float* art_Wih  = (const float*)d_in[22];
  const float* art_Whh  = (const float*)d_in[23];
  const float* art_bih  = (const float*)d_in[24];
  const float* art_bhh  = (const float*)d_in[25];
  const float* W_charge = (const float*)d_in[26];
  const float* b_charge = (const float*)d_in[27];
  const float* W_article= (const float*)d_in[28];
  const float* b_article= (const float*)d_in[29];
  const float* W_time   = (const float*)d_in[30];
  const float* b_time   = (const float*)d_in[31];
  float* out = (float*)d_out;
  float* OUTC = out;            // [32][119]
  float* OUTA = out + 3808;     // [32][103]
  float* OUTT = out + 7104;     // [32][11]

  char* wsb = (char*)d_ws;
  size_t off = 0;
  auto alloc = [&](size_t nf)->float* {
    float* p = (float*)(wsb + off);
    off += ((nf*4 + 255) & ~(size_t)255);
    return p;
  };
  float* XS0   = alloc(14745600ULL);        // 59.0 MB
  float* XS1   = alloc(14745600ULL);        // 59.0 MB
  float* DH    = alloc(4915200);            // d_hidden [32][512][300]
  float* ADC   = alloc(4915200);            // adc, later dsc
  float* SEC   = alloc(4915200);
  float* SSC   = alloc(4915200);
  float* VHYS  = alloc(480000);             // [32][50][300]
  float* MECH  = alloc(66600);              // encch means [222][300]
  float* LC1   = alloc(35700);
  float* LC0   = alloc(35700);
  float* LA1   = alloc(30900);
  float* LA0   = alloc(30900);
  float* AGG   = alloc(35700);
  float* CNTS  = alloc(256);                // counts_c @0, counts_a @128
  float* COEF  = alloc(640);
  float* DHC   = alloc(9600);               // DHC,DA,DHNA,DB contiguous (1 memset)
  float* DA    = alloc(9600);
  float* DHNA  = alloc(9600);
  float* DB    = alloc(9600);
  float* MDH   = alloc(9600);               // mean_t d_hidden [32][300]
  float* MFA   = alloc(38400);              // fa mean [32][1200] (accumulated)
  float* MTH   = alloc(28800);              // th mean [32][900] (accumulated)
  float* RB    = alloc(115200);             // art rowbias [32][3600]
  float* RMX   = alloc(16384);
  float* ATTB  = alloc(16384);
  u64*   HBUF  = (u64*)alloc(76800);        // [2][2][32][300] u64 tagged pairs
  float* HSEED = alloc(38400);              // [2][32][600] exact f32 seeds
  int*   PREDC = (int*)alloc(64);
  int*   PREDA = (int*)alloc(64);
  int*   VTOK  = (int*)alloc(1600);
  int*   TCC   = (int*)alloc(11104);

  if (off > ws_size) return;   // diagnostic: leaves out==0 -> absmax==max|ref|

  hipMemsetAsync(HBUF, 0, 2*2*Bn*300*sizeof(u64), stream);  // tags = 0
  hipMemsetAsync(CNTS, 0, 256*4, stream);
  hipMemsetAsync(DHC, 0, 4*9600*4, stream);   // DHC..DB contiguous

  // --- encch on charge+article token sequences (222 seqs, L=50) ---
  hipMemcpyAsync(TCC, chTok, NCn*LCn*4, hipMemcpyDeviceToDevice, stream);
  hipMemcpyAsync(TCC + NCn*LCn, arTok, NAn*LCn*4, hipMemcpyDeviceToDevice, stream);
  embed_mfma_k<<<dim3(8,87),256,0,stream>>>(E, TCC, ech_Wih, ech_bih,
      XS0, 11100, 900, 200);
  gru_small_k<<<dim3(222,2),640,0,stream>>>(XS0, 900, ech_Whh, ech_bhh, nullptr, MECH, 50);

  // --- enc on documents ---
  embed_mfma_k<<<dim3(8,128),256,0,stream>>>(E, docs, enc_Wih, enc_bih,
      XS0, 16384, 900, 200);
  gru_small_k<<<dim3(32,2),640,0,stream>>>(XS0, 900, enc_Whh, enc_bhh, DH, MDH, 512);

  // --- graph_decomp (charge, article), 2 layers each ---
  count_k<<<3,256,0,stream>>>(c_src, ECn, CNTS);
  count_k<<<2,256,0,stream>>>(a_src, EAn, CNTS+128);
  coef_k<<<150,256,0,stream>>>(MECH, c_src, c_dst, ECn, COEF);
  hipMemsetAsync(AGG, 0, 35700*4, stream);
  agg_k<<<ECn,256,0,stream>>>(MECH, c_src, c_dst, COEF, ECn, AGG);
  upd_k<<<NCn,256,0,stream>>>(MECH, AGG, CNTS, LC1, NCn);
  coef_k<<<150,256,0,stream>>>(LC1, c_src, c_dst, ECn, COEF);
  hipMemsetAsync(AGG, 0, 35700*4, stream);
  agg_k<<<ECn,256,0,stream>>>(LC1, c_src, c_dst, COEF, ECn, AGG);
  upd_k<<<NCn,256,0,stream>>>(LC1, AGG, CNTS, LC0, NCn);

  const float* MEAR = MECH + (size_t)NCn*300;
  coef_k<<<125,256,0,stream>>>(MEAR, a_src, a_dst, EAn, COEF);
  hipMemsetAsync(AGG, 0, 30900*4, stream);
  agg_k<<<EAn,256,0,stream>>>(MEAR, a_src, a_dst, COEF, EAn, AGG);
  upd_k<<<NAn,256,0,stream>>>(MEAR, AGG, CNTS+128, LA1, NAn);
  coef_k<<<125,256,0,stream>>>(LA1, a_src, a_dst, EAn, COEF);
  hipMemsetAsync(AGG, 0, 30900*4, stream);
  agg_k<<<EAn,256,0,stream>>>(LA1, a_src, a_dst, COEF, EAn, AGG);
  upd_k<<<NAn,256,0,stream>>>(LA1, AGG, CNTS+128, LA0, NAn);

  // --- code_wise x4: fused score+rowmax (S never materialized) ---
  auto codewise = [&](const float* q, int Nq, float* outv){
    score_rowmax_k<<<128,256,0,stream>>>(DH, q, Nq, RMX);
    softmaxT_k<<<32,256,0,stream>>>(RMX, ATTB);
    wsum_k<<<dim3(32,8),256,0,stream>>>(ATTB, DH, outv);
  };
  codewise(LC0,  NCn, DHC);    // new_charge
  codewise(MECH, NCn, DA);     // ori charge
  codewise(LA0,  NAn, DHNA);   // new_article
  codewise(MEAR, NAn, DB);     // ori article

  // --- charge head ---
  logits_k<<<dim3(32,30),256,0,stream>>>(MDH, DHC, DA, 300, W_charge, b_charge, NCn, 900, OUTC);
  argmax_k<<<1,64,0,stream>>>(OUTC, NCn, PREDC);

  // --- fact_sep #1 ---
  vtok_k<<<7,256,0,stream>>>(chVerd, PREDC, VTOK, LVn);
  embed_mfma_k<<<dim3(8,13),256,0,stream>>>(E, VTOK, enc_Wih, enc_bih,
      XS0, 1600, 900, 200);
  gru_small_k<<<dim3(32,2),640,0,stream>>>(XS0, 900, enc_Whh, enc_bhh, VHYS, nullptr, 50);
  mask_att_k<<<dim3(64,32),256,0,stream>>>(DH, VHYS, ADC, SEC);

  // --- article bigru: rowbias, then time-sliced dual-dir chunks ---
  {
    dim3 g((3600+127)/128, 1);
    gemm_k<0><<<g,256,0,stream>>>(DHNA, DB, nullptr, nullptr, nullptr,
        art_Wih, 1200, 300, 900, 0, art_bih, nullptr, 1, 1, IDIV,0,0,
        RB, 32, 3600, 600);
  }
  hipMemsetAsync(MFA, 0, 38400*4, stream);
  for (int L = 0; L < 2; L++){
    stage_mfma_k<<<dim3(15,64),256,0,stream>>>(DH, ADC, nullptr,
        art_Wih, 1200, 0, 600, 0,
        nullptr, RB, 3600, 256*L,
        XS0, 1800, 600);
    stage_mfma_k<<<dim3(15,64),256,0,stream>>>(DH, ADC, nullptr,
        art_Wih + (size_t)1800*1200, 1200, 0, 600, 0,
        nullptr, RB + 1800, 3600, 256*(1-L),
        XS1, 1800, 600);
    gru_big_k<384,40,38,600><<<dim3(15,8,2),384,0,stream>>>(XS0, XS1,
        art_Whh, art_bhh, HBUF, HSEED, MFA, 1200, 0u,
        512, 256, 256*L);
  }
  logits_k<<<dim3(32,26),256,0,stream>>>(MFA, nullptr, nullptr, 1200, W_article, b_article, NAn, 1200, OUTA);
  argmax_k<<<1,64,0,stream>>>(OUTA, NAn, PREDA);

  // --- fact_sep #2 (context = sec_vector) ---
  vtok_k<<<7,256,0,stream>>>(arVerd, PREDA, VTOK, LVn);
  embed_mfma_k<<<dim3(8,13),256,0,stream>>>(E, VTOK, enc_Wih, enc_bih,
      XS0, 1600, 900, 200);
  gru_small_k<<<dim3(32,2),640,0,stream>>>(XS0, 900, enc_Whh, enc_bhh, VHYS, nullptr, 50);
  mask_att_k<<<dim3(64,32),256,0,stream>>>(SEC, VHYS, SSC, ADC);   // ssc, dsc(=ADC)

  // --- term bigru, time-sliced dual-dir chunks ---
  hipMemsetAsync(MTH, 0, 28800*4, stream);
  for (int L = 0; L < 2; L++){
    stage_mfma_k<<<dim3(11,64),256,0,stream>>>(DH, SSC, ADC,
        term_Wih, 900, 0, 300, 600,
        term_bih, nullptr, 0, 256*L,
        XS0, 1350, 900);
    stage_mfma_k<<<dim3(11,64),256,0,stream>>>(DH, SSC, ADC,
        term_Wih + (size_t)1350*900, 900, 0, 300, 600,
        term_bih + 1350, nullptr, 0, 256*(1-L),
        XS1, 1350, 900);
    gru_big_k<448,50,29,450><<<dim3(9,8,2),448,0,stream>>>(XS0, XS1,
        term_Whh, term_bhh, HBUF, HSEED, MTH, 900, 512u,
        512, 256, 256*L);
  }
  logits_k<<<dim3(32,3),256,0,stream>>>(MTH, nullptr, nullptr, 900, W_time, b_time, NTn, 900, OUTT);
}

// Round 12
// 8952.269 us; speedup vs baseline: 1.8578x; 1.0564x over previous
//
#include <hip/hip_runtime.h>
#include <stdint.h>
#include <math.h>

typedef unsigned int u32;
typedef unsigned long long u64;
typedef _Float16 f16;
typedef _Float16 h4 __attribute__((ext_vector_type(4)));
typedef _Float16 h2 __attribute__((ext_vector_type(2)));
typedef _Float16 h8 __attribute__((ext_vector_type(8)));
typedef float f4 __attribute__((ext_vector_type(4)));

// Problem constants
#define Vn     50000
#define DEMBn  200
#define Hn     150
#define NCn    119
#define NAn    103
#define NTn    11
#define Bn     32
#define Tn     512
#define LCn    50
#define LVn    50
#define ECn    600
#define EAn    500

#define IDIV 1073741824 // identity arow mapping

__device__ __forceinline__ float sigm(float x){ return 1.0f / (1.0f + expf(-x)); }

#if __has_builtin(__builtin_amdgcn_fdot2)
__device__ __forceinline__ float FDOT2(h2 a, h2 b, float c){
  return __builtin_amdgcn_fdot2(a, b, c, false);
}
#else
__device__ __forceinline__ float FDOT2(h2 a, h2 b, float c){
  return c + (float)a.x*(float)b.x + (float)a.y*(float)b.y;
}
#endif

// LLC-coherent agent-scope 64-bit ops (bypass non-coherent L1/L2).
__device__ __forceinline__ u64 llc_load64(const u64* p){
  return __hip_atomic_load(p, __ATOMIC_RELAXED, __HIP_MEMORY_SCOPE_AGENT);
}
__device__ __forceinline__ void llc_store64(u64* p, u64 v){
  __hip_atomic_store(p, v, __ATOMIC_RELAXED, __HIP_MEMORY_SCOPE_AGENT);
}

// ---------------------------------------------------------------------------
// Tiled fp32 GEMM (small cases): C[M][N] = A[arow(m)][K] @ B[N][K]^T
// ---------------------------------------------------------------------------
template<int AMODE>
__global__ __launch_bounds__(256)
void gemm_k(const float* A0, const float* A1, const float* A2,
            const float* Etab, const int* tok,
            const float* Bm, int ldb, int bc0, int bc1, int bc2,
            const float* bias, const float* rowbias, int rb_div, int rb_stride,
            int arow_div, int arow_stride, int arow_off,
            float* C, int M, int N, int K)
{
  __shared__ float As[8][132];
  __shared__ float Bs[8][132];
  __shared__ int tokS[128];
  int tid = threadIdx.x;
  int m0 = blockIdx.y * 128, n0 = blockIdx.x * 128;
  if (AMODE == 1){
    for (int i = tid; i < 128; i += 256){
      int m = m0 + i;
      tokS[i] = (m < M) ? tok[m] : 0;
    }
  }
  __syncthreads();
  float acc[8][8];
  #pragma unroll
  for (int i=0;i<8;i++)
    #pragma unroll
    for (int j=0;j<8;j++) acc[i][j] = 0.f;

  int tx = tid & 15, ty = tid >> 4;

  for (int k0 = 0; k0 < K; k0 += 8){
    #pragma unroll
    for (int r = 0; r < 4; r++){
      int i = tid + 256*r;          // [0,1024)
      int ml = i >> 3, kl = i & 7;
      int k = k0 + kl;
      {
        int m = m0 + ml;
        float v = 0.f;
        if (m < M && k < K){
          if (AMODE == 0){
            int s = k / 300; int kk = k - s*300;
            const float* Ap = (s==0) ? A0 : ((s==1) ? A1 : A2);
            int ar = (m / arow_div)*arow_stride + (m % arow_div) + arow_off;
            v = Ap[(size_t)ar*300 + kk];
          } else {
            v = Etab[(size_t)tokS[ml]*DEMBn + k];
          }
        }
        As[kl][ml] = v;
      }
      {
        int n = n0 + ml;
        float v = 0.f;
        if (n < N && k < K){
          int col;
          if (AMODE == 0){ int s = k / 300; int kk = k - s*300; col = ((s==0)?bc0:((s==1)?bc1:bc2)) + kk; }
          else col = k;
          v = Bm[(size_t)n*ldb + col];
        }
        Bs[kl][ml] = v;
      }
    }
    __syncthreads();
    #pragma unroll
    for (int kk = 0; kk < 8; kk++){
      float a[8], b[8];
      #pragma unroll
      for (int i=0;i<8;i++) a[i] = As[kk][ty*8+i];
      #pragma unroll
      for (int i=0;i<8;i++) b[i] = Bs[kk][tx*8+i];
      #pragma unroll
      for (int i=0;i<8;i++)
        #pragma unroll
        for (int j=0;j<8;j++) acc[i][j] += a[i]*b[j];
    }
    __syncthreads();
  }
  #pragma unroll
  for (int i=0;i<8;i++){
    int m = m0 + ty*8 + i; if (m >= M) continue;
    #pragma unroll
    for (int j=0;j<8;j++){
      int n = n0 + tx*8 + j; if (n >= N) continue;
      float v = acc[i][j];
      if (bias)    v += bias[n];
      if (rowbias) v += rowbias[(size_t)(m / rb_div)*rb_stride + n];
      C[(size_t)m*N + n] = v;
    }
  }
}

// ---------------------------------------------------------------------------
// Fused code_wise score + row-max, BATCHED over 4 query sets (blockIdx.y).
// RMX[qi][m] = max_n (DH[m] . Bq[qi][n]); Nq <= 128 (one block spans row).
// ---------------------------------------------------------------------------
__global__ __launch_bounds__(256)
void score_rowmax_k(const float* A,
                    const float* B0, const float* B1,
                    const float* B2, const float* B3,
                    int Nq01, int Nq23, float* RMX)
{
  __shared__ float As[8][132];
  __shared__ float Bs[8][132];
  int tid = threadIdx.x;
  int m0 = blockIdx.x * 128;
  int qi = blockIdx.y;
  const float* Bq = (qi==0) ? B0 : ((qi==1) ? B1 : ((qi==2) ? B2 : B3));
  int Nq = (qi < 2) ? Nq01 : Nq23;
  float acc[8][8];
  #pragma unroll
  for (int i=0;i<8;i++)
    #pragma unroll
    for (int j=0;j<8;j++) acc[i][j] = 0.f;
  int tx = tid & 15, ty = tid >> 4;

  for (int k0 = 0; k0 < 300; k0 += 8){
    #pragma unroll
    for (int r = 0; r < 4; r++){
      int i = tid + 256*r;
      int ml = i >> 3, kl = i & 7;
      int k = k0 + kl;
      As[kl][ml] = (k < 300) ? A[(size_t)(m0 + ml)*300 + k] : 0.f;
      Bs[kl][ml] = (ml < Nq && k < 300) ? Bq[(size_t)ml*300 + k] : 0.f;
    }
    __syncthreads();
    #pragma unroll
    for (int kk = 0; kk < 8; kk++){
      float a[8], b[8];
      #pragma unroll
      for (int i=0;i<8;i++) a[i] = As[kk][ty*8+i];
      #pragma unroll
      for (int i=0;i<8;i++) b[i] = Bs[kk][tx*8+i];
      #pragma unroll
      for (int i=0;i<8;i++)
        #pragma unroll
        for (int j=0;j<8;j++) acc[i][j] += a[i]*b[j];
    }
    __syncthreads();
  }
  #pragma unroll
  for (int i=0;i<8;i++){
    float mx = -INFINITY;
    #pragma unroll
    for (int j=0;j<8;j++){
      int n = tx*8 + j;
      if (n < Nq) mx = fmaxf(mx, acc[i][j]);
    }
    mx = fmaxf(mx, __shfl_xor(mx, 1));
    mx = fmaxf(mx, __shfl_xor(mx, 2));
    mx = fmaxf(mx, __shfl_xor(mx, 4));
    mx = fmaxf(mx, __shfl_xor(mx, 8));
    if (tx == 0) RMX[(size_t)qi*16384 + m0 + ty*8 + i] = mx;
  }
}

// ---------------------------------------------------------------------------
// MFMA split-f16 staging GEMM for the big xs gemms (art/term).
// float2 staging loads; R12: XCD-aware m-grouping swizzle — blocks sharing
// an A row-panel land on one XCD (A panel L2-resident, ~8x less A refetch).
// Bijective when gridDim.y % 8 == 0 (both 15x64 and 11x64 grids qualify).
// ---------------------------------------------------------------------------
__global__ __launch_bounds__(256)
void stage_mfma_k(const float* A0, const float* A1, const float* A2,
                  const float* Bm, int ldb, int bc0, int bc1, int bc2,
                  const float* bias, const float* rowbias, int rb_stride,
                  int arow_off,
                  float* C, int N, int K)
{
  constexpr int KP = 40;                    // f16 row stride (80B: 16B-aligned rows)
  __shared__ __align__(16) f16 Ah[128*KP];
  __shared__ __align__(16) f16 Al[128*KP];
  __shared__ __align__(16) f16 Bh[128*KP];
  __shared__ __align__(16) f16 Bl[128*KP];

  int tid = threadIdx.x;
  int nb, mb;
  if ((gridDim.y & 7) == 0){
    int bid = blockIdx.y * gridDim.x + blockIdx.x;
    int xcd = bid & 7;                       // assumed round-robin XCD
    int i = bid >> 3;                        // [0, total/8)
    int NB = gridDim.x;
    nb = i % NB;
    int mlocal = i / NB;                     // [0, gridDim.y/8)
    mb = xcd * (gridDim.y >> 3) + mlocal;
  } else {
    nb = blockIdx.x; mb = blockIdx.y;
  }
  int n0 = nb * 128, m0 = mb * 128;
  int lane = tid & 63, w = tid >> 6;
  int wr = (w >> 1) * 64, wc = (w & 1) * 64;   // wave tile origin in block tile
  int li = lane & 15, lk = (lane >> 4) * 8;

  f4 acc[4][4];
  #pragma unroll
  for (int i=0;i<4;i++)
    #pragma unroll
    for (int j=0;j<4;j++) acc[i][j] = (f4){0.f,0.f,0.f,0.f};

  int srow = tid >> 1, scb = (tid & 1) << 4;   // staging: row, col-base (16 k each)
  int sm = m0 + srow;
  size_t abase = (size_t)(((sm >> 8) * 512) + (sm & 255) + arow_off) * 300;
  int sn = n0 + srow;

  for (int k0 = 0; k0 < K; k0 += 32){
    // ---- stage A,B k-tile as hi/lo f16 (float2 loads) ----
    #pragma unroll
    for (int q = 0; q < 16; q += 2){
      float2 va = {0.f, 0.f}, vb = {0.f, 0.f};
      int k = k0 + scb + q;                  // even; pair (k,k+1) same segment
      if (k < K){
        int s = (k >= 600) ? 2 : ((k >= 300) ? 1 : 0);
        int kk = k - s*300;
        const float* Ap = (s==0) ? A0 : ((s==1) ? A1 : A2);
        va = *(const float2*)&Ap[abase + kk];
        if (sn < N) vb = *(const float2*)&Bm[(size_t)sn*ldb + ((s==0)?bc0:((s==1)?bc1:bc2)) + kk];
      }
      f16 a0h=(f16)va.x, a1h=(f16)va.y, b0h=(f16)vb.x, b1h=(f16)vb.y;
      f16 a0l=(f16)(va.x-(float)a0h), a1l=(f16)(va.y-(float)a1h);
      f16 b0l=(f16)(vb.x-(float)b0h), b1l=(f16)(vb.y-(float)b1h);
      int off = srow*KP + scb + q;
      *(h2*)&Ah[off] = (h2){a0h, a1h};
      *(h2*)&Al[off] = (h2){a0l, a1l};
      *(h2*)&Bh[off] = (h2){b0h, b1h};
      *(h2*)&Bl[off] = (h2){b0l, b1l};
    }
    __syncthreads();

    // ---- fragments + 3-pass MFMA ----
    h8 fah[4], fal[4], fbh[4], fbl[4];
    #pragma unroll
    for (int f = 0; f < 4; f++){
      fah[f] = *(const h8*)&Ah[(wr + f*16 + li)*KP + lk];
      fal[f] = *(const h8*)&Al[(wr + f*16 + li)*KP + lk];
      fbh[f] = *(const h8*)&Bh[(wc + f*16 + li)*KP + lk];
      fbl[f] = *(const h8*)&Bl[(wc + f*16 + li)*KP + lk];
    }
    #pragma unroll
    for (int i = 0; i < 4; i++)
      #pragma unroll
      for (int j = 0; j < 4; j++){
        acc[i][j] = __builtin_amdgcn_mfma_f32_16x16x32_f16(fah[i], fbh[j], acc[i][j], 0,0,0);
        acc[i][j] = __builtin_amdgcn_mfma_f32_16x16x32_f16(fah[i], fbl[j], acc[i][j], 0,0,0);
        acc[i][j] = __builtin_amdgcn_mfma_f32_16x16x32_f16(fal[i], fbh[j], acc[i][j], 0,0,0);
      }
    __syncthreads();
  }

  // ---- epilogue ----
  #pragma unroll
  for (int i = 0; i < 4; i++){
    int r0 = m0 + wr + i*16 + (lane >> 4)*4;
    #pragma unroll
    for (int j = 0; j < 4; j++){
      int c = n0 + wc + j*16 + li;
      if (c < N){
        float badd = bias ? bias[c] : 0.f;
        #pragma unroll
        for (int r = 0; r < 4; r++){
          int row = r0 + r;
          float v = acc[i][j][r] + badd;
          if (rowbias) v += rowbias[(size_t)(row >> 8)*rb_stride + c];
          C[(size_t)row*N + c] = v;
        }
      }
    }
  }
}

// ---------------------------------------------------------------------------
// MFMA split-f16 embedding-gather GEMM (float2 staging loads; K even).
// ---------------------------------------------------------------------------
__global__ __launch_bounds__(256)
void embed_mfma_k(const float* Etab, const int* tok,
                  const float* Bm, const float* bias,
                  float* C, int M, int N, int K)
{
  constexpr int KP = 40;
  __shared__ __align__(16) f16 Ah[128*KP];
  __shared__ __align__(16) f16 Al[128*KP];
  __shared__ __align__(16) f16 Bh[128*KP];
  __shared__ __align__(16) f16 Bl[128*KP];
  __shared__ int tokS[128];

  int tid = threadIdx.x;
  int n0 = blockIdx.x * 128, m0 = blockIdx.y * 128;
  int lane = tid & 63, w = tid >> 6;
  int wr = (w >> 1) * 64, wc = (w & 1) * 64;
  int li = lane & 15, lk = (lane >> 4) * 8;

  for (int i = tid; i < 128; i += 256){
    int m = m0 + i;
    tokS[i] = (m < M) ? tok[m] : 0;
  }
  __syncthreads();

  f4 acc[4][4];
  #pragma unroll
  for (int i=0;i<4;i++)
    #pragma unroll
    for (int j=0;j<4;j++) acc[i][j] = (f4){0.f,0.f,0.f,0.f};

  int srow = tid >> 1, scb = (tid & 1) << 4;
  size_t abase = (size_t)tokS[srow] * (size_t)K;
  int sn = n0 + srow;

  for (int k0 = 0; k0 < K; k0 += 32){
    #pragma unroll
    for (int q = 0; q < 16; q += 2){
      float2 va = {0.f, 0.f}, vb = {0.f, 0.f};
      int k = k0 + scb + q;                 // even; k<K (even) => k+1<K
      if (k < K){
        va = *(const float2*)&Etab[abase + k];
        if (sn < N) vb = *(const float2*)&Bm[(size_t)sn*K + k];
      }
      f16 a0h=(f16)va.x, a1h=(f16)va.y, b0h=(f16)vb.x, b1h=(f16)vb.y;
      f16 a0l=(f16)(va.x-(float)a0h), a1l=(f16)(va.y-(float)a1h);
      f16 b0l=(f16)(vb.x-(float)b0h), b1l=(f16)(vb.y-(float)b1h);
      int off = srow*KP + scb + q;
      *(h2*)&Ah[off] = (h2){a0h, a1h};
      *(h2*)&Al[off] = (h2){a0l, a1l};
      *(h2*)&Bh[off] = (h2){b0h, b1h};
      *(h2*)&Bl[off] = (h2){b0l, b1l};
    }
    __syncthreads();

    h8 fah[4], fal[4], fbh[4], fbl[4];
    #pragma unroll
    for (int f = 0; f < 4; f++){
      fah[f] = *(const h8*)&Ah[(wr + f*16 + li)*KP + lk];
      fal[f] = *(const h8*)&Al[(wr + f*16 + li)*KP + lk];
      fbh[f] = *(const h8*)&Bh[(wc + f*16 + li)*KP + lk];
      fbl[f] = *(const h8*)&Bl[(wc + f*16 + li)*KP + lk];
    }
    #pragma unroll
    for (int i = 0; i < 4; i++)
      #pragma unroll
      for (int j = 0; j < 4; j++){
        acc[i][j] = __builtin_amdgcn_mfma_f32_16x16x32_f16(fah[i], fbh[j], acc[i][j], 0,0,0);
        acc[i][j] = __builtin_amdgcn_mfma_f32_16x16x32_f16(fah[i], fbl[j], acc[i][j], 0,0,0);
        acc[i][j] = __builtin_amdgcn_mfma_f32_16x16x32_f16(fal[i], fbh[j], acc[i][j], 0,0,0);
      }
    __syncthreads();
  }

  #pragma unroll
  for (int i = 0; i < 4; i++){
    int r0 = m0 + wr + i*16 + (lane >> 4)*4;
    #pragma unroll
    for (int j = 0; j < 4; j++){
      int c = n0 + wc + j*16 + li;
      if (c < N){
        float badd = bias ? bias[c] : 0.f;
        #pragma unroll
        for (int r = 0; r < 4; r++){
          int row = r0 + r;
          if (row < M) C[(size_t)row*N + c] = acc[i][j][r] + badd;
        }
      }
    }
  }
}

// ---------------------------------------------------------------------------
// Small-GRU recurrence (H=150): one block per (seq, dir). 4 lanes/row,
// exact f32 weights in VGPRs, parity double-buffered h, 1 barrier/step.
// ---------------------------------------------------------------------------
__global__ __launch_bounds__(640)
void gru_small_k(const float* xs, int ncols,
                 const float* Whh, const float* bhh,
                 float* ys, float* meanOut, int T)
{
  constexpr int KSTEP = 38;                 // ceil(150/4)
  __shared__ __align__(16) float hl[2][152];
  int tid = threadIdx.x;
  int seq = blockIdx.x, dir = blockIdx.y;
  int row = tid >> 2, l = tid & 3;
  bool comp = (row < 150);
  int k0 = l * KSTEP;

  float w0[KSTEP], w1[KSTEP], w2[KSTEP];
  if (comp){
    const float* base = Whh + (size_t)dir*67500;
    const float* p0 = base + (size_t)(0*150 + row)*150;
    const float* p1 = base + (size_t)(1*150 + row)*150;
    const float* p2 = base + (size_t)(2*150 + row)*150;
    #pragma unroll
    for (int i=0;i<KSTEP;i++){
      int k = k0 + i;
      int kc = (k < 150) ? k : 0;
      float m = (k < 150) ? 1.f : 0.f;
      w0[i] = p0[kc]*m; w1[i] = p1[kc]*m; w2[i] = p2[kc]*m;
    }
  }
  float bR=0.f, bZ=0.f, bN=0.f;
  if (comp && l==0){
    bR = bhh[dir*450 + row];
    bZ = bhh[dir*450 + 150 + row];
    bN = bhh[dir*450 + 300 + row];
  }
  for (int i = tid; i < 2*152; i += 640) (&hl[0][0])[i] = 0.f;
  __syncthreads();

  float msum = 0.f;
  size_t rowbase = (size_t)seq * T;
  for (int tt = 0; tt < T; tt++){
    int t = dir ? (T-1-tt) : tt;
    int par = tt & 1;
    const float* hr = hl[par];
    float* hw = hl[1-par];

    float xr=0.f, xz=0.f, xn=0.f, hprev=0.f;
    if (comp && l==0){
      const float* xp = xs + (rowbase + t)*(size_t)ncols + dir*450;
      xr = xp[row]; xz = xp[150+row]; xn = xp[300+row];
      hprev = hr[row];
    }

    float a0=0.f, a1=0.f, a2=0.f;
    if (comp){
      #pragma unroll
      for (int i=0;i<KSTEP;i++){
        float hv = hr[k0 + i];
        a0 += w0[i]*hv; a1 += w1[i]*hv; a2 += w2[i]*hv;
      }
    }
    a0 += __shfl_xor(a0,1); a0 += __shfl_xor(a0,2);
    a1 += __shfl_xor(a1,1); a1 += __shfl_xor(a1,2);
    a2 += __shfl_xor(a2,1); a2 += __shfl_xor(a2,2);

    if (comp && l==0){
      float rr = sigm(xr + a0 + bR);
      float zz = sigm(xz + a1 + bZ);
      float nn = tanhf(xn + rr*(a2 + bN));
      float hn = (1.f - zz)*nn + zz*hprev;
      hw[row] = hn;
      msum += hn;
      if (ys) ys[(rowbase + t)*(size_t)300 + dir*150 + row] = hn;
    }
    __syncthreads();
  }
  if (meanOut && comp && l==0)
    meanOut[(size_t)seq*300 + dir*150 + row] = msum / (float)T;
}

// ---------------------------------------------------------------------------
// Big-GRU recurrence, BOTH dirs per launch, time-sliced. Weights in VGPRs
// (unified AGPR file), tagged-pair LLC h exchange, exact f32 hold + HSEED.
// R6-measured-best partition: small per-block message sets, many blocks.
// ---------------------------------------------------------------------------
template<int BLK, int JB, int KC, int Hh>
__global__ __launch_bounds__(BLK)
void gru_big_k(const float* xs0, const float* xs1,
               const float* Whh,         // [2][3*Hh][Hh] f32
               const float* bhh,         // [2][3*Hh]
               u64* hbuf,                // [2 parity][2 dir][B][Hh/2] tagged pairs
               float* hseed,             // [2 dir][B][Hh] exact f32 chunk seed
               float* meanOut, int mean_stride,
               u32 tagbase,
               int TT, int TC, int t0)
{
  constexpr int LPR   = 8;
  constexpr int KSTEP = 2*KC;
  constexpr int HS    = LPR*KSTEP;
  constexpr int HP    = Hh/2;
  constexpr int NPAIR = 4*HP;
  constexpr int RMAX  = (NPAIR + BLK - 1)/BLK;
  constexpr int H3    = 3*Hh;

  __shared__ __align__(16) f16 hstage[2][4*HS];

  int tid = threadIdx.x;
  int jc = blockIdx.x, bg = blockIdx.y, dir = blockIdx.z;
  int j0 = jc * JB;
  int row = tid >> 3, l = tid & 7;
  bool comp = (row < JB);
  int jg = j0 + row;
  int k0 = l * KSTEP;

  const float* Wd = Whh + (size_t)dir*H3*Hh;
  const float* xs = dir ? xs1 : xs0;
  int xoff = dir ? (TT - TC - t0) : t0;

  h2 w0[KC], w1[KC], w2[KC];
  if (comp){
    const float* p0 = Wd + ((size_t)0*Hh + jg)*(size_t)Hh;
    const float* p1 = Wd + ((size_t)1*Hh + jg)*(size_t)Hh;
    const float* p2 = Wd + ((size_t)2*Hh + jg)*(size_t)Hh;
    #pragma unroll
    for (int i=0;i<KC;i++){
      int k = k0 + 2*i;
      h2 a; a.x=(f16)0.f; a.y=(f16)0.f;
      h2 b = a, c = a;
      if (k < Hh){   a.x=(f16)p0[k];   b.x=(f16)p1[k];   c.x=(f16)p2[k]; }
      if (k+1 < Hh){ a.y=(f16)p0[k+1]; b.y=(f16)p1[k+1]; c.y=(f16)p2[k+1]; }
      w0[i]=a; w1[i]=b; w2[i]=c;
    }
  } else {
    #pragma unroll
    for (int i=0;i<KC;i++){
      h2 z; z.x=(f16)0.f; z.y=(f16)0.f;
      w0[i]=z; w1[i]=z; w2[i]=z;
    }
  }
  float br=0.f, bz=0.f, bn_=0.f;
  if (comp && l < 4){
    br = bhh[(size_t)dir*H3 + jg];
    bz = bhh[(size_t)dir*H3 + Hh + jg];
    bn_= bhh[(size_t)dir*H3 + 2*Hh + jg];
  }

  {
    f16* hz = &hstage[0][0];
    for (int i = tid; i < 2*4*HS; i += BLK) hz[i] = (f16)0.f;
  }

  float msum_own = 0.f;
  float hold_own = 0.f;                  // batch s = l ownership (l < 4)
  if (t0 > 0 && comp && l < 4){
    const float* hs = hseed + (size_t)dir*Bn*Hh;
    hold_own = hs[(size_t)(bg*4+l)*Hh + jg];
  }
  __syncthreads();

  for (int tt = 0; tt < TC; tt++){
    int g = t0 + tt;
    int t = dir ? (TT-1-g) : g;
    int par = g & 1;
    const u64* hrd = hbuf + (size_t)(par*2 + dir)*Bn*HP;
    u64*       hwr = hbuf + (size_t)((1-par)*2 + dir)*Bn*HP;
    f16* hsb = hstage[par];

    u64 tmp[RMAX];
    const u64* hb = hrd + (size_t)(bg*4)*HP;
    if (g != 0){
      #pragma unroll
      for (int r=0;r<RMAX;r++){
        int idx = tid + r*BLK;
        if (idx < NPAIR) tmp[r] = llc_load64(&hb[idx]);
      }
    }

    // xs prefetch: lane l<4 loads batch l only (3 loads, overlaps tag check)
    float xr=0.f, xz=0.f, xn=0.f;
    if (comp && l < 4){
      const float* xp = xs + ((size_t)(bg*4+l)*TC + (t - xoff))*(size_t)H3;
      xr = xp[jg]; xz = xp[Hh+jg]; xn = xp[2*Hh+jg];
    }

    if (g != 0){
      u32 want = tagbase + (u32)g;
      u32 pend = 0;
      #pragma unroll
      for (int r=0;r<RMAX;r++){
        int idx = tid + r*BLK;
        if (idx < NPAIR && (u32)(tmp[r] >> 32) != want) pend |= (1u << r);
      }
      int guard = 0;
      while (pend){
        __builtin_amdgcn_s_sleep(1);
        #pragma unroll
        for (int r=0;r<RMAX;r++)
          if (pend & (1u << r)) tmp[r] = llc_load64(&hb[tid + r*BLK]);
        #pragma unroll
        for (int r=0;r<RMAX;r++)
          if ((pend & (1u << r)) && (u32)(tmp[r] >> 32) == want) pend &= ~(1u << r);
        if (++guard > 200000) break;   // failsafe: wrong result > GPU hang
      }
      #pragma unroll
      for (int r=0;r<RMAX;r++){
        int idx = tid + r*BLK;
        if (idx < NPAIR){
          int s = idx / HP, jp = idx - s*HP;
          union { u32 i; h2 h; } u; u.i = (u32)tmp[r];
          *(h2*)(hsb + s*HS + 2*jp) = u.h;
        }
      }
    }
    __syncthreads();

    float a0[4]={0,0,0,0}, a1[4]={0,0,0,0}, a2[4]={0,0,0,0};
    if (comp){
      const f16* hp = hsb + k0;
      #pragma unroll
      for (int i=0;i<KC;i++){
        const int kk = 2*i;
        h2 hv0 = *(const h2*)(hp + 0*HS + kk);
        h2 hv1 = *(const h2*)(hp + 1*HS + kk);
        h2 hv2 = *(const h2*)(hp + 2*HS + kk);
        h2 hv3 = *(const h2*)(hp + 3*HS + kk);
        a0[0]=FDOT2(w0[i],hv0,a0[0]); a0[1]=FDOT2(w0[i],hv1,a0[1]);
        a0[2]=FDOT2(w0[i],hv2,a0[2]); a0[3]=FDOT2(w0[i],hv3,a0[3]);
        a1[0]=FDOT2(w1[i],hv0,a1[0]); a1[1]=FDOT2(w1[i],hv1,a1[1]);
        a1[2]=FDOT2(w1[i],hv2,a1[2]); a1[3]=FDOT2(w1[i],hv3,a1[3]);
        a2[0]=FDOT2(w2[i],hv0,a2[0]); a2[1]=FDOT2(w2[i],hv1,a2[1]);
        a2[2]=FDOT2(w2[i],hv2,a2[2]); a2[3]=FDOT2(w2[i],hv3,a2[3]);
      }
    }
    #pragma unroll
    for (int s=0;s<4;s++){
      a0[s] += __shfl_xor(a0[s],1); a0[s] += __shfl_xor(a0[s],2); a0[s] += __shfl_xor(a0[s],4);
      a1[s] += __shfl_xor(a1[s],1); a1[s] += __shfl_xor(a1[s],2); a1[s] += __shfl_xor(a1[s],4);
      a2[s] += __shfl_xor(a2[s],1); a2[s] += __shfl_xor(a2[s],2); a2[s] += __shfl_xor(a2[s],4);
    }
    // select own batch's sums via cndmask chain (no runtime array index)
    float t0a = (l & 1) ? a0[1] : a0[0], t0b = (l & 1) ? a0[3] : a0[2];
    float A0 = (l & 2) ? t0b : t0a;
    float t1a = (l & 1) ? a1[1] : a1[0], t1b = (l & 1) ? a1[3] : a1[2];
    float A1 = (l & 2) ? t1b : t1a;
    float t2a = (l & 1) ? a2[1] : a2[0], t2b = (l & 1) ? a2[3] : a2[2];
    float A2 = (l & 2) ? t2b : t2a;

    float hn_own = 0.f;
    if (comp && l < 4){
      float rr = sigm(xr + A0 + br);
      float zz = sigm(xz + A1 + bz);
      float nn = tanhf(xn + rr*(A2 + bn_));
      hn_own = (1.f - zz)*nn + zz*hold_own;
      hold_own = hn_own;
      msum_own += hn_own;
    }
    // pair adjacent rows: even row's lane l grabs odd row's hn (lane+8)
    u32 wtag = tagbase + (u32)g + 1u;
    float hp2 = __shfl_down(hn_own, 8);
    if (comp && l < 4 && !(row & 1)){
      h2 pk; pk.x = (f16)hn_own; pk.y = (f16)hp2;
      union { h2 h; u32 i; } u; u.h = pk;
      llc_store64(&hwr[(size_t)(bg*4+l)*HP + ((unsigned)(j0+row) >> 1)],
                  ((u64)wtag << 32) | (u64)u.i);
    }
    if (tt == TC-1 && comp && l < 4){
      float* hs = hseed + (size_t)dir*Bn*Hh;
      hs[(size_t)(bg*4+l)*Hh + jg] = hold_own;
    }
  }
  if (comp && l < 4){
    float* mp = meanOut + (size_t)(bg*4+l)*mean_stride + dir*Hh + jg;
    *mp += msum_own / (float)TT;
  }
}

// ---------------------------------------------------------------------------
// mask_att + fact_sep fused: per (b, 8-t chunk). float4 staging + dots;
// R12: scenl phase float4 too (identical per-element sum order).
// ---------------------------------------------------------------------------
__global__ __launch_bounds__(256)
void mask_att_k(const float* ctx, const float* vh, float* simOut, float* diffOut)
{
  __shared__ __align__(16) float vhl[50*300];
  __shared__ __align__(16) float ctxl[8*300];
  __shared__ float attl[8*52];
  __shared__ __align__(16) float scenl[8*300];
  __shared__ float ratio[8];
  int tid = threadIdx.x;
  int b = blockIdx.y, tc = blockIdx.x;
  int grp = tid >> 5, ln = tid & 31;        // 8 groups x 32 lanes
  size_t cbase = ((size_t)b*Tn + tc*8) * 300;
  {
    const f4* vsrc = (const f4*)(vh + (size_t)b*15000);
    f4* vdst = (f4*)vhl;
    for (int i = tid; i < 3750; i += 256) vdst[i] = vsrc[i];
    const f4* csrc = (const f4*)(ctx + cbase);
    f4* cdst = (f4*)ctxl;
    for (int i = tid; i < 600; i += 256) cdst[i] = csrc[i];
  }
  __syncthreads();
  for (int p = tid; p < 400; p += 256){
    int ttl = p / 50, v = p % 50;
    const f4* cp = (const f4*)(ctxl + ttl*300);
    const f4* vp = (const f4*)(vhl + v*300);
    float acc = 0.f;
    for (int d4 = 0; d4 < 75; d4++){
      f4 c = cp[d4], vv = vp[d4];
      acc += c.x*vv.x + c.y*vv.y + c.z*vv.z + c.w*vv.w;
    }
    attl[ttl*52 + v] = acc;
  }
  __syncthreads();
  // masked softmax over v=0..50 per row (group grp owns row grp)
  {
    float mx = -INFINITY;
    for (int v = ln; v < 50; v += 32){
      float a = attl[grp*52+v];
      float msk = (a == 0.f) ? -INFINITY : a;
      attl[grp*52+v] = msk;
      mx = fmaxf(mx, msk);
    }
    #pragma unroll
    for (int m=1; m<32; m<<=1) mx = fmaxf(mx, __shfl_xor(mx, m));
    if (mx == -INFINITY){
      for (int v = ln; v < 50; v += 32) attl[grp*52+v] = 0.f;
    } else {
      float sum = 0.f;
      for (int v = ln; v < 50; v += 32){
        float e = expf(attl[grp*52+v] - mx);
        attl[grp*52+v] = e;
        sum += e;
      }
      #pragma unroll
      for (int m=1; m<32; m<<=1) sum += __shfl_xor(sum, m);
      float inv = 1.f/sum;
      for (int v = ln; v < 50; v += 32) attl[grp*52+v] *= inv;
    }
  }
  __syncthreads();
  // scen[ttl][d] = sum_v att[ttl][v] * vh[v][d] — float4 over d
  for (int p4 = tid; p4 < 600; p4 += 256){
    int ttl = p4 / 75, d4 = p4 % 75;
    f4 acc = (f4){0.f,0.f,0.f,0.f};
    for (int v = 0; v < 50; v++){
      float a = attl[ttl*52+v];
      f4 vv = ((const f4*)(vhl + v*300))[d4];
      acc.x += a*vv.x; acc.y += a*vv.y; acc.z += a*vv.z; acc.w += a*vv.w;
    }
    ((f4*)scenl)[p4] = acc;
  }
  __syncthreads();
  // ratio = <ctx,scen>/<scen,scen> per row, 32-lane parallel dot
  {
    float x3 = 0.f, x4 = 0.f;
    for (int d = ln; d < 300; d += 32){
      float s = scenl[grp*300+d];
      x3 += ctxl[grp*300+d]*s; x4 += s*s;
    }
    #pragma unroll
    for (int m=1; m<32; m<<=1){ x3 += __shfl_xor(x3, m); x4 += __shfl_xor(x4, m); }
    if (ln == 0) ratio[grp] = x3 / (x4 + 1e-10f);
  }
  __syncthreads();
  {
    f4* so = (f4*)(simOut + cbase);
    f4* dfo = (f4*)(diffOut + cbase);
    const f4* sc = (const f4*)scenl;
    const f4* cl = (const f4*)ctxl;
    for (int p4 = tid; p4 < 600; p4 += 256){
      float rt = ratio[p4 / 75];
      f4 s = sc[p4], c = cl[p4];
      f4 sim = (f4){rt*s.x, rt*s.y, rt*s.z, rt*s.w};
      so[p4] = sim;
      dfo[p4] = (f4){c.x - sim.x, c.y - sim.y, c.z - sim.z, c.w - sim.w};
    }
  }
}

// ---------------------------------------------------------------------------
// code_wise helpers (batched over qi = blockIdx.y / blockIdx.z)
// ---------------------------------------------------------------------------
__global__ __launch_bounds__(256)
void softmaxT_k(const float* m, float* att){
  __shared__ float red[256];
  int b = blockIdx.x, tid = threadIdx.x;
  size_t base = (size_t)blockIdx.y*16384;
  float v1 = m[base + b*512 + tid], v2 = m[base + b*512 + 256 + tid];
  red[tid] = fmaxf(v1, v2); __syncthreads();
  for (int s=128; s; s>>=1){ if (tid<s) red[tid] = fmaxf(red[tid], red[tid+s]); __syncthreads(); }
  float M = red[0]; __syncthreads();
  float e1 = expf(v1-M), e2 = expf(v2-M);
  red[tid] = e1+e2; __syncthreads();
  for (int s=128; s; s>>=1){ if (tid<s) red[tid] += red[tid+s]; __syncthreads(); }
  float inv = 1.f / red[0];
  att[base + b*512+tid] = e1*inv; att[base + b*512+256+tid] = e2*inv;
}

// t split over 8 blocks, qi over z; partial sums via atomicAdd; out zeroed.
__global__ __launch_bounds__(256)
void wsum_k(const float* att, const float* dh, float* out){
  int b = blockIdx.x, c = blockIdx.y, tid = threadIdx.x;
  int qi = blockIdx.z;
  const float* ap = att + (size_t)qi*16384 + b*512;
  float* op = out + (size_t)qi*9600 + b*300;
  int t0 = c * 64;
  for (int d = tid; d < 300; d += 256){
    float acc = 0.f;
    #pragma unroll 8
    for (int t = t0; t < t0 + 64; t++)
      acc += ap[t] * dh[((size_t)b*512 + t)*300 + d];
    atomicAdd(&op[d], acc);
  }
}

// ---------------------------------------------------------------------------
// graph_decomp helpers
// ---------------------------------------------------------------------------
__global__ void count_k(const int* src, int E, float* counts){
  int e = blockIdx.x*256 + threadIdx.x;
  if (e < E) atomicAdd(&counts[src[e]], 1.f);
}
__global__ void coef_k(const float* L, const int* src, const int* dst, int E, float* coef){
  int e = blockIdx.x*4 + (threadIdx.x >> 6);
  int lane = threadIdx.x & 63;
  if (e >= E) return;
  const float* Li = L + (size_t)src[e]*300;
  const float* Lj = L + (size_t)dst[e]*300;
  float num = 0.f, den = 0.f;
  for (int d = lane; d < 300; d += 64){ float lj = Lj[d]; num += Li[d]*lj; den += lj*lj; }
  for (int off = 32; off; off >>= 1){ num += __shfl_xor(num, off, 64); den += __shfl_xor(den, off, 64); }
  if (lane == 0) coef[e] = num / (den + 1e-10f);
}
__global__ void agg_k(const float* L, const int* src, const int* dst, const float* coef, int E, float* agg){
  int e = blockIdx.x;
  float c = coef[e];
  const float* Lj = L + (size_t)dst[e]*300;
  float* ag = agg + (size_t)src[e]*300;
  for (int d = threadIdx.x; d < 300; d += 256) atomicAdd(&ag[d], c*Lj[d]);
}
__global__ void upd_k(const float* L, const float* agg, const float* counts, float* out, int n){
  int i = blockIdx.x;
  float c = counts[i];
  for (int d = threadIdx.x; d < 300; d += 256){
    float v = L[(size_t)i*300+d];
    out[(size_t)i*300+d] = (c > 0.f) ? v - agg[(size_t)i*300+d]/fmaxf(c, 1.f) : v;
  }
}

// ---------------------------------------------------------------------------
// classifier heads: one 64-lane wave per (b, c), k strided by lane.
// ---------------------------------------------------------------------------
__global__ __launch_bounds__(256)
void logits_k(const float* A0, const float* A1, const float* A2, int srcw,
              const float* W, const float* bias, int C, int K,
              float* outF){
  int b = blockIdx.x;
  int c = blockIdx.y*4 + (threadIdx.x >> 6);
  int lane = threadIdx.x & 63;
  if (c >= C) return;
  const float* wp = W + (size_t)c*K;
  float acc = 0.f;
  for (int k = lane; k < K; k += 64){
    int s = k / srcw; int kk = k - s*srcw;
    const float* Ap = (s==0) ? A0 : ((s==1) ? A1 : A2);
    acc += Ap[(size_t)b*srcw + kk] * wp[k];
  }
  for (int off = 32; off; off >>= 1) acc += __shfl_xor(acc, off, 64);
  if (lane == 0) outF[b*C + c] = acc + bias[c];
}
__global__ void argmax_k(const float* lf, int C, int* pred){
  int b = threadIdx.x;
  if (b < 32){
    const float* p = lf + (size_t)b*C;
    int best = 0; float bv = p[0];
    for (int c = 1; c < C; c++){ float v = p[c]; if (v > bv){ bv = v; best = c; } }
    pred[b] = best;
  }
}
__global__ void vtok_k(const int* table, const int* pred, int* vt, int L){
  int i = blockIdx.x*256 + threadIdx.x;
  if (i < 32*L) vt[i] = table[pred[i/L]*L + i%L];
}

// ---------------------------------------------------------------------------
extern "C" void kernel_launch(void* const* d_in, const int* in_sizes, int n_in,
                              void* d_out, int out_size, void* d_ws, size_t ws_size,
                              hipStream_t stream)
{
  (void)in_sizes; (void)n_in; (void)out_size;
  const float* E        = (const float*)d_in[0];
  const int* chTok    = (const int*)d_in[1];
  const int* arTok    = (const int*)d_in[2];
  const int* docs     = (const int*)d_in[3];
  const int* chVerd   = (const int*)d_in[4];
  const int* arVerd   = (const int*)d_in[5];
  const int* c_src    = (const int*)d_in[6];
  const int* c_dst    = (const int*)d_in[7];
  const int* a_src    = (const int*)d_in[8];
  const int* a_dst    = (const int*)d_in[9];
  const float* enc_Wih  = (const float*)d_in[10];
  const float* enc_Whh  = (const float*)d_in[11];
  const float* enc_bih  = (const float*)d_in[12];
  const float* enc_bhh  = (const float*)d_in[13];
  const float* ech_Wih  = (const float*)d_in[14];
  const float* ech_Whh  = (const float*)d_in[15];
  const float* ech_bih  = (const float*)d_in[16];
  const float* ech_bhh  = (const float*)d_in[17];
  const float* term_Wih = (const float*)d_in[18];
  const float* term_Whh = (const float*)d_in[19];
  const float* term_bih = (const float*)d_in[20];
  const float* term_bhh = (const float*)d_in[21];
  const float* art_Wih  = (const float*)d_in[22];
  const float* art_Whh  = (const float*)d_in[23];
  const float* art_bih  = (const float*)d_in[24];
  const float* art_bhh  = (const float*)d_in[25];
  const float* W_charge = (const float*)d_in[26];
  const float* b_charge = (const float*)d_in[27];
  const float* W_article= (const float*)d_in[28];
  const float* b_article= (const float*)d_in[29];
  const float* W_time   = (const float*)d_in[30];
  const float* b_time   = (const float*)d_in[31];
  float* out = (float*)d_out;
  float* OUTC = out;            // [32][119]
  float* OUTA = out + 3808;     // [32][103]
  float* OUTT = out + 7104;     // [32][11]

  char* wsb = (char*)d_ws;
  size_t off = 0;
  auto alloc = [&](size_t nf)->float* {
    float* p = (float*)(wsb + off);
    off += ((nf*4 + 255) & ~(size_t)255);
    return p;
  };
  float* XS0   = alloc(14745600ULL);        // 59.0 MB
  float* XS1   = alloc(14745600ULL);        // 59.0 MB
  float* DH    = alloc(4915200);            // d_hidden [32][512][300]
  float* ADC   = alloc(4915200);            // adc, later dsc
  float* SEC   = alloc(4915200);
  float* SSC   = alloc(4915200);
  float* VHYS  = alloc(480000);             // [32][50][300]
  float* MECH  = alloc(66600);              // encch means [222][300]
  float* LC1   = alloc(35700);
  float* LC0   = alloc(35700);
  float* LA1   = alloc(30900);
  float* LA0   = alloc(30900);
  float* AGG   = alloc(35700);
  float* CNTS  = alloc(256);                // counts_c @0, counts_a @128
  float* COEF  = alloc(640);
  float* DHC   = alloc(9600);               // DHC,DA,DHNA,DB contiguous (qi stride 9600)
  float* DA    = alloc(9600);
  float* DHNA  = alloc(9600);
  float* DB    = alloc(9600);
  float* MDH   = alloc(9600);               // mean_t d_hidden [32][300]
  float* MFA   = alloc(38400);              // fa mean [32][1200] (accumulated)
  float* MTH   = alloc(28800);              // th mean [32][900] (accumulated)
  float* RB    = alloc(115200);             // art rowbias [32][3600]
  float* RMX   = alloc(65536);              // [4][16384]
  float* ATTB  = alloc(65536);              // [4][16384]
  u64*   HBUF  = (u64*)alloc(76800);        // [2][2][32][300] u64 tagged pairs
  float* HSEED = alloc(38400);              // [2][32][600] exact f32 seeds
  int*   PREDC = (int*)alloc(64);
  int*   PREDA = (int*)alloc(64);
  int*   VTOK  = (int*)alloc(1600);
  int*   TCC   = (int*)alloc(11104);

  if (off > ws_size) return;   // diagnostic: leaves out==0 -> absmax==max|ref|

  hipMemsetAsync(HBUF, 0, 2*2*Bn*300*sizeof(u64), stream);  // tags = 0
  hipMemsetAsync(CNTS, 0, 256*4, stream);
  hipMemsetAsync(DHC, 0, 4*9600*4, stream);   // DHC..DB contiguous

  // --- encch on charge+article token sequences (222 seqs, L=50) ---
  hipMemcpyAsync(TCC, chTok, NCn*LCn*4, hipMemcpyDeviceToDevice, stream);
  hipMemcpyAsync(TCC + NCn*LCn, arTok, NAn*LCn*4, hipMemcpyDeviceToDevice, stream);
  embed_mfma_k<<<dim3(8,87),256,0,stream>>>(E, TCC, ech_Wih, ech_bih,
      XS0, 11100, 900, 200);
  gru_small_k<<<dim3(222,2),640,0,stream>>>(XS0, 900, ech_Whh, ech_bhh, nullptr, MECH, 50);

  // --- enc on documents ---
  embed_mfma_k<<<dim3(8,128),256,0,stream>>>(E, docs, enc_Wih, enc_bih,
      XS0, 16384, 900, 200);
  gru_small_k<<<dim3(32,2),640,0,stream>>>(XS0, 900, enc_Whh, enc_bhh, DH, MDH, 512);

  // --- graph_decomp (charge, article), 2 layers each ---
  count_k<<<3,256,0,stream>>>(c_src, ECn, CNTS);
  count_k<<<2,256,0,stream>>>(a_src, EAn, CNTS+128);
  coef_k<<<150,256,0,stream>>>(MECH, c_src, c_dst, ECn, COEF);
  hipMemsetAsync(AGG, 0, 35700*4, stream);
  agg_k<<<ECn,256,0,stream>>>(MECH, c_src, c_dst, COEF, ECn, AGG);
  upd_k<<<NCn,256,0,stream>>>(MECH, AGG, CNTS, LC1, NCn);
  coef_k<<<150,256,0,stream>>>(LC1, c_src, c_dst, ECn, COEF);
  hipMemsetAsync(AGG, 0, 35700*4, stream);
  agg_k<<<ECn,256,0,stream>>>(LC1, c_src, c_dst, COEF, ECn, AGG);
  upd_k<<<NCn,256,0,stream>>>(LC1, AGG, CNTS, LC0, NCn);

  const float* MEAR = MECH + (size_t)NCn*300;
  coef_k<<<125,256,0,stream>>>(MEAR, a_src, a_dst, EAn, COEF);
  hipMemsetAsync(AGG, 0, 30900*4, stream);
  agg_k<<<EAn,256,0,stream>>>(MEAR, a_src, a_dst, COEF, EAn, AGG);
  upd_k<<<NAn,256,0,stream>>>(MEAR, AGG, CNTS+128, LA1, NAn);
  coef_k<<<125,256,0,stream>>>(LA1, a_src, a_dst, EAn, COEF);
  hipMemsetAsync(AGG, 0, 30900*4, stream);
  agg_k<<<EAn,256,0,stream>>>(LA1, a_src, a_dst, COEF, EAn, AGG);
  upd_k<<<NAn,256,0,stream>>>(LA1, AGG, CNTS+128, LA0, NAn);

  // --- code_wise x4, BATCHED: qi = {LC0->DHC, MECH->DA, LA0->DHNA, MEAR->DB} ---
  score_rowmax_k<<<dim3(128,4),256,0,stream>>>(DH, LC0, MECH, LA0, MEAR,
      NCn, NAn, RMX);
  softmaxT_k<<<dim3(32,4),256,0,stream>>>(RMX, ATTB);
  wsum_k<<<dim3(32,8,4),256,0,stream>>>(ATTB, DH, DHC);

  // --- charge head ---
  logits_k<<<dim3(32,30),256,0,stream>>>(MDH, DHC, DA, 300, W_charge, b_charge, NCn, 900, OUTC);
  argmax_k<<<1,64,0,stream>>>(OUTC, NCn, PREDC);

  // --- fact_sep #1 ---
  vtok_k<<<7,256,0,stream>>>(chVerd, PREDC, VTOK, LVn);
  embed_mfma_k<<<dim3(8,13),256,0,stream>>>(E, VTOK, enc_Wih, enc_bih,
      XS0, 1600, 900, 200);
  gru_small_k<<<dim3(32,2),640,0,stream>>>(XS0, 900, enc_Whh, enc_bhh, VHYS, nullptr, 50);
  mask_att_k<<<dim3(64,32),256,0,stream>>>(DH, VHYS, ADC, SEC);

  // --- article bigru: rowbias, then time-sliced dual-dir chunks ---
  {
    dim3 g((3600+127)/128, 1);
    gemm_k<0><<<g,256,0,stream>>>(DHNA, DB, nullptr, nullptr, nullptr,
        art_Wih, 1200, 300, 900, 0, art_bih, nullptr, 1, 1, IDIV,0,0,
        RB, 32, 3600, 600);
  }
  hipMemsetAsync(MFA, 0, 38400*4, stream);
  for (int L = 0; L < 2; L++){
    stage_mfma_k<<<dim3(15,64),256,0,stream>>>(DH, ADC, nullptr,
        art_Wih, 1200, 0, 600, 0,
        nullptr, RB, 3600, 256*L,
        XS0, 1800, 600);
    stage_mfma_k<<<dim3(15,64),256,0,stream>>>(DH, ADC, nullptr,
        art_Wih + (size_t)1800*1200, 1200, 0, 600, 0,
        nullptr, RB + 1800, 3600, 256*(1-L),
        XS1, 1800, 600);
    gru_big_k<384,40,38,600><<<dim3(15,8,2),384,0,stream>>>(XS0, XS1,
        art_Whh, art_bhh, HBUF, HSEED, MFA, 1200, 0u,
        512, 256, 256*L);
  }
  logits_k<<<dim3(32,26),256,0,stream>>>(MFA, nullptr, nullptr, 1200, W_article, b_article, NAn, 1200, OUTA);
  argmax_k<<<1,64,0,stream>>>(OUTA, NAn, PREDA);

  // --- fact_sep #2 (context = sec_vector) ---
  vtok_k<<<7,256,0,stream>>>(arVerd, PREDA, VTOK, LVn);
  embed_mfma_k<<<dim3(8,13),256,0,stream>>>(E, VTOK, enc_Wih, enc_bih,
      XS0, 1600, 900, 200);
  gru_small_k<<<dim3(32,2),640,0,stream>>>(XS0, 900, enc_Whh, enc_bhh, VHYS, nullptr, 50);
  mask_att_k<<<dim3(64,32),256,0,stream>>>(SEC, VHYS, SSC, ADC);   // ssc, dsc(=ADC)

  // --- term bigru, time-sliced dual-dir chunks ---
  hipMemsetAsync(MTH, 0, 28800*4, stream);
  for (int L = 0; L < 2; L++){
    stage_mfma_k<<<dim3(11,64),256,0,stream>>>(DH, SSC, ADC,
        term_Wih, 900, 0, 300, 600,
        term_bih, nullptr, 0, 256*L,
        XS0, 1350, 900);
    stage_mfma_k<<<dim3(11,64),256,0,stream>>>(DH, SSC, ADC,
        term_Wih + (size_t)1350*900, 900, 0, 300, 600,
        term_bih + 1350, nullptr, 0, 256*(1-L),
        XS1, 1350, 900);
    gru_big_k<448,50,29,450><<<dim3(9,8,2),448,0,stream>>>(XS0, XS1,
        term_Whh, term_bhh, HBUF, HSEED, MTH, 900, 512u,
        512, 256, 256*L);
  }
  logits_k<<<dim3(32,3),256,0,stream>>>(MTH, nullptr, nullptr, 900, W_time, b_time, NTn, 900, OUTT);
}

// Round 13
// 8760.143 us; speedup vs baseline: 1.8986x; 1.0219x over previous
//
#include <hip/hip_runtime.h>
#include <stdint.h>
#include <math.h>

typedef unsigned int u32;
typedef unsigned long long u64;
typedef _Float16 f16;
typedef _Float16 h4 __attribute__((ext_vector_type(4)));
typedef _Float16 h2 __attribute__((ext_vector_type(2)));
typedef _Float16 h8 __attribute__((ext_vector_type(8)));
typedef float f4 __attribute__((ext_vector_type(4)));

// Problem constants
#define Vn     50000
#define DEMBn  200
#define Hn     150
#define NCn    119
#define NAn    103
#define NTn    11
#define Bn     32
#define Tn     512
#define LCn    50
#define LVn    50
#define ECn    600
#define EAn    500

#define IDIV 1073741824 // identity arow mapping

__device__ __forceinline__ float sigm(float x){ return 1.0f / (1.0f + expf(-x)); }

#if __has_builtin(__builtin_amdgcn_fdot2)
__device__ __forceinline__ float FDOT2(h2 a, h2 b, float c){
  return __builtin_amdgcn_fdot2(a, b, c, false);
}
#else
__device__ __forceinline__ float FDOT2(h2 a, h2 b, float c){
  return c + (float)a.x*(float)b.x + (float)a.y*(float)b.y;
}
#endif

// LLC-coherent agent-scope 64-bit ops (bypass non-coherent L1/L2).
__device__ __forceinline__ u64 llc_load64(const u64* p){
  return __hip_atomic_load(p, __ATOMIC_RELAXED, __HIP_MEMORY_SCOPE_AGENT);
}
__device__ __forceinline__ void llc_store64(u64* p, u64 v){
  __hip_atomic_store(p, v, __ATOMIC_RELAXED, __HIP_MEMORY_SCOPE_AGENT);
}

// ---------------------------------------------------------------------------
// Tiled fp32 GEMM (small cases): C[M][N] = A[arow(m)][K] @ B[N][K]^T
// ---------------------------------------------------------------------------
template<int AMODE>
__global__ __launch_bounds__(256)
void gemm_k(const float* A0, const float* A1, const float* A2,
            const float* Etab, const int* tok,
            const float* Bm, int ldb, int bc0, int bc1, int bc2,
            const float* bias, const float* rowbias, int rb_div, int rb_stride,
            int arow_div, int arow_stride, int arow_off,
            float* C, int M, int N, int K)
{
  __shared__ float As[8][132];
  __shared__ float Bs[8][132];
  __shared__ int tokS[128];
  int tid = threadIdx.x;
  int m0 = blockIdx.y * 128, n0 = blockIdx.x * 128;
  if (AMODE == 1){
    for (int i = tid; i < 128; i += 256){
      int m = m0 + i;
      tokS[i] = (m < M) ? tok[m] : 0;
    }
  }
  __syncthreads();
  float acc[8][8];
  #pragma unroll
  for (int i=0;i<8;i++)
    #pragma unroll
    for (int j=0;j<8;j++) acc[i][j] = 0.f;

  int tx = tid & 15, ty = tid >> 4;

  for (int k0 = 0; k0 < K; k0 += 8){
    #pragma unroll
    for (int r = 0; r < 4; r++){
      int i = tid + 256*r;          // [0,1024)
      int ml = i >> 3, kl = i & 7;
      int k = k0 + kl;
      {
        int m = m0 + ml;
        float v = 0.f;
        if (m < M && k < K){
          if (AMODE == 0){
            int s = k / 300; int kk = k - s*300;
            const float* Ap = (s==0) ? A0 : ((s==1) ? A1 : A2);
            int ar = (m / arow_div)*arow_stride + (m % arow_div) + arow_off;
            v = Ap[(size_t)ar*300 + kk];
          } else {
            v = Etab[(size_t)tokS[ml]*DEMBn + k];
          }
        }
        As[kl][ml] = v;
      }
      {
        int n = n0 + ml;
        float v = 0.f;
        if (n < N && k < K){
          int col;
          if (AMODE == 0){ int s = k / 300; int kk = k - s*300; col = ((s==0)?bc0:((s==1)?bc1:bc2)) + kk; }
          else col = k;
          v = Bm[(size_t)n*ldb + col];
        }
        Bs[kl][ml] = v;
      }
    }
    __syncthreads();
    #pragma unroll
    for (int kk = 0; kk < 8; kk++){
      float a[8], b[8];
      #pragma unroll
      for (int i=0;i<8;i++) a[i] = As[kk][ty*8+i];
      #pragma unroll
      for (int i=0;i<8;i++) b[i] = Bs[kk][tx*8+i];
      #pragma unroll
      for (int i=0;i<8;i++)
        #pragma unroll
        for (int j=0;j<8;j++) acc[i][j] += a[i]*b[j];
    }
    __syncthreads();
  }
  #pragma unroll
  for (int i=0;i<8;i++){
    int m = m0 + ty*8 + i; if (m >= M) continue;
    #pragma unroll
    for (int j=0;j<8;j++){
      int n = n0 + tx*8 + j; if (n >= N) continue;
      float v = acc[i][j];
      if (bias)    v += bias[n];
      if (rowbias) v += rowbias[(size_t)(m / rb_div)*rb_stride + n];
      C[(size_t)m*N + n] = v;
    }
  }
}

// ---------------------------------------------------------------------------
// Fused code_wise score + row-max, BATCHED over 4 query sets (blockIdx.y).
// ---------------------------------------------------------------------------
__global__ __launch_bounds__(256)
void score_rowmax_k(const float* A,
                    const float* B0, const float* B1,
                    const float* B2, const float* B3,
                    int Nq01, int Nq23, float* RMX)
{
  __shared__ float As[8][132];
  __shared__ float Bs[8][132];
  int tid = threadIdx.x;
  int m0 = blockIdx.x * 128;
  int qi = blockIdx.y;
  const float* Bq = (qi==0) ? B0 : ((qi==1) ? B1 : ((qi==2) ? B2 : B3));
  int Nq = (qi < 2) ? Nq01 : Nq23;
  float acc[8][8];
  #pragma unroll
  for (int i=0;i<8;i++)
    #pragma unroll
    for (int j=0;j<8;j++) acc[i][j] = 0.f;
  int tx = tid & 15, ty = tid >> 4;

  for (int k0 = 0; k0 < 300; k0 += 8){
    #pragma unroll
    for (int r = 0; r < 4; r++){
      int i = tid + 256*r;
      int ml = i >> 3, kl = i & 7;
      int k = k0 + kl;
      As[kl][ml] = (k < 300) ? A[(size_t)(m0 + ml)*300 + k] : 0.f;
      Bs[kl][ml] = (ml < Nq && k < 300) ? Bq[(size_t)ml*300 + k] : 0.f;
    }
    __syncthreads();
    #pragma unroll
    for (int kk = 0; kk < 8; kk++){
      float a[8], b[8];
      #pragma unroll
      for (int i=0;i<8;i++) a[i] = As[kk][ty*8+i];
      #pragma unroll
      for (int i=0;i<8;i++) b[i] = Bs[kk][tx*8+i];
      #pragma unroll
      for (int i=0;i<8;i++)
        #pragma unroll
        for (int j=0;j<8;j++) acc[i][j] += a[i]*b[j];
    }
    __syncthreads();
  }
  #pragma unroll
  for (int i=0;i<8;i++){
    float mx = -INFINITY;
    #pragma unroll
    for (int j=0;j<8;j++){
      int n = tx*8 + j;
      if (n < Nq) mx = fmaxf(mx, acc[i][j]);
    }
    mx = fmaxf(mx, __shfl_xor(mx, 1));
    mx = fmaxf(mx, __shfl_xor(mx, 2));
    mx = fmaxf(mx, __shfl_xor(mx, 4));
    mx = fmaxf(mx, __shfl_xor(mx, 8));
    if (tx == 0) RMX[(size_t)qi*16384 + m0 + ty*8 + i] = mx;
  }
}

// ---------------------------------------------------------------------------
// MFMA split-f16 staging GEMM for the big xs gemms (art/term).
// R13: z-batched over the fwd/bwd halves (blockIdx.z selects B/bias/rowbias/
// C/arow_off) — 2 launches merged into 1. float2 staging loads; XCD-aware
// m-grouping swizzle (bijective when gridDim.y % 8 == 0).
// ---------------------------------------------------------------------------
__global__ __launch_bounds__(256)
void stage_mfma_k(const float* A0, const float* A1, const float* A2,
                  const float* BmA, const float* BmB, int ldb,
                  int bc0, int bc1, int bc2,
                  const float* biasA, const float* biasB,
                  const float* rowbiasA, const float* rowbiasB, int rb_stride,
                  int arow_offA, int arow_offB,
                  float* CA, float* CB, int N, int K)
{
  constexpr int KP = 40;                    // f16 row stride (80B: 16B-aligned rows)
  __shared__ __align__(16) f16 Ah[128*KP];
  __shared__ __align__(16) f16 Al[128*KP];
  __shared__ __align__(16) f16 Bh[128*KP];
  __shared__ __align__(16) f16 Bl[128*KP];

  int tid = threadIdx.x;
  const float* Bm      = blockIdx.z ? BmB      : BmA;
  const float* bias    = blockIdx.z ? biasB    : biasA;
  const float* rowbias = blockIdx.z ? rowbiasB : rowbiasA;
  float*       C       = blockIdx.z ? CB       : CA;
  int arow_off         = blockIdx.z ? arow_offB : arow_offA;

  int nb, mb;
  if ((gridDim.y & 7) == 0){
    int bid = blockIdx.y * gridDim.x + blockIdx.x;
    int xcd = bid & 7;                       // assumed round-robin XCD
    int i = bid >> 3;                        // [0, total/8)
    int NB = gridDim.x;
    nb = i % NB;
    int mlocal = i / NB;                     // [0, gridDim.y/8)
    mb = xcd * (gridDim.y >> 3) + mlocal;
  } else {
    nb = blockIdx.x; mb = blockIdx.y;
  }
  int n0 = nb * 128, m0 = mb * 128;
  int lane = tid & 63, w = tid >> 6;
  int wr = (w >> 1) * 64, wc = (w & 1) * 64;   // wave tile origin in block tile
  int li = lane & 15, lk = (lane >> 4) * 8;

  f4 acc[4][4];
  #pragma unroll
  for (int i=0;i<4;i++)
    #pragma unroll
    for (int j=0;j<4;j++) acc[i][j] = (f4){0.f,0.f,0.f,0.f};

  int srow = tid >> 1, scb = (tid & 1) << 4;   // staging: row, col-base (16 k each)
  int sm = m0 + srow;
  size_t abase = (size_t)(((sm >> 8) * 512) + (sm & 255) + arow_off) * 300;
  int sn = n0 + srow;

  for (int k0 = 0; k0 < K; k0 += 32){
    // ---- stage A,B k-tile as hi/lo f16 (float2 loads) ----
    #pragma unroll
    for (int q = 0; q < 16; q += 2){
      float2 va = {0.f, 0.f}, vb = {0.f, 0.f};
      int k = k0 + scb + q;                  // even; pair (k,k+1) same segment
      if (k < K){
        int s = (k >= 600) ? 2 : ((k >= 300) ? 1 : 0);
        int kk = k - s*300;
        const float* Ap = (s==0) ? A0 : ((s==1) ? A1 : A2);
        va = *(const float2*)&Ap[abase + kk];
        if (sn < N) vb = *(const float2*)&Bm[(size_t)sn*ldb + ((s==0)?bc0:((s==1)?bc1:bc2)) + kk];
      }
      f16 a0h=(f16)va.x, a1h=(f16)va.y, b0h=(f16)vb.x, b1h=(f16)vb.y;
      f16 a0l=(f16)(va.x-(float)a0h), a1l=(f16)(va.y-(float)a1h);
      f16 b0l=(f16)(vb.x-(float)b0h), b1l=(f16)(vb.y-(float)b1h);
      int off = srow*KP + scb + q;
      *(h2*)&Ah[off] = (h2){a0h, a1h};
      *(h2*)&Al[off] = (h2){a0l, a1l};
      *(h2*)&Bh[off] = (h2){b0h, b1h};
      *(h2*)&Bl[off] = (h2){b0l, b1l};
    }
    __syncthreads();

    // ---- fragments + 3-pass MFMA ----
    h8 fah[4], fal[4], fbh[4], fbl[4];
    #pragma unroll
    for (int f = 0; f < 4; f++){
      fah[f] = *(const h8*)&Ah[(wr + f*16 + li)*KP + lk];
      fal[f] = *(const h8*)&Al[(wr + f*16 + li)*KP + lk];
      fbh[f] = *(const h8*)&Bh[(wc + f*16 + li)*KP + lk];
      fbl[f] = *(const h8*)&Bl[(wc + f*16 + li)*KP + lk];
    }
    #pragma unroll
    for (int i = 0; i < 4; i++)
      #pragma unroll
      for (int j = 0; j < 4; j++){
        acc[i][j] = __builtin_amdgcn_mfma_f32_16x16x32_f16(fah[i], fbh[j], acc[i][j], 0,0,0);
        acc[i][j] = __builtin_amdgcn_mfma_f32_16x16x32_f16(fah[i], fbl[j], acc[i][j], 0,0,0);
        acc[i][j] = __builtin_amdgcn_mfma_f32_16x16x32_f16(fal[i], fbh[j], acc[i][j], 0,0,0);
      }
    __syncthreads();
  }

  // ---- epilogue ----
  #pragma unroll
  for (int i = 0; i < 4; i++){
    int r0 = m0 + wr + i*16 + (lane >> 4)*4;
    #pragma unroll
    for (int j = 0; j < 4; j++){
      int c = n0 + wc + j*16 + li;
      if (c < N){
        float badd = bias ? bias[c] : 0.f;
        #pragma unroll
        for (int r = 0; r < 4; r++){
          int row = r0 + r;
          float v = acc[i][j][r] + badd;
          if (rowbias) v += rowbias[(size_t)(row >> 8)*rb_stride + c];
          C[(size_t)row*N + c] = v;
        }
      }
    }
  }
}

// ---------------------------------------------------------------------------
// MFMA split-f16 embedding-gather GEMM (float2 staging loads; K even).
// R13: z-batched over two independent gathers (tok/M/B/bias/C selected by z);
// blocks with m0 >= M exit early (grid y sized to max of the two).
// ---------------------------------------------------------------------------
__global__ __launch_bounds__(256)
void embed_mfma_k(const float* Etab,
                  const int* tokA, const int* tokB,
                  const float* BmA, const float* BmB,
                  const float* biasA, const float* biasB,
                  float* CA, float* CB, int MA, int MB, int N, int K)
{
  constexpr int KP = 40;
  __shared__ __align__(16) f16 Ah[128*KP];
  __shared__ __align__(16) f16 Al[128*KP];
  __shared__ __align__(16) f16 Bh[128*KP];
  __shared__ __align__(16) f16 Bl[128*KP];
  __shared__ int tokS[128];

  const int* tok   = blockIdx.z ? tokB  : tokA;
  const float* Bm  = blockIdx.z ? BmB   : BmA;
  const float* bias= blockIdx.z ? biasB : biasA;
  float* C         = blockIdx.z ? CB    : CA;
  int M            = blockIdx.z ? MB    : MA;

  int tid = threadIdx.x;
  int n0 = blockIdx.x * 128, m0 = blockIdx.y * 128;
  if (m0 >= M) return;
  int lane = tid & 63, w = tid >> 6;
  int wr = (w >> 1) * 64, wc = (w & 1) * 64;
  int li = lane & 15, lk = (lane >> 4) * 8;

  for (int i = tid; i < 128; i += 256){
    int m = m0 + i;
    tokS[i] = (m < M) ? tok[m] : 0;
  }
  __syncthreads();

  f4 acc[4][4];
  #pragma unroll
  for (int i=0;i<4;i++)
    #pragma unroll
    for (int j=0;j<4;j++) acc[i][j] = (f4){0.f,0.f,0.f,0.f};

  int srow = tid >> 1, scb = (tid & 1) << 4;
  size_t abase = (size_t)tokS[srow] * (size_t)K;
  int sn = n0 + srow;

  for (int k0 = 0; k0 < K; k0 += 32){
    #pragma unroll
    for (int q = 0; q < 16; q += 2){
      float2 va = {0.f, 0.f}, vb = {0.f, 0.f};
      int k = k0 + scb + q;                 // even; k<K (even) => k+1<K
      if (k < K){
        va = *(const float2*)&Etab[abase + k];
        if (sn < N) vb = *(const float2*)&Bm[(size_t)sn*K + k];
      }
      f16 a0h=(f16)va.x, a1h=(f16)va.y, b0h=(f16)vb.x, b1h=(f16)vb.y;
      f16 a0l=(f16)(va.x-(float)a0h), a1l=(f16)(va.y-(float)a1h);
      f16 b0l=(f16)(vb.x-(float)b0h), b1l=(f16)(vb.y-(float)b1h);
      int off = srow*KP + scb + q;
      *(h2*)&Ah[off] = (h2){a0h, a1h};
      *(h2*)&Al[off] = (h2){a0l, a1l};
      *(h2*)&Bh[off] = (h2){b0h, b1h};
      *(h2*)&Bl[off] = (h2){b0l, b1l};
    }
    __syncthreads();

    h8 fah[4], fal[4], fbh[4], fbl[4];
    #pragma unroll
    for (int f = 0; f < 4; f++){
      fah[f] = *(const h8*)&Ah[(wr + f*16 + li)*KP + lk];
      fal[f] = *(const h8*)&Al[(wr + f*16 + li)*KP + lk];
      fbh[f] = *(const h8*)&Bh[(wc + f*16 + li)*KP + lk];
      fbl[f] = *(const h8*)&Bl[(wc + f*16 + li)*KP + lk];
    }
    #pragma unroll
    for (int i = 0; i < 4; i++)
      #pragma unroll
      for (int j = 0; j < 4; j++){
        acc[i][j] = __builtin_amdgcn_mfma_f32_16x16x32_f16(fah[i], fbh[j], acc[i][j], 0,0,0);
        acc[i][j] = __builtin_amdgcn_mfma_f32_16x16x32_f16(fah[i], fbl[j], acc[i][j], 0,0,0);
        acc[i][j] = __builtin_amdgcn_mfma_f32_16x16x32_f16(fal[i], fbh[j], acc[i][j], 0,0,0);
      }
    __syncthreads();
  }

  #pragma unroll
  for (int i = 0; i < 4; i++){
    int r0 = m0 + wr + i*16 + (lane >> 4)*4;
    #pragma unroll
    for (int j = 0; j < 4; j++){
      int c = n0 + wc + j*16 + li;
      if (c < N){
        float badd = bias ? bias[c] : 0.f;
        #pragma unroll
        for (int r = 0; r < 4; r++){
          int row = r0 + r;
          if (row < M) C[(size_t)row*N + c] = acc[i][j][r] + badd;
        }
      }
    }
  }
}

// ---------------------------------------------------------------------------
// Small-GRU recurrence (H=150): one block per (seq, dir). 4 lanes/row,
// exact f32 weights in VGPRs, parity double-buffered h, 1 barrier/step.
// ---------------------------------------------------------------------------
__global__ __launch_bounds__(640)
void gru_small_k(const float* xs, int ncols,
                 const float* Whh, const float* bhh,
                 float* ys, float* meanOut, int T)
{
  constexpr int KSTEP = 38;                 // ceil(150/4)
  __shared__ __align__(16) float hl[2][152];
  int tid = threadIdx.x;
  int seq = blockIdx.x, dir = blockIdx.y;
  int row = tid >> 2, l = tid & 3;
  bool comp = (row < 150);
  int k0 = l * KSTEP;

  float w0[KSTEP], w1[KSTEP], w2[KSTEP];
  if (comp){
    const float* base = Whh + (size_t)dir*67500;
    const float* p0 = base + (size_t)(0*150 + row)*150;
    const float* p1 = base + (size_t)(1*150 + row)*150;
    const float* p2 = base + (size_t)(2*150 + row)*150;
    #pragma unroll
    for (int i=0;i<KSTEP;i++){
      int k = k0 + i;
      int kc = (k < 150) ? k : 0;
      float m = (k < 150) ? 1.f : 0.f;
      w0[i] = p0[kc]*m; w1[i] = p1[kc]*m; w2[i] = p2[kc]*m;
    }
  }
  float bR=0.f, bZ=0.f, bN=0.f;
  if (comp && l==0){
    bR = bhh[dir*450 + row];
    bZ = bhh[dir*450 + 150 + row];
    bN = bhh[dir*450 + 300 + row];
  }
  for (int i = tid; i < 2*152; i += 640) (&hl[0][0])[i] = 0.f;
  __syncthreads();

  float msum = 0.f;
  size_t rowbase = (size_t)seq * T;
  for (int tt = 0; tt < T; tt++){
    int t = dir ? (T-1-tt) : tt;
    int par = tt & 1;
    const float* hr = hl[par];
    float* hw = hl[1-par];

    float xr=0.f, xz=0.f, xn=0.f, hprev=0.f;
    if (comp && l==0){
      const float* xp = xs + (rowbase + t)*(size_t)ncols + dir*450;
      xr = xp[row]; xz = xp[150+row]; xn = xp[300+row];
      hprev = hr[row];
    }

    float a0=0.f, a1=0.f, a2=0.f;
    if (comp){
      #pragma unroll
      for (int i=0;i<KSTEP;i++){
        float hv = hr[k0 + i];
        a0 += w0[i]*hv; a1 += w1[i]*hv; a2 += w2[i]*hv;
      }
    }
    a0 += __shfl_xor(a0,1); a0 += __shfl_xor(a0,2);
    a1 += __shfl_xor(a1,1); a1 += __shfl_xor(a1,2);
    a2 += __shfl_xor(a2,1); a2 += __shfl_xor(a2,2);

    if (comp && l==0){
      float rr = sigm(xr + a0 + bR);
      float zz = sigm(xz + a1 + bZ);
      float nn = tanhf(xn + rr*(a2 + bN));
      float hn = (1.f - zz)*nn + zz*hprev;
      hw[row] = hn;
      msum += hn;
      if (ys) ys[(rowbase + t)*(size_t)300 + dir*150 + row] = hn;
    }
    __syncthreads();
  }
  if (meanOut && comp && l==0)
    meanOut[(size_t)seq*300 + dir*150 + row] = msum / (float)T;
}

// ---------------------------------------------------------------------------
// Big-GRU recurrence, BOTH dirs per launch, time-sliced. Weights in VGPRs
// (unified AGPR file), tagged-pair LLC h exchange, exact f32 hold + HSEED.
// R6-measured-best partition: small per-block message sets, many blocks.
// ---------------------------------------------------------------------------
template<int BLK, int JB, int KC, int Hh>
__global__ __launch_bounds__(BLK)
void gru_big_k(const float* xs0, const float* xs1,
               const float* Whh,         // [2][3*Hh][Hh] f32
               const float* bhh,         // [2][3*Hh]
               u64* hbuf,                // [2 parity][2 dir][B][Hh/2] tagged pairs
               float* hseed,             // [2 dir][B][Hh] exact f32 chunk seed
               float* meanOut, int mean_stride,
               u32 tagbase,
               int TT, int TC, int t0)
{
  constexpr int LPR   = 8;
  constexpr int KSTEP = 2*KC;
  constexpr int HS    = LPR*KSTEP;
  constexpr int HP    = Hh/2;
  constexpr int NPAIR = 4*HP;
  constexpr int RMAX  = (NPAIR + BLK - 1)/BLK;
  constexpr int H3    = 3*Hh;

  __shared__ __align__(16) f16 hstage[2][4*HS];

  int tid = threadIdx.x;
  int jc = blockIdx.x, bg = blockIdx.y, dir = blockIdx.z;
  int j0 = jc * JB;
  int row = tid >> 3, l = tid & 7;
  bool comp = (row < JB);
  int jg = j0 + row;
  int k0 = l * KSTEP;

  const float* Wd = Whh + (size_t)dir*H3*Hh;
  const float* xs = dir ? xs1 : xs0;
  int xoff = dir ? (TT - TC - t0) : t0;

  h2 w0[KC], w1[KC], w2[KC];
  if (comp){
    const float* p0 = Wd + ((size_t)0*Hh + jg)*(size_t)Hh;
    const float* p1 = Wd + ((size_t)1*Hh + jg)*(size_t)Hh;
    const float* p2 = Wd + ((size_t)2*Hh + jg)*(size_t)Hh;
    #pragma unroll
    for (int i=0;i<KC;i++){
      int k = k0 + 2*i;
      h2 a; a.x=(f16)0.f; a.y=(f16)0.f;
      h2 b = a, c = a;
      if (k < Hh){   a.x=(f16)p0[k];   b.x=(f16)p1[k];   c.x=(f16)p2[k]; }
      if (k+1 < Hh){ a.y=(f16)p0[k+1]; b.y=(f16)p1[k+1]; c.y=(f16)p2[k+1]; }
      w0[i]=a; w1[i]=b; w2[i]=c;
    }
  } else {
    #pragma unroll
    for (int i=0;i<KC;i++){
      h2 z; z.x=(f16)0.f; z.y=(f16)0.f;
      w0[i]=z; w1[i]=z; w2[i]=z;
    }
  }
  float br=0.f, bz=0.f, bn_=0.f;
  if (comp && l < 4){
    br = bhh[(size_t)dir*H3 + jg];
    bz = bhh[(size_t)dir*H3 + Hh + jg];
    bn_= bhh[(size_t)dir*H3 + 2*Hh + jg];
  }

  {
    f16* hz = &hstage[0][0];
    for (int i = tid; i < 2*4*HS; i += BLK) hz[i] = (f16)0.f;
  }

  float msum_own = 0.f;
  float hold_own = 0.f;                  // batch s = l ownership (l < 4)
  if (t0 > 0 && comp && l < 4){
    const float* hs = hseed + (size_t)dir*Bn*Hh;
    hold_own = hs[(size_t)(bg*4+l)*Hh + jg];
  }
  __syncthreads();

  for (int tt = 0; tt < TC; tt++){
    int g = t0 + tt;
    int t = dir ? (TT-1-g) : g;
    int par = g & 1;
    const u64* hrd = hbuf + (size_t)(par*2 + dir)*Bn*HP;
    u64*       hwr = hbuf + (size_t)((1-par)*2 + dir)*Bn*HP;
    f16* hsb = hstage[par];

    u64 tmp[RMAX];
    const u64* hb = hrd + (size_t)(bg*4)*HP;
    if (g != 0){
      #pragma unroll
      for (int r=0;r<RMAX;r++){
        int idx = tid + r*BLK;
        if (idx < NPAIR) tmp[r] = llc_load64(&hb[idx]);
      }
    }

    // xs prefetch: lane l<4 loads batch l only (3 loads, overlaps tag check)
    float xr=0.f, xz=0.f, xn=0.f;
    if (comp && l < 4){
      const float* xp = xs + ((size_t)(bg*4+l)*TC + (t - xoff))*(size_t)H3;
      xr = xp[jg]; xz = xp[Hh+jg]; xn = xp[2*Hh+jg];
    }

    if (g != 0){
      u32 want = tagbase + (u32)g;
      u32 pend = 0;
      #pragma unroll
      for (int r=0;r<RMAX;r++){
        int idx = tid + r*BLK;
        if (idx < NPAIR && (u32)(tmp[r] >> 32) != want) pend |= (1u << r);
      }
      int guard = 0;
      while (pend){
        __builtin_amdgcn_s_sleep(1);
        #pragma unroll
        for (int r=0;r<RMAX;r++)
          if (pend & (1u << r)) tmp[r] = llc_load64(&hb[tid + r*BLK]);
        #pragma unroll
        for (int r=0;r<RMAX;r++)
          if ((pend & (1u << r)) && (u32)(tmp[r] >> 32) == want) pend &= ~(1u << r);
        if (++guard > 200000) break;   // failsafe: wrong result > GPU hang
      }
      #pragma unroll
      for (int r=0;r<RMAX;r++){
        int idx = tid + r*BLK;
        if (idx < NPAIR){
          int s = idx / HP, jp = idx - s*HP;
          union { u32 i; h2 h; } u; u.i = (u32)tmp[r];
          *(h2*)(hsb + s*HS + 2*jp) = u.h;
        }
      }
    }
    __syncthreads();

    float a0[4]={0,0,0,0}, a1[4]={0,0,0,0}, a2[4]={0,0,0,0};
    if (comp){
      const f16* hp = hsb + k0;
      #pragma unroll
      for (int i=0;i<KC;i++){
        const int kk = 2*i;
        h2 hv0 = *(const h2*)(hp + 0*HS + kk);
        h2 hv1 = *(const h2*)(hp + 1*HS + kk);
        h2 hv2 = *(const h2*)(hp + 2*HS + kk);
        h2 hv3 = *(const h2*)(hp + 3*HS + kk);
        a0[0]=FDOT2(w0[i],hv0,a0[0]); a0[1]=FDOT2(w0[i],hv1,a0[1]);
        a0[2]=FDOT2(w0[i],hv2,a0[2]); a0[3]=FDOT2(w0[i],hv3,a0[3]);
        a1[0]=FDOT2(w1[i],hv0,a1[0]); a1[1]=FDOT2(w1[i],hv1,a1[1]);
        a1[2]=FDOT2(w1[i],hv2,a1[2]); a1[3]=FDOT2(w1[i],hv3,a1[3]);
        a2[0]=FDOT2(w2[i],hv0,a2[0]); a2[1]=FDOT2(w2[i],hv1,a2[1]);
        a2[2]=FDOT2(w2[i],hv2,a2[2]); a2[3]=FDOT2(w2[i],hv3,a2[3]);
      }
    }
    #pragma unroll
    for (int s=0;s<4;s++){
      a0[s] += __shfl_xor(a0[s],1); a0[s] += __shfl_xor(a0[s],2); a0[s] += __shfl_xor(a0[s],4);
      a1[s] += __shfl_xor(a1[s],1); a1[s] += __shfl_xor(a1[s],2); a1[s] += __shfl_xor(a1[s],4);
      a2[s] += __shfl_xor(a2[s],1); a2[s] += __shfl_xor(a2[s],2); a2[s] += __shfl_xor(a2[s],4);
    }
    // select own batch's sums via cndmask chain (no runtime array index)
    float t0a = (l & 1) ? a0[1] : a0[0], t0b = (l & 1) ? a0[3] : a0[2];
    float A0 = (l & 2) ? t0b : t0a;
    float t1a = (l & 1) ? a1[1] : a1[0], t1b = (l & 1) ? a1[3] : a1[2];
    float A1 = (l & 2) ? t1b : t1a;
    float t2a = (l & 1) ? a2[1] : a2[0], t2b = (l & 1) ? a2[3] : a2[2];
    float A2 = (l & 2) ? t2b : t2a;

    float hn_own = 0.f;
    if (comp && l < 4){
      float rr = sigm(xr + A0 + br);
      float zz = sigm(xz + A1 + bz);
      float nn = tanhf(xn + rr*(A2 + bn_));
      hn_own = (1.f - zz)*nn + zz*hold_own;
      hold_own = hn_own;
      msum_own += hn_own;
    }
    // pair adjacent rows: even row's lane l grabs odd row's hn (lane+8)
    u32 wtag = tagbase + (u32)g + 1u;
    float hp2 = __shfl_down(hn_own, 8);
    if (comp && l < 4 && !(row & 1)){
      h2 pk; pk.x = (f16)hn_own; pk.y = (f16)hp2;
      union { h2 h; u32 i; } u; u.h = pk;
      llc_store64(&hwr[(size_t)(bg*4+l)*HP + ((unsigned)(j0+row) >> 1)],
                  ((u64)wtag << 32) | (u64)u.i);
    }
    if (tt == TC-1 && comp && l < 4){
      float* hs = hseed + (size_t)dir*Bn*Hh;
      hs[(size_t)(bg*4+l)*Hh + jg] = hold_own;
    }
  }
  if (comp && l < 4){
    float* mp = meanOut + (size_t)(bg*4+l)*mean_stride + dir*Hh + jg;
    *mp += msum_own / (float)TT;
  }
}

// ---------------------------------------------------------------------------
// mask_att + fact_sep fused: per (b, 8-t chunk). float4 staging + dots.
// ---------------------------------------------------------------------------
__global__ __launch_bounds__(256)
void mask_att_k(const float* ctx, const float* vh, float* simOut, float* diffOut)
{
  __shared__ __align__(16) float vhl[50*300];
  __shared__ __align__(16) float ctxl[8*300];
  __shared__ float attl[8*52];
  __shared__ __align__(16) float scenl[8*300];
  __shared__ float ratio[8];
  int tid = threadIdx.x;
  int b = blockIdx.y, tc = blockIdx.x;
  int grp = tid >> 5, ln = tid & 31;        // 8 groups x 32 lanes
  size_t cbase = ((size_t)b*Tn + tc*8) * 300;
  {
    const f4* vsrc = (const f4*)(vh + (size_t)b*15000);
    f4* vdst = (f4*)vhl;
    for (int i = tid; i < 3750; i += 256) vdst[i] = vsrc[i];
    const f4* csrc = (const f4*)(ctx + cbase);
    f4* cdst = (f4*)ctxl;
    for (int i = tid; i < 600; i += 256) cdst[i] = csrc[i];
  }
  __syncthreads();
  for (int p = tid; p < 400; p += 256){
    int ttl = p / 50, v = p % 50;
    const f4* cp = (const f4*)(ctxl + ttl*300);
    const f4* vp = (const f4*)(vhl + v*300);
    float acc = 0.f;
    for (int d4 = 0; d4 < 75; d4++){
      f4 c = cp[d4], vv = vp[d4];
      acc += c.x*vv.x + c.y*vv.y + c.z*vv.z + c.w*vv.w;
    }
    attl[ttl*52 + v] = acc;
  }
  __syncthreads();
  // masked softmax over v=0..50 per row (group grp owns row grp)
  {
    float mx = -INFINITY;
    for (int v = ln; v < 50; v += 32){
      float a = attl[grp*52+v];
      float msk = (a == 0.f) ? -INFINITY : a;
      attl[grp*52+v] = msk;
      mx = fmaxf(mx, msk);
    }
    #pragma unroll
    for (int m=1; m<32; m<<=1) mx = fmaxf(mx, __shfl_xor(mx, m));
    if (mx == -INFINITY){
      for (int v = ln; v < 50; v += 32) attl[grp*52+v] = 0.f;
    } else {
      float sum = 0.f;
      for (int v = ln; v < 50; v += 32){
        float e = expf(attl[grp*52+v] - mx);
        attl[grp*52+v] = e;
        sum += e;
      }
      #pragma unroll
      for (int m=1; m<32; m<<=1) sum += __shfl_xor(sum, m);
      float inv = 1.f/sum;
      for (int v = ln; v < 50; v += 32) attl[grp*52+v] *= inv;
    }
  }
  __syncthreads();
  // scen[ttl][d] = sum_v att[ttl][v] * vh[v][d] — float4 over d
  for (int p4 = tid; p4 < 600; p4 += 256){
    int ttl = p4 / 75, d4 = p4 % 75;
    f4 acc = (f4){0.f,0.f,0.f,0.f};
    for (int v = 0; v < 50; v++){
      float a = attl[ttl*52+v];
      f4 vv = ((const f4*)(vhl + v*300))[d4];
      acc.x += a*vv.x; acc.y += a*vv.y; acc.z += a*vv.z; acc.w += a*vv.w;
    }
    ((f4*)scenl)[p4] = acc;
  }
  __syncthreads();
  // ratio = <ctx,scen>/<scen,scen> per row, 32-lane parallel dot
  {
    float x3 = 0.f, x4 = 0.f;
    for (int d = ln; d < 300; d += 32){
      float s = scenl[grp*300+d];
      x3 += ctxl[grp*300+d]*s; x4 += s*s;
    }
    #pragma unroll
    for (int m=1; m<32; m<<=1){ x3 += __shfl_xor(x3, m); x4 += __shfl_xor(x4, m); }
    if (ln == 0) ratio[grp] = x3 / (x4 + 1e-10f);
  }
  __syncthreads();
  {
    f4* so = (f4*)(simOut + cbase);
    f4* dfo = (f4*)(diffOut + cbase);
    const f4* sc = (const f4*)scenl;
    const f4* cl = (const f4*)ctxl;
    for (int p4 = tid; p4 < 600; p4 += 256){
      float rt = ratio[p4 / 75];
      f4 s = sc[p4], c = cl[p4];
      f4 sim = (f4){rt*s.x, rt*s.y, rt*s.z, rt*s.w};
      so[p4] = sim;
      dfo[p4] = (f4){c.x - sim.x, c.y - sim.y, c.z - sim.z, c.w - sim.w};
    }
  }
}

// ---------------------------------------------------------------------------
// code_wise helpers (batched over qi)
// ---------------------------------------------------------------------------
__global__ __launch_bounds__(256)
void softmaxT_k(const float* m, float* att){
  __shared__ float red[256];
  int b = blockIdx.x, tid = threadIdx.x;
  size_t base = (size_t)blockIdx.y*16384;
  float v1 = m[base + b*512 + tid], v2 = m[base + b*512 + 256 + tid];
  red[tid] = fmaxf(v1, v2); __syncthreads();
  for (int s=128; s; s>>=1){ if (tid<s) red[tid] = fmaxf(red[tid], red[tid+s]); __syncthreads(); }
  float M = red[0]; __syncthreads();
  float e1 = expf(v1-M), e2 = expf(v2-M);
  red[tid] = e1+e2; __syncthreads();
  for (int s=128; s; s>>=1){ if (tid<s) red[tid] += red[tid+s]; __syncthreads(); }
  float inv = 1.f / red[0];
  att[base + b*512+tid] = e1*inv; att[base + b*512+256+tid] = e2*inv;
}

// t split over 8 blocks, qi over z; partial sums via atomicAdd; out zeroed.
__global__ __launch_bounds__(256)
void wsum_k(const float* att, const float* dh, float* out){
  int b = blockIdx.x, c = blockIdx.y, tid = threadIdx.x;
  int qi = blockIdx.z;
  const float* ap = att + (size_t)qi*16384 + b*512;
  float* op = out + (size_t)qi*9600 + b*300;
  int t0 = c * 64;
  for (int d = tid; d < 300; d += 256){
    float acc = 0.f;
    #pragma unroll 8
    for (int t = t0; t < t0 + 64; t++)
      acc += ap[t] * dh[((size_t)b*512 + t)*300 + d];
    atomicAdd(&op[d], acc);
  }
}

// ---------------------------------------------------------------------------
// graph_decomp: fused coef+agg (one 64-lane wave per edge), then upd.
// ---------------------------------------------------------------------------
__global__ __launch_bounds__(64)
void coefagg_k(const float* L, const int* src, const int* dst, int E, float* agg){
  int e = blockIdx.x;
  int lane = threadIdx.x;
  const float* Li = L + (size_t)src[e]*300;
  const float* Lj = L + (size_t)dst[e]*300;
  float num = 0.f, den = 0.f;
  for (int d = lane; d < 300; d += 64){ float lj = Lj[d]; num += Li[d]*lj; den += lj*lj; }
  for (int off = 32; off; off >>= 1){ num += __shfl_xor(num, off, 64); den += __shfl_xor(den, off, 64); }
  float c = num / (den + 1e-10f);
  float* ag = agg + (size_t)src[e]*300;
  for (int d = lane; d < 300; d += 64) atomicAdd(&ag[d], c*Lj[d]);
}
__global__ void count_k(const int* src, int E, float* counts){
  int e = blockIdx.x*256 + threadIdx.x;
  if (e < E) atomicAdd(&counts[src[e]], 1.f);
}
__global__ void upd_k(const float* L, const float* agg, const float* counts, float* out, int n){
  int i = blockIdx.x;
  float c = counts[i];
  for (int d = threadIdx.x; d < 300; d += 256){
    float v = L[(size_t)i*300+d];
    out[(size_t)i*300+d] = (c > 0.f) ? v - agg[(size_t)i*300+d]/fmaxf(c, 1.f) : v;
  }
}

// ---------------------------------------------------------------------------
// classifier heads: one 64-lane wave per (b, c), k strided by lane.
// ---------------------------------------------------------------------------
__global__ __launch_bounds__(256)
void logits_k(const float* A0, const float* A1, const float* A2, int srcw,
              const float* W, const float* bias, int C, int K,
              float* outF){
  int b = blockIdx.x;
  int c = blockIdx.y*4 + (threadIdx.x >> 6);
  int lane = threadIdx.x & 63;
  if (c >= C) return;
  const float* wp = W + (size_t)c*K;
  float acc = 0.f;
  for (int k = lane; k < K; k += 64){
    int s = k / srcw; int kk = k - s*srcw;
    const float* Ap = (s==0) ? A0 : ((s==1) ? A1 : A2);
    acc += Ap[(size_t)b*srcw + kk] * wp[k];
  }
  for (int off = 32; off; off >>= 1) acc += __shfl_xor(acc, off, 64);
  if (lane == 0) outF[b*C + c] = acc + bias[c];
}
__global__ void argmax_k(const float* lf, int C, int* pred){
  int b = threadIdx.x;
  if (b < 32){
    const float* p = lf + (size_t)b*C;
    int best = 0; float bv = p[0];
    for (int c = 1; c < C; c++){ float v = p[c]; if (v > bv){ bv = v; best = c; } }
    pred[b] = best;
  }
}
__global__ void vtok_k(const int* table, const int* pred, int* vt, int L){
  int i = blockIdx.x*256 + threadIdx.x;
  if (i < 32*L) vt[i] = table[pred[i/L]*L + i%L];
}

// ---------------------------------------------------------------------------
extern "C" void kernel_launch(void* const* d_in, const int* in_sizes, int n_in,
                              void* d_out, int out_size, void* d_ws, size_t ws_size,
                              hipStream_t stream)
{
  (void)in_sizes; (void)n_in; (void)out_size;
  const float* E        = (const float*)d_in[0];
  const int* chTok    = (const int*)d_in[1];
  const int* arTok    = (const int*)d_in[2];
  const int* docs     = (const int*)d_in[3];
  const int* chVerd   = (const int*)d_in[4];
  const int* arVerd   = (const int*)d_in[5];
  const int* c_src    = (const int*)d_in[6];
  const int* c_dst    = (const int*)d_in[7];
  const int* a_src    = (const int*)d_in[8];
  const int* a_dst    = (const int*)d_in[9];
  const float* enc_Wih  = (const float*)d_in[10];
  const float* enc_Whh  = (const float*)d_in[11];
  const float* enc_bih  = (const float*)d_in[12];
  const float* enc_bhh  = (const float*)d_in[13];
  const float* ech_Wih  = (const float*)d_in[14];
  const float* ech_Whh  = (const float*)d_in[15];
  const float* ech_bih  = (const float*)d_in[16];
  const float* ech_bhh  = (const float*)d_in[17];
  const float* term_Wih = (const float*)d_in[18];
  const float* term_Whh = (const float*)d_in[19];
  const float* term_bih = (const float*)d_in[20];
  const float* term_bhh = (const float*)d_in[21];
  const float* art_Wih  = (const float*)d_in[22];
  const float* art_Whh  = (const float*)d_in[23];
  const float* art_bih  = (const float*)d_in[24];
  const float* art_bhh  = (const float*)d_in[25];
  const float* W_charge = (const float*)d_in[26];
  const float* b_charge = (const float*)d_in[27];
  const float* W_article= (const float*)d_in[28];
  const float* b_article= (const float*)d_in[29];
  const float* W_time   = (const float*)d_in[30];
  const float* b_time   = (const float*)d_in[31];
  float* out = (float*)d_out;
  float* OUTC = out;            // [32][119]
  float* OUTA = out + 3808;     // [32][103]
  float* OUTT = out + 7104;     // [32][11]

  char* wsb = (char*)d_ws;
  size_t off = 0;
  auto alloc = [&](size_t nf)->float* {
    float* p = (float*)(wsb + off);
    off += ((nf*4 + 255) & ~(size_t)255);
    return p;
  };
  float* XS0   = alloc(14745600ULL);        // 59.0 MB
  float* XS1   = alloc(14745600ULL);        // 59.0 MB
  float* DH    = alloc(4915200);            // d_hidden [32][512][300]
  float* ADC   = alloc(4915200);            // adc, later dsc
  float* SEC   = alloc(4915200);
  float* SSC   = alloc(4915200);
  float* VHYS  = alloc(480000);             // [32][50][300]
  float* MECH  = alloc(66600);              // encch means [222][300]
  float* LC1   = alloc(35700);
  float* LC0   = alloc(35700);
  float* LA1   = alloc(30900);
  float* LA0   = alloc(30900);
  float* AGG   = alloc(142800);             // 4 x 35700 (zeroed once)
  float* CNTS  = alloc(256);                // counts_c @0, counts_a @128
  float* DHC   = alloc(9600);               // DHC..DB contiguous (qi stride 9600)
  float* DA    = alloc(9600);
  float* DHNA  = alloc(9600);
  float* DB    = alloc(9600);
  float* MDH   = alloc(9600);               // mean_t d_hidden [32][300]
  float* MFA   = alloc(38400);              // fa mean [32][1200] (accumulated)
  float* MTH   = alloc(28800);              // th mean [32][900] (accumulated)
  float* RB    = alloc(115200);             // art rowbias [32][3600]
  float* RMX   = alloc(65536);              // [4][16384]
  float* ATTB  = alloc(65536);              // [4][16384]
  u64*   HBUF  = (u64*)alloc(76800);        // [2][2][32][300] u64 tagged pairs
  float* HSEED = alloc(38400);              // [2][32][600] exact f32 seeds
  int*   PREDC = (int*)alloc(64);
  int*   PREDA = (int*)alloc(64);
  int*   VTOK  = (int*)alloc(1600);
  int*   TCC   = (int*)alloc(11104);

  if (off > ws_size) return;   // diagnostic: leaves out==0 -> absmax==max|ref|

  float* AGGc1 = AGG;
  float* AGGc2 = AGG + 35700;
  float* AGGa1 = AGG + 71400;
  float* AGGa2 = AGG + 107100;

  hipMemsetAsync(HBUF, 0, 2*2*Bn*300*sizeof(u64), stream);  // tags = 0
  // zero AGG(4x) + CNTS + DHC..DB in ONE contiguous memset (span incl. pads)
  {
    size_t zlen = (size_t)((char*)(DB + 9600) - (char*)AGG);
    hipMemsetAsync(AGG, 0, zlen, stream);
  }

  // --- embeds for encch (-> XS1) and docs (-> XS0), z-batched ---
  hipMemcpyAsync(TCC, chTok, NCn*LCn*4, hipMemcpyDeviceToDevice, stream);
  hipMemcpyAsync(TCC + NCn*LCn, arTok, NAn*LCn*4, hipMemcpyDeviceToDevice, stream);
  embed_mfma_k<<<dim3(8,128,2),256,0,stream>>>(E, TCC, docs,
      ech_Wih, enc_Wih, ech_bih, enc_bih,
      XS1, XS0, 11100, 16384, 900, 200);
  gru_small_k<<<dim3(222,2),640,0,stream>>>(XS1, 900, ech_Whh, ech_bhh, nullptr, MECH, 50);
  gru_small_k<<<dim3(32,2),640,0,stream>>>(XS0, 900, enc_Whh, enc_bhh, DH, MDH, 512);

  // --- graph_decomp (charge, article), 2 layers each, fused coef+agg ---
  count_k<<<3,256,0,stream>>>(c_src, ECn, CNTS);
  count_k<<<2,256,0,stream>>>(a_src, EAn, CNTS+128);
  coefagg_k<<<ECn,64,0,stream>>>(MECH, c_src, c_dst, ECn, AGGc1);
  upd_k<<<NCn,256,0,stream>>>(MECH, AGGc1, CNTS, LC1, NCn);
  coefagg_k<<<ECn,64,0,stream>>>(LC1, c_src, c_dst, ECn, AGGc2);
  upd_k<<<NCn,256,0,stream>>>(LC1, AGGc2, CNTS, LC0, NCn);

  const float* MEAR = MECH + (size_t)NCn*300;
  coefagg_k<<<EAn,64,0,stream>>>(MEAR, a_src, a_dst, EAn, AGGa1);
  upd_k<<<NAn,256,0,stream>>>(MEAR, AGGa1, CNTS+128, LA1, NAn);
  coefagg_k<<<EAn,64,0,stream>>>(LA1, a_src, a_dst, EAn, AGGa2);
  upd_k<<<NAn,256,0,stream>>>(LA1, AGGa2, CNTS+128, LA0, NAn);

  // --- code_wise x4, BATCHED: qi = {LC0->DHC, MECH->DA, LA0->DHNA, MEAR->DB} ---
  score_rowmax_k<<<dim3(128,4),256,0,stream>>>(DH, LC0, MECH, LA0, MEAR,
      NCn, NAn, RMX);
  softmaxT_k<<<dim3(32,4),256,0,stream>>>(RMX, ATTB);
  wsum_k<<<dim3(32,8,4),256,0,stream>>>(ATTB, DH, DHC);

  // --- charge head ---
  logits_k<<<dim3(32,30),256,0,stream>>>(MDH, DHC, DA, 300, W_charge, b_charge, NCn, 900, OUTC);
  argmax_k<<<1,64,0,stream>>>(OUTC, NCn, PREDC);

  // --- fact_sep #1 ---
  vtok_k<<<7,256,0,stream>>>(chVerd, PREDC, VTOK, LVn);
  embed_mfma_k<<<dim3(8,13,1),256,0,stream>>>(E, VTOK, VTOK,
      enc_Wih, enc_Wih, enc_bih, enc_bih,
      XS0, XS0, 1600, 1600, 900, 200);
  gru_small_k<<<dim3(32,2),640,0,stream>>>(XS0, 900, enc_Whh, enc_bhh, VHYS, nullptr, 50);
  mask_att_k<<<dim3(64,32),256,0,stream>>>(DH, VHYS, ADC, SEC);

  // --- article bigru: rowbias, then time-sliced dual-dir chunks ---
  {
    dim3 g((3600+127)/128, 1);
    gemm_k<0><<<g,256,0,stream>>>(DHNA, DB, nullptr, nullptr, nullptr,
        art_Wih, 1200, 300, 900, 0, art_bih, nullptr, 1, 1, IDIV,0,0,
        RB, 32, 3600, 600);
  }
  hipMemsetAsync(MFA, 0, 38400*4, stream);
  for (int L = 0; L < 2; L++){
    stage_mfma_k<<<dim3(15,64,2),256,0,stream>>>(DH, ADC, nullptr,
        art_Wih, art_Wih + (size_t)1800*1200, 1200, 0, 600, 0,
        nullptr, nullptr, RB, RB + 1800, 3600,
        256*L, 256*(1-L),
        XS0, XS1, 1800, 600);
    gru_big_k<384,40,38,600><<<dim3(15,8,2),384,0,stream>>>(XS0, XS1,
        art_Whh, art_bhh, HBUF, HSEED, MFA, 1200, 0u,
        512, 256, 256*L);
  }
  logits_k<<<dim3(32,26),256,0,stream>>>(MFA, nullptr, nullptr, 1200, W_article, b_article, NAn, 1200, OUTA);
  argmax_k<<<1,64,0,stream>>>(OUTA, NAn, PREDA);

  // --- fact_sep #2 (context = sec_vector) ---
  vtok_k<<<7,256,0,stream>>>(arVerd, PREDA, VTOK, LVn);
  embed_mfma_k<<<dim3(8,13,1),256,0,stream>>>(E, VTOK, VTOK,
      enc_Wih, enc_Wih, enc_bih, enc_bih,
      XS0, XS0, 1600, 1600, 900, 200);
  gru_small_k<<<dim3(32,2),640,0,stream>>>(XS0, 900, enc_Whh, enc_bhh, VHYS, nullptr, 50);
  mask_att_k<<<dim3(64,32),256,0,stream>>>(SEC, VHYS, SSC, ADC);   // ssc, dsc(=ADC)

  // --- term bigru, time-sliced dual-dir chunks ---
  hipMemsetAsync(MTH, 0, 28800*4, stream);
  for (int L = 0; L < 2; L++){
    stage_mfma_k<<<dim3(11,64,2),256,0,stream>>>(DH, SSC, ADC,
        term_Wih, term_Wih + (size_t)1350*900, 900, 0, 300, 600,
        term_bih, term_bih + 1350, nullptr, nullptr, 0,
        256*L, 256*(1-L),
        XS0, XS1, 1350, 900);
    gru_big_k<448,50,29,450><<<dim3(9,8,2),448,0,stream>>>(XS0, XS1,
        term_Whh, term_bhh, HBUF, HSEED, MTH, 900, 512u,
        512, 256, 256*L);
  }
  logits_k<<<dim3(32,3),256,0,stream>>>(MTH, nullptr, nullptr, 900, W_time, b_time, NTn, 900, OUTT);
}